// Round 1
// baseline (2326.607 us; speedup 1.0000x reference)
//
#include <hip/hip_runtime.h>

#define N_NODES 100000
#define N_EDGES 1600000
#define EP (N_EDGES + N_NODES)
#define NG 64
#define NH 4

static inline int cdiv(int a, int b) { return (a + b - 1) / b; }

__device__ __forceinline__ float lrelu(float x) { return x >= 0.f ? x : 0.2f * x; }

__device__ __forceinline__ float wredmax(float v) {
#pragma unroll
  for (int off = 32; off; off >>= 1) v = fmaxf(v, __shfl_xor(v, off));
  return v;
}
__device__ __forceinline__ float wredsum(float v) {
#pragma unroll
  for (int off = 32; off; off >>= 1) v += __shfl_xor(v, off);
  return v;
}

// ---------------- CSR build ----------------
__global__ void k_count(const int* __restrict__ ei, int* __restrict__ cnt) {
  int e = blockIdx.x * blockDim.x + threadIdx.x;
  if (e < N_EDGES) atomicAdd(&cnt[ei[N_EDGES + e]], 1);
  else if (e < EP) atomicAdd(&cnt[e - N_EDGES], 1);  // self loop
}

__global__ void k_scan(const int* __restrict__ cnt, int* __restrict__ indptr) {
  __shared__ int sh[1024];
  __shared__ int carry;
  int t = threadIdx.x;
  if (t == 0) { carry = 0; indptr[0] = 0; }
  __syncthreads();
  for (int base = 0; base < N_NODES; base += 1024) {
    int idx = base + t;
    int v = (idx < N_NODES) ? cnt[idx] : 0;
    sh[t] = v;
    __syncthreads();
    for (int off = 1; off < 1024; off <<= 1) {
      int add = (t >= off) ? sh[t - off] : 0;
      __syncthreads();
      sh[t] += add;
      __syncthreads();
    }
    if (idx < N_NODES) indptr[idx + 1] = carry + sh[t];
    int tot = sh[1023];
    __syncthreads();
    if (t == 0) carry += tot;
    __syncthreads();
  }
}

__global__ void k_scatter(const int* __restrict__ ei, const int* __restrict__ indptr,
                          int* __restrict__ epos, int* __restrict__ esrc) {
  int e = blockIdx.x * blockDim.x + threadIdx.x;
  if (e < N_EDGES) {
    int d = ei[N_EDGES + e], s = ei[e];
    int p = atomicAdd(&epos[d], 1);
    esrc[indptr[d] + p] = s;
  } else if (e < EP) {
    int nn = e - N_EDGES;
    int p = atomicAdd(&epos[nn], 1);
    esrc[indptr[nn] + p] = nn;
  }
}

// ---------------- h = x @ W ----------------
template <int FIN, int HD, int NPB>
__global__ __launch_bounds__(256) void k_lin(const float* __restrict__ x, const float* __restrict__ W,
                                             float* __restrict__ hout) {
  __shared__ float xs[NPB][FIN];
  int n0 = blockIdx.x * NPB;
  int t = threadIdx.x;
  for (int i = t; i < NPB * FIN; i += 256) {
    int nd = i / FIN, f = i - nd * FIN;
    int n = n0 + nd;
    xs[nd][f] = (n < N_NODES) ? x[(size_t)n * FIN + f] : 0.f;
  }
  __syncthreads();
  for (int col = t; col < HD; col += 256) {
    float acc[NPB];
#pragma unroll
    for (int nd = 0; nd < NPB; nd++) acc[nd] = 0.f;
    for (int i = 0; i < FIN; i++) {
      float w = W[i * HD + col];
#pragma unroll
      for (int nd = 0; nd < NPB; nd++) acc[nd] = fmaf(xs[nd][i], w, acc[nd]);
    }
#pragma unroll
    for (int nd = 0; nd < NPB; nd++) {
      int n = n0 + nd;
      if (n < N_NODES) hout[(size_t)n * HD + col] = acc[nd];
    }
  }
}

// ---------------- per-node attention dots ----------------
template <int D>
__global__ void k_alpha(const float* __restrict__ h, const float* __restrict__ aS,
                        const float* __restrict__ aD, float* __restrict__ as_,
                        float* __restrict__ ad_) {
  int i = blockIdx.x * blockDim.x + threadIdx.x;
  if (i >= N_NODES * NH) return;
  int n = i >> 2, hh = i & 3;
  const float* hr = h + (size_t)n * (NH * D) + hh * D;
  const float* sa = aS + hh * D;
  const float* da = aD + hh * D;
  float vs = 0.f, vd = 0.f;
#pragma unroll 8
  for (int k = 0; k < D; k++) {
    float hv = hr[k];
    vs = fmaf(hv, sa[k], vs);
    vd = fmaf(hv, da[k], vd);
  }
  as_[i] = vs;
  ad_[i] = vd;
}

// ---------------- softmax + gather-aggregate (wave per node) ----------------
template <int D>
__global__ __launch_bounds__(256) void k_agg(const int* __restrict__ indptr, const int* __restrict__ esrc,
                                             const float* __restrict__ h, const float4* __restrict__ as4,
                                             const float4* __restrict__ ad4, const float* __restrict__ bias,
                                             float* __restrict__ tout) {
  int lane = threadIdx.x & 63;
  int n = blockIdx.x * 4 + (threadIdx.x >> 6);
  if (n >= N_NODES) return;
  int e0 = indptr[n], e1 = indptr[n + 1];
  float4 ad = ad4[n];
  // pass 1: per-head max
  float m0 = -3.4e38f, m1 = m0, m2 = m0, m3 = m0;
  for (int i = e0 + lane; i < e1; i += 64) {
    float4 av = as4[esrc[i]];
    m0 = fmaxf(m0, lrelu(av.x + ad.x));
    m1 = fmaxf(m1, lrelu(av.y + ad.y));
    m2 = fmaxf(m2, lrelu(av.z + ad.z));
    m3 = fmaxf(m3, lrelu(av.w + ad.w));
  }
  m0 = wredmax(m0); m1 = wredmax(m1); m2 = wredmax(m2); m3 = wredmax(m3);
  // pass 2: sum of exps
  float s0 = 0.f, s1 = 0.f, s2 = 0.f, s3 = 0.f;
  for (int i = e0 + lane; i < e1; i += 64) {
    float4 av = as4[esrc[i]];
    s0 += __expf(lrelu(av.x + ad.x) - m0);
    s1 += __expf(lrelu(av.y + ad.y) - m1);
    s2 += __expf(lrelu(av.z + ad.z) - m2);
    s3 += __expf(lrelu(av.w + ad.w) - m3);
  }
  s0 = wredsum(s0); s1 = wredsum(s1); s2 = wredsum(s2); s3 = wredsum(s3);
  float r0 = 1.f / (s0 + 1e-16f), r1 = 1.f / (s1 + 1e-16f);
  float r2 = 1.f / (s2 + 1e-16f), r3 = 1.f / (s3 + 1e-16f);
  // pass 3: weighted gather
  if constexpr (D == 64) {
    float a0 = 0.f, a1 = 0.f, a2 = 0.f, a3 = 0.f;
    for (int i = e0; i < e1; i++) {
      int s = esrc[i];
      float4 av = as4[s];
      float w0 = __expf(lrelu(av.x + ad.x) - m0) * r0;
      float w1 = __expf(lrelu(av.y + ad.y) - m1) * r1;
      float w2 = __expf(lrelu(av.z + ad.z) - m2) * r2;
      float w3 = __expf(lrelu(av.w + ad.w) - m3) * r3;
      const float* hr = h + (size_t)s * 256;
      a0 = fmaf(w0, hr[lane], a0);
      a1 = fmaf(w1, hr[64 + lane], a1);
      a2 = fmaf(w2, hr[128 + lane], a2);
      a3 = fmaf(w3, hr[192 + lane], a3);
    }
    float v = (a0 + a1 + a2 + a3) * 0.25f + bias[lane];
    tout[(size_t)n * 64 + lane] = fmaxf(v, 0.f);  // fused ReLU
  } else {
    // D == 32: lanes 0..31 handle heads 0,1; lanes 32..63 handle heads 2,3
    int d = lane & 31, hi = lane >> 5;
    float a0 = 0.f, a1 = 0.f;
    for (int i = e0; i < e1; i++) {
      int s = esrc[i];
      float4 av = as4[s];
      float w0 = __expf(lrelu(av.x + ad.x) - m0) * r0;
      float w1 = __expf(lrelu(av.y + ad.y) - m1) * r1;
      float w2 = __expf(lrelu(av.z + ad.z) - m2) * r2;
      float w3 = __expf(lrelu(av.w + ad.w) - m3) * r3;
      float wa = hi ? w2 : w0;
      float wb = hi ? w3 : w1;
      const float* hr = h + (size_t)s * 128 + hi * 64 + d;
      a0 = fmaf(wa, hr[0], a0);
      a1 = fmaf(wb, hr[32], a1);
    }
    float v = a0 + a1;
    v += __shfl_xor(v, 32);
    if (lane < 32) tout[(size_t)n * 32 + d] = fmaxf(v * 0.25f + bias[d], 0.f);
  }
}

// ---------------- batch norm ----------------
template <int C>
__global__ __launch_bounds__(256) void k_bnstat(const float* __restrict__ x, float* __restrict__ part) {
  const int RG = 256 / C;
  int col = threadIdx.x & (C - 1);
  int rg = threadIdx.x / C;
  int rows = (N_NODES + gridDim.x - 1) / gridDim.x;
  int r0 = blockIdx.x * rows;
  int r1 = min(N_NODES, r0 + rows);
  float s = 0.f, q = 0.f;
  for (int r = r0 + rg; r < r1; r += RG) {
    float v = x[(size_t)r * C + col];
    s += v;
    q = fmaf(v, v, q);
  }
  __shared__ float sh[512];
  sh[threadIdx.x] = s;
  sh[256 + threadIdx.x] = q;
  __syncthreads();
  for (int step = 128; step >= C; step >>= 1) {
    if (threadIdx.x < step) {
      sh[threadIdx.x] += sh[threadIdx.x + step];
      sh[256 + threadIdx.x] += sh[256 + threadIdx.x + step];
    }
    __syncthreads();
  }
  if (threadIdx.x < C) {
    part[blockIdx.x * 2 * C + threadIdx.x] = sh[threadIdx.x];
    part[blockIdx.x * 2 * C + C + threadIdx.x] = sh[256 + threadIdx.x];
  }
}

template <int C>
__global__ void k_bnfinal(const float* __restrict__ part, const float* __restrict__ g,
                          const float* __restrict__ be, float* __restrict__ scale,
                          float* __restrict__ shift) {
  int c = threadIdx.x;
  if (c >= C) return;
  float s = 0.f, q = 0.f;
  for (int b = 0; b < 256; b++) {
    s += part[b * 2 * C + c];
    q += part[b * 2 * C + C + c];
  }
  float mean = s / (float)N_NODES;
  float var = q / (float)N_NODES - mean * mean;
  float sc = g[c] * rsqrtf(var + 1e-5f);
  scale[c] = sc;
  shift[c] = be[c] - mean * sc;
}

template <int C>
__global__ void k_bnapply(const float* __restrict__ t, const float* __restrict__ scale,
                          const float* __restrict__ shift, float* __restrict__ y) {
  int i = blockIdx.x * blockDim.x + threadIdx.x;
  if (i >= N_NODES * C) return;
  int c = i & (C - 1);
  y[i] = fmaf(t[i], scale[c], shift[c]);
}

// ---------------- pooling + MLP ----------------
__global__ void k_pool(const float* __restrict__ f3, const int* __restrict__ batch,
                       float* __restrict__ pool, float* __restrict__ cntg) {
  int i = blockIdx.x * blockDim.x + threadIdx.x;
  if (i >= N_NODES * 32) return;
  int n = i >> 5, c = i & 31;
  int b = batch[n];
  atomicAdd(&pool[b * 32 + c], f3[i]);
  if (c == 0) atomicAdd(&cntg[b], 1.0f);
}

__global__ void k_mlp(const float* __restrict__ pool, const float* __restrict__ cntg,
                      const float* __restrict__ Wp1, const float* __restrict__ bp1,
                      const float* __restrict__ Wp2, const float* __restrict__ bp2,
                      float* __restrict__ out) {
  int g = threadIdx.x;
  if (g >= NG) return;
  float inv = 1.f / fmaxf(cntg[g], 1.f);
  float p[32];
#pragma unroll
  for (int c = 0; c < 32; c++) p[c] = pool[g * 32 + c] * inv;
  float o = bp2[0];
  for (int j = 0; j < 16; j++) {
    float hsum = bp1[j];
#pragma unroll
    for (int c = 0; c < 32; c++) hsum = fmaf(p[c], Wp1[c * 16 + j], hsum);
    o = fmaf(fmaxf(hsum, 0.f), Wp2[j], o);
  }
  out[g] = o;
}

extern "C" void kernel_launch(void* const* d_in, const int* in_sizes, int n_in,
                              void* d_out, int out_size, void* d_ws, size_t ws_size,
                              hipStream_t stream) {
  const float* x = (const float*)d_in[0];
  const int* ei = (const int*)d_in[1];
  const int* batch = (const int*)d_in[2];
  const float* W1 = (const float*)d_in[3];
  const float* aS1 = (const float*)d_in[4];
  const float* aD1 = (const float*)d_in[5];
  const float* b1 = (const float*)d_in[6];
  const float* g1 = (const float*)d_in[7];
  const float* be1 = (const float*)d_in[8];
  const float* W2 = (const float*)d_in[9];
  const float* aS2 = (const float*)d_in[10];
  const float* aD2 = (const float*)d_in[11];
  const float* b2 = (const float*)d_in[12];
  const float* g2 = (const float*)d_in[13];
  const float* be2 = (const float*)d_in[14];
  const float* W3 = (const float*)d_in[15];
  const float* aS3 = (const float*)d_in[16];
  const float* aD3 = (const float*)d_in[17];
  const float* b3 = (const float*)d_in[18];
  const float* g3 = (const float*)d_in[19];
  const float* be3 = (const float*)d_in[20];
  const float* Wp1 = (const float*)d_in[21];
  const float* bp1 = (const float*)d_in[22];
  const float* Wp2 = (const float*)d_in[23];
  const float* bp2 = (const float*)d_in[24];
  float* out = (float*)d_out;

  size_t off = 0;
  auto alloc = [&](size_t bytes) -> void* {
    void* p = (char*)d_ws + off;
    off += (bytes + 255) & ~(size_t)255;
    return p;
  };
  int* cnt = (int*)alloc((size_t)N_NODES * 4);
  int* indptr = (int*)alloc((size_t)(N_NODES + 1) * 4);
  int* epos = (int*)alloc((size_t)N_NODES * 4);
  int* esrc = (int*)alloc((size_t)EP * 4);
  float* hbuf = (float*)alloc((size_t)N_NODES * 256 * 4);
  float* as_ = (float*)alloc((size_t)N_NODES * 4 * 4);
  float* ad_ = (float*)alloc((size_t)N_NODES * 4 * 4);
  float* tbuf = (float*)alloc((size_t)N_NODES * 64 * 4);
  float* xa = (float*)alloc((size_t)N_NODES * 64 * 4);
  float* xb = (float*)alloc((size_t)N_NODES * 64 * 4);
  float* part = (float*)alloc((size_t)256 * 128 * 4);
  float* scale = (float*)alloc(64 * 4);
  float* shift = (float*)alloc(64 * 4);
  float* pool = (float*)alloc((size_t)NG * 32 * 4);
  float* cntg = (float*)alloc((size_t)NG * 4);
  if (off > ws_size) return;  // workspace too small — fail loudly via poison

  hipMemsetAsync(cnt, 0, (size_t)N_NODES * 4, stream);
  hipMemsetAsync(epos, 0, (size_t)N_NODES * 4, stream);
  hipMemsetAsync(pool, 0, (size_t)NG * 32 * 4, stream);
  hipMemsetAsync(cntg, 0, (size_t)NG * 4, stream);

  k_count<<<cdiv(EP, 256), 256, 0, stream>>>(ei, cnt);
  k_scan<<<1, 1024, 0, stream>>>(cnt, indptr);
  k_scatter<<<cdiv(EP, 256), 256, 0, stream>>>(ei, indptr, epos, esrc);

  // ---- layer 1: 8 -> 64, D=64 ----
  k_lin<8, 256, 8><<<cdiv(N_NODES, 8), 256, 0, stream>>>(x, W1, hbuf);
  k_alpha<64><<<cdiv(N_NODES * 4, 256), 256, 0, stream>>>(hbuf, aS1, aD1, as_, ad_);
  k_agg<64><<<cdiv(N_NODES, 4), 256, 0, stream>>>(indptr, esrc, hbuf, (const float4*)as_,
                                                  (const float4*)ad_, b1, tbuf);
  k_bnstat<64><<<256, 256, 0, stream>>>(tbuf, part);
  k_bnfinal<64><<<1, 64, 0, stream>>>(part, g1, be1, scale, shift);
  k_bnapply<64><<<cdiv(N_NODES * 64, 256), 256, 0, stream>>>(tbuf, scale, shift, xa);

  // ---- layer 2: 64 -> 64, D=64 ----
  k_lin<64, 256, 8><<<cdiv(N_NODES, 8), 256, 0, stream>>>(xa, W2, hbuf);
  k_alpha<64><<<cdiv(N_NODES * 4, 256), 256, 0, stream>>>(hbuf, aS2, aD2, as_, ad_);
  k_agg<64><<<cdiv(N_NODES, 4), 256, 0, stream>>>(indptr, esrc, hbuf, (const float4*)as_,
                                                  (const float4*)ad_, b2, tbuf);
  k_bnstat<64><<<256, 256, 0, stream>>>(tbuf, part);
  k_bnfinal<64><<<1, 64, 0, stream>>>(part, g2, be2, scale, shift);
  k_bnapply<64><<<cdiv(N_NODES * 64, 256), 256, 0, stream>>>(tbuf, scale, shift, xb);

  // ---- layer 3: 64 -> 32, D=32 ----
  k_lin<64, 128, 8><<<cdiv(N_NODES, 8), 256, 0, stream>>>(xb, W3, hbuf);
  k_alpha<32><<<cdiv(N_NODES * 4, 256), 256, 0, stream>>>(hbuf, aS3, aD3, as_, ad_);
  k_agg<32><<<cdiv(N_NODES, 4), 256, 0, stream>>>(indptr, esrc, hbuf, (const float4*)as_,
                                                  (const float4*)ad_, b3, tbuf);
  k_bnstat<32><<<256, 256, 0, stream>>>(tbuf, part);
  k_bnfinal<32><<<1, 32, 0, stream>>>(part, g3, be3, scale, shift);
  k_bnapply<32><<<cdiv(N_NODES * 32, 256), 256, 0, stream>>>(tbuf, scale, shift, xa);

  // ---- pool + MLP ----
  k_pool<<<cdiv(N_NODES * 32, 256), 256, 0, stream>>>(xa, batch, pool, cntg);
  k_mlp<<<1, 64, 0, stream>>>(pool, cntg, Wp1, bp1, Wp2, bp2, out);
}

// Round 2
// 1410.653 us; speedup vs baseline: 1.6493x; 1.6493x over previous
//
#include <hip/hip_runtime.h>

#define N_NODES 100000
#define N_EDGES 1600000
#define EP (N_EDGES + N_NODES)
#define NG 64
#define NH 4
#define SCAN_CHUNK 512
#define POOL_NPB 2048

static inline int cdiv(int a, int b) { return (a + b - 1) / b; }

__device__ __forceinline__ float lrelu(float x) { return x >= 0.f ? x : 0.2f * x; }

__device__ __forceinline__ float wredmax(float v) {
#pragma unroll
  for (int off = 32; off; off >>= 1) v = fmaxf(v, __shfl_xor(v, off));
  return v;
}
__device__ __forceinline__ float wredsum(float v) {
#pragma unroll
  for (int off = 32; off; off >>= 1) v += __shfl_xor(v, off);
  return v;
}

// ---------------- CSR build ----------------
__global__ void k_count(const int* __restrict__ ei, int* __restrict__ cnt) {
  int e = blockIdx.x * blockDim.x + threadIdx.x;
  if (e < N_EDGES) atomicAdd(&cnt[ei[N_EDGES + e]], 1);
  else if (e < EP) atomicAdd(&cnt[e - N_EDGES], 1);  // self loop
}

// 3-phase parallel scan: per-block reduce -> scan block sums -> local scan + offset
__global__ __launch_bounds__(512) void k_scan_partial(const int* __restrict__ cnt,
                                                      int* __restrict__ bsum) {
  __shared__ int sh[SCAN_CHUNK];
  int t = threadIdx.x;
  int idx = blockIdx.x * SCAN_CHUNK + t;
  sh[t] = (idx < N_NODES) ? cnt[idx] : 0;
  __syncthreads();
  for (int s = SCAN_CHUNK / 2; s; s >>= 1) {
    if (t < s) sh[t] += sh[t + s];
    __syncthreads();
  }
  if (t == 0) bsum[blockIdx.x] = sh[0];
}

__global__ void k_scan_bsum(int* __restrict__ bsum, int nb) {
  __shared__ int sh[256];
  int t = threadIdx.x;
  int v = (t < nb) ? bsum[t] : 0;
  sh[t] = v;
  __syncthreads();
  for (int off = 1; off < 256; off <<= 1) {
    int add = (t >= off) ? sh[t - off] : 0;
    __syncthreads();
    sh[t] += add;
    __syncthreads();
  }
  if (t < nb) bsum[t] = sh[t] - v;  // exclusive
}

__global__ __launch_bounds__(512) void k_scan_final(const int* __restrict__ cnt,
                                                    const int* __restrict__ bsum,
                                                    int* __restrict__ indptr) {
  __shared__ int sh[SCAN_CHUNK];
  int t = threadIdx.x;
  int idx = blockIdx.x * SCAN_CHUNK + t;
  sh[t] = (idx < N_NODES) ? cnt[idx] : 0;
  __syncthreads();
  for (int off = 1; off < SCAN_CHUNK; off <<= 1) {
    int add = (t >= off) ? sh[t - off] : 0;
    __syncthreads();
    sh[t] += add;
    __syncthreads();
  }
  if (idx < N_NODES) indptr[idx + 1] = bsum[blockIdx.x] + sh[t];
  if (idx == 0) indptr[0] = 0;
}

__global__ void k_scatter(const int* __restrict__ ei, const int* __restrict__ indptr,
                          int* __restrict__ epos, int* __restrict__ esrc) {
  int e = blockIdx.x * blockDim.x + threadIdx.x;
  if (e < N_EDGES) {
    int d = ei[N_EDGES + e], s = ei[e];
    int p = atomicAdd(&epos[d], 1);
    esrc[indptr[d] + p] = s;
  } else if (e < EP) {
    int nn = e - N_EDGES;
    int p = atomicAdd(&epos[nn], 1);
    esrc[indptr[nn] + p] = nn;
  }
}

// ---------------- h = x @ W ----------------
template <int FIN, int HD, int NPB>
__global__ __launch_bounds__(256) void k_lin(const float* __restrict__ x, const float* __restrict__ W,
                                             float* __restrict__ hout) {
  __shared__ float xs[NPB][FIN];
  int n0 = blockIdx.x * NPB;
  int t = threadIdx.x;
  for (int i = t; i < NPB * FIN; i += 256) {
    int nd = i / FIN, f = i - nd * FIN;
    int n = n0 + nd;
    xs[nd][f] = (n < N_NODES) ? x[(size_t)n * FIN + f] : 0.f;
  }
  __syncthreads();
  for (int col = t; col < HD; col += 256) {
    float acc[NPB];
#pragma unroll
    for (int nd = 0; nd < NPB; nd++) acc[nd] = 0.f;
    for (int i = 0; i < FIN; i++) {
      float w = W[i * HD + col];
#pragma unroll
      for (int nd = 0; nd < NPB; nd++) acc[nd] = fmaf(xs[nd][i], w, acc[nd]);
    }
#pragma unroll
    for (int nd = 0; nd < NPB; nd++) {
      int n = n0 + nd;
      if (n < N_NODES) hout[(size_t)n * HD + col] = acc[nd];
    }
  }
}

// ---------------- per-node attention dots ----------------
template <int D>
__global__ void k_alpha(const float* __restrict__ h, const float* __restrict__ aS,
                        const float* __restrict__ aD, float* __restrict__ as_,
                        float* __restrict__ ad_) {
  int i = blockIdx.x * blockDim.x + threadIdx.x;
  if (i >= N_NODES * NH) return;
  int n = i >> 2, hh = i & 3;
  const float* hr = h + (size_t)n * (NH * D) + hh * D;
  const float* sa = aS + hh * D;
  const float* da = aD + hh * D;
  float vs = 0.f, vd = 0.f;
#pragma unroll 8
  for (int k = 0; k < D; k++) {
    float hv = hr[k];
    vs = fmaf(hv, sa[k], vs);
    vd = fmaf(hv, da[k], vd);
  }
  as_[i] = vs;
  ad_[i] = vd;
}

// ---------------- softmax + gather-aggregate (wave per node) ----------------
template <int D>
__global__ __launch_bounds__(256) void k_agg(const int* __restrict__ indptr, const int* __restrict__ esrc,
                                             const float* __restrict__ h, const float4* __restrict__ as4,
                                             const float4* __restrict__ ad4, const float* __restrict__ bias,
                                             float* __restrict__ tout) {
  int lane = threadIdx.x & 63;
  int n = blockIdx.x * 4 + (threadIdx.x >> 6);
  if (n >= N_NODES) return;
  int e0 = indptr[n], e1 = indptr[n + 1];
  float4 ad = ad4[n];
  // pass 1: per-head max
  float m0 = -3.4e38f, m1 = m0, m2 = m0, m3 = m0;
  for (int i = e0 + lane; i < e1; i += 64) {
    float4 av = as4[esrc[i]];
    m0 = fmaxf(m0, lrelu(av.x + ad.x));
    m1 = fmaxf(m1, lrelu(av.y + ad.y));
    m2 = fmaxf(m2, lrelu(av.z + ad.z));
    m3 = fmaxf(m3, lrelu(av.w + ad.w));
  }
  m0 = wredmax(m0); m1 = wredmax(m1); m2 = wredmax(m2); m3 = wredmax(m3);
  // pass 2: sum of exps
  float s0 = 0.f, s1 = 0.f, s2 = 0.f, s3 = 0.f;
  for (int i = e0 + lane; i < e1; i += 64) {
    float4 av = as4[esrc[i]];
    s0 += __expf(lrelu(av.x + ad.x) - m0);
    s1 += __expf(lrelu(av.y + ad.y) - m1);
    s2 += __expf(lrelu(av.z + ad.z) - m2);
    s3 += __expf(lrelu(av.w + ad.w) - m3);
  }
  s0 = wredsum(s0); s1 = wredsum(s1); s2 = wredsum(s2); s3 = wredsum(s3);
  float r0 = 1.f / (s0 + 1e-16f), r1 = 1.f / (s1 + 1e-16f);
  float r2 = 1.f / (s2 + 1e-16f), r3 = 1.f / (s3 + 1e-16f);
  // pass 3: weighted gather
  if constexpr (D == 64) {
    float a0 = 0.f, a1 = 0.f, a2 = 0.f, a3 = 0.f;
    for (int i = e0; i < e1; i++) {
      int s = esrc[i];
      float4 av = as4[s];
      float w0 = __expf(lrelu(av.x + ad.x) - m0) * r0;
      float w1 = __expf(lrelu(av.y + ad.y) - m1) * r1;
      float w2 = __expf(lrelu(av.z + ad.z) - m2) * r2;
      float w3 = __expf(lrelu(av.w + ad.w) - m3) * r3;
      const float* hr = h + (size_t)s * 256;
      a0 = fmaf(w0, hr[lane], a0);
      a1 = fmaf(w1, hr[64 + lane], a1);
      a2 = fmaf(w2, hr[128 + lane], a2);
      a3 = fmaf(w3, hr[192 + lane], a3);
    }
    float v = (a0 + a1 + a2 + a3) * 0.25f + bias[lane];
    tout[(size_t)n * 64 + lane] = fmaxf(v, 0.f);  // fused ReLU
  } else {
    // D == 32: lanes 0..31 handle heads 0,1; lanes 32..63 handle heads 2,3
    int d = lane & 31, hi = lane >> 5;
    float a0 = 0.f, a1 = 0.f;
    for (int i = e0; i < e1; i++) {
      int s = esrc[i];
      float4 av = as4[s];
      float w0 = __expf(lrelu(av.x + ad.x) - m0) * r0;
      float w1 = __expf(lrelu(av.y + ad.y) - m1) * r1;
      float w2 = __expf(lrelu(av.z + ad.z) - m2) * r2;
      float w3 = __expf(lrelu(av.w + ad.w) - m3) * r3;
      float wa = hi ? w2 : w0;
      float wb = hi ? w3 : w1;
      const float* hr = h + (size_t)s * 128 + hi * 64 + d;
      a0 = fmaf(wa, hr[0], a0);
      a1 = fmaf(wb, hr[32], a1);
    }
    float v = a0 + a1;
    v += __shfl_xor(v, 32);
    if (lane < 32) tout[(size_t)n * 32 + d] = fmaxf(v * 0.25f + bias[d], 0.f);
  }
}

// ---------------- batch norm ----------------
template <int C>
__global__ __launch_bounds__(256) void k_bnstat(const float* __restrict__ x, float* __restrict__ part) {
  const int RG = 256 / C;
  int col = threadIdx.x & (C - 1);
  int rg = threadIdx.x / C;
  int rows = (N_NODES + gridDim.x - 1) / gridDim.x;
  int r0 = blockIdx.x * rows;
  int r1 = min(N_NODES, r0 + rows);
  float s = 0.f, q = 0.f;
  for (int r = r0 + rg; r < r1; r += RG) {
    float v = x[(size_t)r * C + col];
    s += v;
    q = fmaf(v, v, q);
  }
  __shared__ float sh[512];
  sh[threadIdx.x] = s;
  sh[256 + threadIdx.x] = q;
  __syncthreads();
  for (int step = 128; step >= C; step >>= 1) {
    if (threadIdx.x < step) {
      sh[threadIdx.x] += sh[threadIdx.x + step];
      sh[256 + threadIdx.x] += sh[256 + threadIdx.x + step];
    }
    __syncthreads();
  }
  if (threadIdx.x < C) {
    part[blockIdx.x * 2 * C + threadIdx.x] = sh[threadIdx.x];
    part[blockIdx.x * 2 * C + C + threadIdx.x] = sh[256 + threadIdx.x];
  }
}

template <int C>
__global__ void k_bnfinal(const float* __restrict__ part, const float* __restrict__ g,
                          const float* __restrict__ be, float* __restrict__ scale,
                          float* __restrict__ shift) {
  int c = threadIdx.x;
  if (c >= C) return;
  float s = 0.f, q = 0.f;
  for (int b = 0; b < 256; b++) {
    s += part[b * 2 * C + c];
    q += part[b * 2 * C + C + c];
  }
  float mean = s / (float)N_NODES;
  float var = q / (float)N_NODES - mean * mean;
  float sc = g[c] * rsqrtf(var + 1e-5f);
  scale[c] = sc;
  shift[c] = be[c] - mean * sc;
}

template <int C>
__global__ void k_bnapply(const float* __restrict__ t, const float* __restrict__ scale,
                          const float* __restrict__ shift, float* __restrict__ y) {
  int i = blockIdx.x * blockDim.x + threadIdx.x;
  if (i >= N_NODES * C) return;
  int c = i & (C - 1);
  y[i] = fmaf(t[i], scale[c], shift[c]);
}

// ---------------- pooling (batch is sorted -> block-local LDS accumulation) ----------------
__global__ __launch_bounds__(256) void k_pool(const float* __restrict__ f3,
                                              const int* __restrict__ batch,
                                              float* __restrict__ pool,
                                              float* __restrict__ cntg) {
  __shared__ float acc[NG][33];  // [graph][col 0..31 + count at 32]
  int t = threadIdx.x;
  for (int i = t; i < NG * 33; i += 256) ((float*)acc)[i] = 0.f;
  __syncthreads();
  int c = t & 31, rg = t >> 5;  // 8 row groups
  int n0 = blockIdx.x * POOL_NPB;
  int n1 = min(N_NODES, n0 + POOL_NPB);
  float r = 0.f, rc = 0.f;
  int gcur = -1;
  for (int n = n0 + rg; n < n1; n += 8) {
    int g = batch[n];
    if (g != gcur) {
      if (gcur >= 0) {
        atomicAdd(&acc[gcur][c], r);
        if (c == 0) atomicAdd(&acc[gcur][32], rc);
      }
      gcur = g;
      r = 0.f;
      rc = 0.f;
    }
    r += f3[(size_t)n * 32 + c];
    rc += 1.f;
  }
  if (gcur >= 0) {
    atomicAdd(&acc[gcur][c], r);
    if (c == 0) atomicAdd(&acc[gcur][32], rc);
  }
  __syncthreads();
  for (int i = t; i < NG * 32; i += 256) {
    int g = i >> 5, cc = i & 31;
    float v = acc[g][cc];
    if (v != 0.f) atomicAdd(&pool[i], v);
  }
  for (int g = t; g < NG; g += 256) {
    float v = acc[g][32];
    if (v != 0.f) atomicAdd(&cntg[g], v);
  }
}

__global__ void k_mlp(const float* __restrict__ pool, const float* __restrict__ cntg,
                      const float* __restrict__ Wp1, const float* __restrict__ bp1,
                      const float* __restrict__ Wp2, const float* __restrict__ bp2,
                      float* __restrict__ out) {
  int g = threadIdx.x;
  if (g >= NG) return;
  float inv = 1.f / fmaxf(cntg[g], 1.f);
  float p[32];
#pragma unroll
  for (int c = 0; c < 32; c++) p[c] = pool[g * 32 + c] * inv;
  float o = bp2[0];
  for (int j = 0; j < 16; j++) {
    float hsum = bp1[j];
#pragma unroll
    for (int c = 0; c < 32; c++) hsum = fmaf(p[c], Wp1[c * 16 + j], hsum);
    o = fmaf(fmaxf(hsum, 0.f), Wp2[j], o);
  }
  out[g] = o;
}

extern "C" void kernel_launch(void* const* d_in, const int* in_sizes, int n_in,
                              void* d_out, int out_size, void* d_ws, size_t ws_size,
                              hipStream_t stream) {
  const float* x = (const float*)d_in[0];
  const int* ei = (const int*)d_in[1];
  const int* batch = (const int*)d_in[2];
  const float* W1 = (const float*)d_in[3];
  const float* aS1 = (const float*)d_in[4];
  const float* aD1 = (const float*)d_in[5];
  const float* b1 = (const float*)d_in[6];
  const float* g1 = (const float*)d_in[7];
  const float* be1 = (const float*)d_in[8];
  const float* W2 = (const float*)d_in[9];
  const float* aS2 = (const float*)d_in[10];
  const float* aD2 = (const float*)d_in[11];
  const float* b2 = (const float*)d_in[12];
  const float* g2 = (const float*)d_in[13];
  const float* be2 = (const float*)d_in[14];
  const float* W3 = (const float*)d_in[15];
  const float* aS3 = (const float*)d_in[16];
  const float* aD3 = (const float*)d_in[17];
  const float* b3 = (const float*)d_in[18];
  const float* g3 = (const float*)d_in[19];
  const float* be3 = (const float*)d_in[20];
  const float* Wp1 = (const float*)d_in[21];
  const float* bp1 = (const float*)d_in[22];
  const float* Wp2 = (const float*)d_in[23];
  const float* bp2 = (const float*)d_in[24];
  float* out = (float*)d_out;

  size_t off = 0;
  auto alloc = [&](size_t bytes) -> void* {
    void* p = (char*)d_ws + off;
    off += (bytes + 255) & ~(size_t)255;
    return p;
  };
  int* cnt = (int*)alloc((size_t)N_NODES * 4);
  int* indptr = (int*)alloc((size_t)(N_NODES + 1) * 4);
  int* epos = (int*)alloc((size_t)N_NODES * 4);
  int* esrc = (int*)alloc((size_t)EP * 4);
  int* bsum = (int*)alloc((size_t)256 * 4);
  float* hbuf = (float*)alloc((size_t)N_NODES * 256 * 4);
  float* as_ = (float*)alloc((size_t)N_NODES * 4 * 4);
  float* ad_ = (float*)alloc((size_t)N_NODES * 4 * 4);
  float* tbuf = (float*)alloc((size_t)N_NODES * 64 * 4);
  float* xa = (float*)alloc((size_t)N_NODES * 64 * 4);
  float* xb = (float*)alloc((size_t)N_NODES * 64 * 4);
  float* part = (float*)alloc((size_t)256 * 128 * 4);
  float* scale = (float*)alloc(64 * 4);
  float* shift = (float*)alloc(64 * 4);
  float* pool = (float*)alloc((size_t)NG * 32 * 4);
  float* cntg = (float*)alloc((size_t)NG * 4);
  if (off > ws_size) return;

  hipMemsetAsync(cnt, 0, (size_t)N_NODES * 4, stream);
  hipMemsetAsync(epos, 0, (size_t)N_NODES * 4, stream);
  hipMemsetAsync(pool, 0, (size_t)NG * 32 * 4, stream);
  hipMemsetAsync(cntg, 0, (size_t)NG * 4, stream);

  int nscan = cdiv(N_NODES, SCAN_CHUNK);  // 196
  k_count<<<cdiv(EP, 256), 256, 0, stream>>>(ei, cnt);
  k_scan_partial<<<nscan, SCAN_CHUNK, 0, stream>>>(cnt, bsum);
  k_scan_bsum<<<1, 256, 0, stream>>>(bsum, nscan);
  k_scan_final<<<nscan, SCAN_CHUNK, 0, stream>>>(cnt, bsum, indptr);
  k_scatter<<<cdiv(EP, 256), 256, 0, stream>>>(ei, indptr, epos, esrc);

  // ---- layer 1: 8 -> 64, D=64 ----
  k_lin<8, 256, 8><<<cdiv(N_NODES, 8), 256, 0, stream>>>(x, W1, hbuf);
  k_alpha<64><<<cdiv(N_NODES * 4, 256), 256, 0, stream>>>(hbuf, aS1, aD1, as_, ad_);
  k_agg<64><<<cdiv(N_NODES, 4), 256, 0, stream>>>(indptr, esrc, hbuf, (const float4*)as_,
                                                  (const float4*)ad_, b1, tbuf);
  k_bnstat<64><<<256, 256, 0, stream>>>(tbuf, part);
  k_bnfinal<64><<<1, 64, 0, stream>>>(part, g1, be1, scale, shift);
  k_bnapply<64><<<cdiv(N_NODES * 64, 256), 256, 0, stream>>>(tbuf, scale, shift, xa);

  // ---- layer 2: 64 -> 64, D=64 ----
  k_lin<64, 256, 8><<<cdiv(N_NODES, 8), 256, 0, stream>>>(xa, W2, hbuf);
  k_alpha<64><<<cdiv(N_NODES * 4, 256), 256, 0, stream>>>(hbuf, aS2, aD2, as_, ad_);
  k_agg<64><<<cdiv(N_NODES, 4), 256, 0, stream>>>(indptr, esrc, hbuf, (const float4*)as_,
                                                  (const float4*)ad_, b2, tbuf);
  k_bnstat<64><<<256, 256, 0, stream>>>(tbuf, part);
  k_bnfinal<64><<<1, 64, 0, stream>>>(part, g2, be2, scale, shift);
  k_bnapply<64><<<cdiv(N_NODES * 64, 256), 256, 0, stream>>>(tbuf, scale, shift, xb);

  // ---- layer 3: 64 -> 32, D=32 ----
  k_lin<64, 128, 8><<<cdiv(N_NODES, 8), 256, 0, stream>>>(xb, W3, hbuf);
  k_alpha<32><<<cdiv(N_NODES * 4, 256), 256, 0, stream>>>(hbuf, aS3, aD3, as_, ad_);
  k_agg<32><<<cdiv(N_NODES, 4), 256, 0, stream>>>(indptr, esrc, hbuf, (const float4*)as_,
                                                  (const float4*)ad_, b3, tbuf);
  k_bnstat<32><<<256, 256, 0, stream>>>(tbuf, part);
  k_bnfinal<32><<<1, 32, 0, stream>>>(part, g3, be3, scale, shift);
  k_bnapply<32><<<cdiv(N_NODES * 32, 256), 256, 0, stream>>>(tbuf, scale, shift, xa);

  // ---- pool + MLP ----
  k_pool<<<cdiv(N_NODES, POOL_NPB), 256, 0, stream>>>(xa, batch, pool, cntg);
  k_mlp<<<1, 64, 0, stream>>>(pool, cntg, Wp1, bp1, Wp2, bp2, out);
}

// Round 3
// 1342.665 us; speedup vs baseline: 1.7328x; 1.0506x over previous
//
#include <hip/hip_runtime.h>

#define N_NODES 100000
#define N_EDGES 1600000
#define EP (N_EDGES + N_NODES)
#define NG 64
#define NH 4
#define SCAN_CHUNK 512
#define POOL_NPB 2048

static inline int cdiv(int a, int b) { return (a + b - 1) / b; }

__device__ __forceinline__ float lrelu(float x) { return x >= 0.f ? x : 0.2f * x; }

__device__ __forceinline__ float wredmax(float v) {
#pragma unroll
  for (int off = 32; off; off >>= 1) v = fmaxf(v, __shfl_xor(v, off));
  return v;
}
__device__ __forceinline__ float wredsum(float v) {
#pragma unroll
  for (int off = 32; off; off >>= 1) v += __shfl_xor(v, off);
  return v;
}

// ---------------- CSR build ----------------
__global__ void k_count(const int* __restrict__ ei, int* __restrict__ cnt) {
  int e = blockIdx.x * blockDim.x + threadIdx.x;
  if (e < N_EDGES) atomicAdd(&cnt[ei[N_EDGES + e]], 1);
  else if (e < EP) atomicAdd(&cnt[e - N_EDGES], 1);  // self loop
}

__global__ __launch_bounds__(512) void k_scan_partial(const int* __restrict__ cnt,
                                                      int* __restrict__ bsum) {
  __shared__ int sh[SCAN_CHUNK];
  int t = threadIdx.x;
  int idx = blockIdx.x * SCAN_CHUNK + t;
  sh[t] = (idx < N_NODES) ? cnt[idx] : 0;
  __syncthreads();
  for (int s = SCAN_CHUNK / 2; s; s >>= 1) {
    if (t < s) sh[t] += sh[t + s];
    __syncthreads();
  }
  if (t == 0) bsum[blockIdx.x] = sh[0];
}

__global__ void k_scan_bsum(int* __restrict__ bsum, int nb) {
  __shared__ int sh[256];
  int t = threadIdx.x;
  int v = (t < nb) ? bsum[t] : 0;
  sh[t] = v;
  __syncthreads();
  for (int off = 1; off < 256; off <<= 1) {
    int add = (t >= off) ? sh[t - off] : 0;
    __syncthreads();
    sh[t] += add;
    __syncthreads();
  }
  if (t < nb) bsum[t] = sh[t] - v;  // exclusive
}

__global__ __launch_bounds__(512) void k_scan_final(const int* __restrict__ cnt,
                                                    const int* __restrict__ bsum,
                                                    int* __restrict__ indptr) {
  __shared__ int sh[SCAN_CHUNK];
  int t = threadIdx.x;
  int idx = blockIdx.x * SCAN_CHUNK + t;
  sh[t] = (idx < N_NODES) ? cnt[idx] : 0;
  __syncthreads();
  for (int off = 1; off < SCAN_CHUNK; off <<= 1) {
    int add = (t >= off) ? sh[t - off] : 0;
    __syncthreads();
    sh[t] += add;
    __syncthreads();
  }
  if (idx < N_NODES) indptr[idx + 1] = bsum[blockIdx.x] + sh[t];
  if (idx == 0) indptr[0] = 0;
}

__global__ void k_scatter(const int* __restrict__ ei, const int* __restrict__ indptr,
                          int* __restrict__ epos, int* __restrict__ esrc) {
  int e = blockIdx.x * blockDim.x + threadIdx.x;
  if (e < N_EDGES) {
    int d = ei[N_EDGES + e], s = ei[e];
    int p = atomicAdd(&epos[d], 1);
    esrc[indptr[d] + p] = s;
  } else if (e < EP) {
    int nn = e - N_EDGES;
    int p = atomicAdd(&epos[nn], 1);
    esrc[indptr[nn] + p] = nn;
  }
}

// ---------------- h = BN(x) @ W (scale/shift fused on load; null => identity) ----------------
template <int FIN, int HD, int NPB>
__global__ __launch_bounds__(256) void k_lin(const float* __restrict__ x, const float* __restrict__ W,
                                             const float* __restrict__ scale,
                                             const float* __restrict__ shift,
                                             float* __restrict__ hout) {
  __shared__ float xs[NPB][FIN];
  int n0 = blockIdx.x * NPB;
  int t = threadIdx.x;
  for (int i = t; i < NPB * FIN; i += 256) {
    int nd = i / FIN, f = i - nd * FIN;
    int n = n0 + nd;
    float v = (n < N_NODES) ? x[(size_t)n * FIN + f] : 0.f;
    if (scale) v = fmaf(v, scale[f], shift[f]);
    xs[nd][f] = v;
  }
  __syncthreads();
  for (int col = t; col < HD; col += 256) {
    float acc[NPB];
#pragma unroll
    for (int nd = 0; nd < NPB; nd++) acc[nd] = 0.f;
    for (int i = 0; i < FIN; i++) {
      float w = W[i * HD + col];
#pragma unroll
      for (int nd = 0; nd < NPB; nd++) acc[nd] = fmaf(xs[nd][i], w, acc[nd]);
    }
#pragma unroll
    for (int nd = 0; nd < NPB; nd++) {
      int n = n0 + nd;
      if (n < N_NODES) hout[(size_t)n * HD + col] = acc[nd];
    }
  }
}

// ---------------- per-node attention dots ----------------
template <int D>
__global__ void k_alpha(const float* __restrict__ h, const float* __restrict__ aS,
                        const float* __restrict__ aD, float* __restrict__ as_,
                        float* __restrict__ ad_) {
  int i = blockIdx.x * blockDim.x + threadIdx.x;
  if (i >= N_NODES * NH) return;
  int n = i >> 2, hh = i & 3;
  const float* hr = h + (size_t)n * (NH * D) + hh * D;
  const float* sa = aS + hh * D;
  const float* da = aD + hh * D;
  float vs = 0.f, vd = 0.f;
#pragma unroll 8
  for (int k = 0; k < D; k++) {
    float hv = hr[k];
    vs = fmaf(hv, sa[k], vs);
    vd = fmaf(hv, da[k], vd);
  }
  as_[i] = vs;
  ad_[i] = vd;
}

// ---------------- per-edge softmax weights (unnormalized) + per-node reciprocal ----------------
__global__ __launch_bounds__(256) void k_weights(const int* __restrict__ indptr,
                                                 const int* __restrict__ esrc,
                                                 const float4* __restrict__ as4,
                                                 const float4* __restrict__ ad4,
                                                 float4* __restrict__ w4,
                                                 float4* __restrict__ rnorm4) {
  int lane = threadIdx.x & 63;
  int n = blockIdx.x * 4 + (threadIdx.x >> 6);
  if (n >= N_NODES) return;
  int e0 = indptr[n], e1 = indptr[n + 1];
  float4 ad = ad4[n];
  float m0 = -3.4e38f, m1 = m0, m2 = m0, m3 = m0;
  for (int i = e0 + lane; i < e1; i += 64) {
    float4 av = as4[esrc[i]];
    m0 = fmaxf(m0, lrelu(av.x + ad.x));
    m1 = fmaxf(m1, lrelu(av.y + ad.y));
    m2 = fmaxf(m2, lrelu(av.z + ad.z));
    m3 = fmaxf(m3, lrelu(av.w + ad.w));
  }
  m0 = wredmax(m0); m1 = wredmax(m1); m2 = wredmax(m2); m3 = wredmax(m3);
  float s0 = 0.f, s1 = 0.f, s2 = 0.f, s3 = 0.f;
  for (int i = e0 + lane; i < e1; i += 64) {
    float4 av = as4[esrc[i]];
    float e0v = __expf(lrelu(av.x + ad.x) - m0);
    float e1v = __expf(lrelu(av.y + ad.y) - m1);
    float e2v = __expf(lrelu(av.z + ad.z) - m2);
    float e3v = __expf(lrelu(av.w + ad.w) - m3);
    s0 += e0v; s1 += e1v; s2 += e2v; s3 += e3v;
    w4[i] = make_float4(e0v, e1v, e2v, e3v);
  }
  s0 = wredsum(s0); s1 = wredsum(s1); s2 = wredsum(s2); s3 = wredsum(s3);
  if (lane == 0)
    rnorm4[n] = make_float4(1.f / (s0 + 1e-16f), 1.f / (s1 + 1e-16f),
                            1.f / (s2 + 1e-16f), 1.f / (s3 + 1e-16f));
}

// ---------------- weighted gather-aggregate (wave per node, weights precomputed) ----------------
template <int D>
__global__ __launch_bounds__(256) void k_agg(const int* __restrict__ indptr, const int* __restrict__ esrc,
                                             const float* __restrict__ h, const float4* __restrict__ w4,
                                             const float4* __restrict__ rnorm4,
                                             const float* __restrict__ bias,
                                             float* __restrict__ tout) {
  int lane = threadIdx.x & 63;
  int n = blockIdx.x * 4 + (threadIdx.x >> 6);
  if (n >= N_NODES) return;
  int e0 = indptr[n], e1 = indptr[n + 1];
  if constexpr (D == 64) {
    float a0 = 0.f, a1 = 0.f, a2 = 0.f, a3 = 0.f;
#pragma unroll 2
    for (int i = e0; i < e1; i++) {
      int s = esrc[i];
      float4 w = w4[i];
      const float* hr = h + (size_t)s * 256;
      a0 = fmaf(w.x, hr[lane], a0);
      a1 = fmaf(w.y, hr[64 + lane], a1);
      a2 = fmaf(w.z, hr[128 + lane], a2);
      a3 = fmaf(w.w, hr[192 + lane], a3);
    }
    float4 r = rnorm4[n];
    float v = (a0 * r.x + a1 * r.y + a2 * r.z + a3 * r.w) * 0.25f + bias[lane];
    tout[(size_t)n * 64 + lane] = fmaxf(v, 0.f);  // fused ReLU
  } else {
    int d = lane & 31, hi = lane >> 5;
    float a0 = 0.f, a1 = 0.f;
#pragma unroll 2
    for (int i = e0; i < e1; i++) {
      int s = esrc[i];
      float4 w = w4[i];
      float wa = hi ? w.z : w.x;
      float wb = hi ? w.w : w.y;
      const float* hr = h + (size_t)s * 128 + hi * 64 + d;
      a0 = fmaf(wa, hr[0], a0);
      a1 = fmaf(wb, hr[32], a1);
    }
    float4 r = rnorm4[n];
    float ra = hi ? r.z : r.x;
    float rb = hi ? r.w : r.y;
    float v = a0 * ra + a1 * rb;
    v += __shfl_xor(v, 32);
    if (lane < 32) tout[(size_t)n * 32 + d] = fmaxf(v * 0.25f + bias[d], 0.f);
  }
}

// ---------------- batch norm stats ----------------
template <int C>
__global__ __launch_bounds__(256) void k_bnstat(const float* __restrict__ x, float* __restrict__ part) {
  const int RG = 256 / C;
  int col = threadIdx.x & (C - 1);
  int rg = threadIdx.x / C;
  int rows = (N_NODES + gridDim.x - 1) / gridDim.x;
  int r0 = blockIdx.x * rows;
  int r1 = min(N_NODES, r0 + rows);
  float s = 0.f, q = 0.f;
  for (int r = r0 + rg; r < r1; r += RG) {
    float v = x[(size_t)r * C + col];
    s += v;
    q = fmaf(v, v, q);
  }
  __shared__ float sh[512];
  sh[threadIdx.x] = s;
  sh[256 + threadIdx.x] = q;
  __syncthreads();
  for (int step = 128; step >= C; step >>= 1) {
    if (threadIdx.x < step) {
      sh[threadIdx.x] += sh[threadIdx.x + step];
      sh[256 + threadIdx.x] += sh[256 + threadIdx.x + step];
    }
    __syncthreads();
  }
  if (threadIdx.x < C) {
    part[blockIdx.x * 2 * C + threadIdx.x] = sh[threadIdx.x];
    part[blockIdx.x * 2 * C + C + threadIdx.x] = sh[256 + threadIdx.x];
  }
}

template <int C>
__global__ void k_bnfinal(const float* __restrict__ part, const float* __restrict__ g,
                          const float* __restrict__ be, float* __restrict__ scale,
                          float* __restrict__ shift) {
  int c = threadIdx.x;
  if (c >= C) return;
  float s = 0.f, q = 0.f;
  for (int b = 0; b < 256; b++) {
    s += part[b * 2 * C + c];
    q += part[b * 2 * C + C + c];
  }
  float mean = s / (float)N_NODES;
  float var = q / (float)N_NODES - mean * mean;
  float sc = g[c] * rsqrtf(var + 1e-5f);
  scale[c] = sc;
  shift[c] = be[c] - mean * sc;
}

// ---------------- pooling (applies layer-3 BN on load; batch sorted) ----------------
__global__ __launch_bounds__(256) void k_pool(const float* __restrict__ f3,
                                              const int* __restrict__ batch,
                                              const float* __restrict__ scale,
                                              const float* __restrict__ shift,
                                              float* __restrict__ pool,
                                              float* __restrict__ cntg) {
  __shared__ float acc[NG][33];
  int t = threadIdx.x;
  for (int i = t; i < NG * 33; i += 256) ((float*)acc)[i] = 0.f;
  __syncthreads();
  int c = t & 31, rg = t >> 5;
  float sc = scale[c], sh = shift[c];
  int n0 = blockIdx.x * POOL_NPB;
  int n1 = min(N_NODES, n0 + POOL_NPB);
  float r = 0.f, rc = 0.f;
  int gcur = -1;
  for (int n = n0 + rg; n < n1; n += 8) {
    int g = batch[n];
    if (g != gcur) {
      if (gcur >= 0) {
        atomicAdd(&acc[gcur][c], r);
        if (c == 0) atomicAdd(&acc[gcur][32], rc);
      }
      gcur = g;
      r = 0.f;
      rc = 0.f;
    }
    r += fmaf(f3[(size_t)n * 32 + c], sc, sh);
    rc += 1.f;
  }
  if (gcur >= 0) {
    atomicAdd(&acc[gcur][c], r);
    if (c == 0) atomicAdd(&acc[gcur][32], rc);
  }
  __syncthreads();
  for (int i = t; i < NG * 32; i += 256) {
    int g = i >> 5, cc = i & 31;
    float v = acc[g][cc];
    if (v != 0.f) atomicAdd(&pool[i], v);
  }
  for (int g = t; g < NG; g += 256) {
    float v = acc[g][32];
    if (v != 0.f) atomicAdd(&cntg[g], v);
  }
}

__global__ void k_mlp(const float* __restrict__ pool, const float* __restrict__ cntg,
                      const float* __restrict__ Wp1, const float* __restrict__ bp1,
                      const float* __restrict__ Wp2, const float* __restrict__ bp2,
                      float* __restrict__ out) {
  int g = threadIdx.x;
  if (g >= NG) return;
  float inv = 1.f / fmaxf(cntg[g], 1.f);
  float p[32];
#pragma unroll
  for (int c = 0; c < 32; c++) p[c] = pool[g * 32 + c] * inv;
  float o = bp2[0];
  for (int j = 0; j < 16; j++) {
    float hsum = bp1[j];
#pragma unroll
    for (int c = 0; c < 32; c++) hsum = fmaf(p[c], Wp1[c * 16 + j], hsum);
    o = fmaf(fmaxf(hsum, 0.f), Wp2[j], o);
  }
  out[g] = o;
}

extern "C" void kernel_launch(void* const* d_in, const int* in_sizes, int n_in,
                              void* d_out, int out_size, void* d_ws, size_t ws_size,
                              hipStream_t stream) {
  const float* x = (const float*)d_in[0];
  const int* ei = (const int*)d_in[1];
  const int* batch = (const int*)d_in[2];
  const float* W1 = (const float*)d_in[3];
  const float* aS1 = (const float*)d_in[4];
  const float* aD1 = (const float*)d_in[5];
  const float* b1 = (const float*)d_in[6];
  const float* g1 = (const float*)d_in[7];
  const float* be1 = (const float*)d_in[8];
  const float* W2 = (const float*)d_in[9];
  const float* aS2 = (const float*)d_in[10];
  const float* aD2 = (const float*)d_in[11];
  const float* b2 = (const float*)d_in[12];
  const float* g2 = (const float*)d_in[13];
  const float* be2 = (const float*)d_in[14];
  const float* W3 = (const float*)d_in[15];
  const float* aS3 = (const float*)d_in[16];
  const float* aD3 = (const float*)d_in[17];
  const float* b3 = (const float*)d_in[18];
  const float* g3 = (const float*)d_in[19];
  const float* be3 = (const float*)d_in[20];
  const float* Wp1 = (const float*)d_in[21];
  const float* bp1 = (const float*)d_in[22];
  const float* Wp2 = (const float*)d_in[23];
  const float* bp2 = (const float*)d_in[24];
  float* out = (float*)d_out;

  size_t off = 0;
  auto alloc = [&](size_t bytes) -> void* {
    void* p = (char*)d_ws + off;
    off += (bytes + 255) & ~(size_t)255;
    return p;
  };
  int* cnt = (int*)alloc((size_t)N_NODES * 4);
  int* indptr = (int*)alloc((size_t)(N_NODES + 1) * 4);
  int* epos = (int*)alloc((size_t)N_NODES * 4);
  int* esrc = (int*)alloc((size_t)EP * 4);
  int* bsum = (int*)alloc((size_t)256 * 4);
  float* hbuf = (float*)alloc((size_t)N_NODES * 256 * 4);
  float* as_ = (float*)alloc((size_t)N_NODES * 4 * 4);
  float* ad_ = (float*)alloc((size_t)N_NODES * 4 * 4);
  float* w4 = (float*)alloc((size_t)EP * 16);
  float* rnorm = (float*)alloc((size_t)N_NODES * 16);
  float* tbuf = (float*)alloc((size_t)N_NODES * 64 * 4);
  float* part = (float*)alloc((size_t)256 * 128 * 4);
  float* scale = (float*)alloc(64 * 4);
  float* shift = (float*)alloc(64 * 4);
  float* pool = (float*)alloc((size_t)NG * 32 * 4);
  float* cntg = (float*)alloc((size_t)NG * 4);
  if (off > ws_size) return;

  hipMemsetAsync(cnt, 0, (size_t)N_NODES * 4, stream);
  hipMemsetAsync(epos, 0, (size_t)N_NODES * 4, stream);
  hipMemsetAsync(pool, 0, (size_t)NG * 32 * 4, stream);
  hipMemsetAsync(cntg, 0, (size_t)NG * 4, stream);

  int nscan = cdiv(N_NODES, SCAN_CHUNK);
  k_count<<<cdiv(EP, 256), 256, 0, stream>>>(ei, cnt);
  k_scan_partial<<<nscan, SCAN_CHUNK, 0, stream>>>(cnt, bsum);
  k_scan_bsum<<<1, 256, 0, stream>>>(bsum, nscan);
  k_scan_final<<<nscan, SCAN_CHUNK, 0, stream>>>(cnt, bsum, indptr);
  k_scatter<<<cdiv(EP, 256), 256, 0, stream>>>(ei, indptr, epos, esrc);

  int nblk = cdiv(N_NODES, 4);

  // ---- layer 1: 8 -> 64, D=64 ----
  k_lin<8, 256, 8><<<cdiv(N_NODES, 8), 256, 0, stream>>>(x, W1, nullptr, nullptr, hbuf);
  k_alpha<64><<<cdiv(N_NODES * 4, 256), 256, 0, stream>>>(hbuf, aS1, aD1, as_, ad_);
  k_weights<<<nblk, 256, 0, stream>>>(indptr, esrc, (const float4*)as_, (const float4*)ad_,
                                      (float4*)w4, (float4*)rnorm);
  k_agg<64><<<nblk, 256, 0, stream>>>(indptr, esrc, hbuf, (const float4*)w4,
                                      (const float4*)rnorm, b1, tbuf);
  k_bnstat<64><<<256, 256, 0, stream>>>(tbuf, part);
  k_bnfinal<64><<<1, 64, 0, stream>>>(part, g1, be1, scale, shift);

  // ---- layer 2: 64 -> 64, D=64 (BN1 applied on load) ----
  k_lin<64, 256, 8><<<cdiv(N_NODES, 8), 256, 0, stream>>>(tbuf, W2, scale, shift, hbuf);
  k_alpha<64><<<cdiv(N_NODES * 4, 256), 256, 0, stream>>>(hbuf, aS2, aD2, as_, ad_);
  k_weights<<<nblk, 256, 0, stream>>>(indptr, esrc, (const float4*)as_, (const float4*)ad_,
                                      (float4*)w4, (float4*)rnorm);
  k_agg<64><<<nblk, 256, 0, stream>>>(indptr, esrc, hbuf, (const float4*)w4,
                                      (const float4*)rnorm, b2, tbuf);
  k_bnstat<64><<<256, 256, 0, stream>>>(tbuf, part);
  k_bnfinal<64><<<1, 64, 0, stream>>>(part, g2, be2, scale, shift);

  // ---- layer 3: 64 -> 32, D=32 (BN2 applied on load) ----
  k_lin<64, 128, 8><<<cdiv(N_NODES, 8), 256, 0, stream>>>(tbuf, W3, scale, shift, hbuf);
  k_alpha<32><<<cdiv(N_NODES * 4, 256), 256, 0, stream>>>(hbuf, aS3, aD3, as_, ad_);
  k_weights<<<nblk, 256, 0, stream>>>(indptr, esrc, (const float4*)as_, (const float4*)ad_,
                                      (float4*)w4, (float4*)rnorm);
  k_agg<32><<<nblk, 256, 0, stream>>>(indptr, esrc, hbuf, (const float4*)w4,
                                      (const float4*)rnorm, b3, tbuf);
  k_bnstat<32><<<256, 256, 0, stream>>>(tbuf, part);
  k_bnfinal<32><<<1, 32, 0, stream>>>(part, g3, be3, scale, shift);

  // ---- pool (BN3 on load) + MLP ----
  k_pool<<<cdiv(N_NODES, POOL_NPB), 256, 0, stream>>>(tbuf, batch, scale, shift, pool, cntg);
  k_mlp<<<1, 64, 0, stream>>>(pool, cntg, Wp1, bp1, Wp2, bp2, out);
}

// Round 4
// 1232.679 us; speedup vs baseline: 1.8874x; 1.0892x over previous
//
#include <hip/hip_runtime.h>

#define N_NODES 100000
#define N_EDGES 1600000
#define EP (N_EDGES + N_NODES)
#define NG 64
#define NH 4
#define SCAN_CHUNK 512
#define POOL_NPB 2048

static inline int cdiv(int a, int b) { return (a + b - 1) / b; }

__device__ __forceinline__ float lrelu(float x) { return x >= 0.f ? x : 0.2f * x; }

__device__ __forceinline__ float wredsum(float v) {
#pragma unroll
  for (int off = 32; off; off >>= 1) v += __shfl_xor(v, off);
  return v;
}

// ---------------- CSR build ----------------
__global__ void k_count(const int* __restrict__ ei, int* __restrict__ cnt) {
  int e = blockIdx.x * blockDim.x + threadIdx.x;
  if (e < N_EDGES) atomicAdd(&cnt[ei[N_EDGES + e]], 1);
  else if (e < EP) atomicAdd(&cnt[e - N_EDGES], 1);  // self loop
}

__global__ __launch_bounds__(512) void k_scan_partial(const int* __restrict__ cnt,
                                                      int* __restrict__ bsum) {
  __shared__ int sh[SCAN_CHUNK];
  int t = threadIdx.x;
  int idx = blockIdx.x * SCAN_CHUNK + t;
  sh[t] = (idx < N_NODES) ? cnt[idx] : 0;
  __syncthreads();
  for (int s = SCAN_CHUNK / 2; s; s >>= 1) {
    if (t < s) sh[t] += sh[t + s];
    __syncthreads();
  }
  if (t == 0) bsum[blockIdx.x] = sh[0];
}

__global__ void k_scan_bsum(int* __restrict__ bsum, int nb) {
  __shared__ int sh[256];
  int t = threadIdx.x;
  int v = (t < nb) ? bsum[t] : 0;
  sh[t] = v;
  __syncthreads();
  for (int off = 1; off < 256; off <<= 1) {
    int add = (t >= off) ? sh[t - off] : 0;
    __syncthreads();
    sh[t] += add;
    __syncthreads();
  }
  if (t < nb) bsum[t] = sh[t] - v;  // exclusive
}

__global__ __launch_bounds__(512) void k_scan_final(const int* __restrict__ cnt,
                                                    const int* __restrict__ bsum,
                                                    int* __restrict__ indptr) {
  __shared__ int sh[SCAN_CHUNK];
  int t = threadIdx.x;
  int idx = blockIdx.x * SCAN_CHUNK + t;
  sh[t] = (idx < N_NODES) ? cnt[idx] : 0;
  __syncthreads();
  for (int off = 1; off < SCAN_CHUNK; off <<= 1) {
    int add = (t >= off) ? sh[t - off] : 0;
    __syncthreads();
    sh[t] += add;
    __syncthreads();
  }
  if (idx < N_NODES) indptr[idx + 1] = bsum[blockIdx.x] + sh[t];
  if (idx == 0) indptr[0] = 0;
}

__global__ void k_scatter(const int* __restrict__ ei, const int* __restrict__ indptr,
                          int* __restrict__ epos, int* __restrict__ esrc) {
  int e = blockIdx.x * blockDim.x + threadIdx.x;
  if (e < N_EDGES) {
    int d = ei[N_EDGES + e], s = ei[e];
    int p = atomicAdd(&epos[d], 1);
    esrc[indptr[d] + p] = s;
  } else if (e < EP) {
    int nn = e - N_EDGES;
    int p = atomicAdd(&epos[nn], 1);
    esrc[indptr[nn] + p] = nn;
  }
}

// ---------------- h = BN(x) @ W, fused per-node attention dots ----------------
// HD = H*D total cols; thread t owns col t. Head = col/D; aS/aD flat-indexed by col.
template <int FIN, int HD, int D, int NPB>
__global__ __launch_bounds__(256) void k_lin(const float* __restrict__ x, const float* __restrict__ W,
                                             const float* __restrict__ scale,
                                             const float* __restrict__ shift,
                                             const float* __restrict__ aS,
                                             const float* __restrict__ aD,
                                             float* __restrict__ hout,
                                             float* __restrict__ as_, float* __restrict__ ad_) {
  __shared__ float xs[NPB][FIN];
  int n0 = blockIdx.x * NPB;
  int t = threadIdx.x;
  for (int i = t; i < NPB * FIN; i += 256) {
    int nd = i / FIN, f = i - nd * FIN;
    int n = n0 + nd;
    float v = (n < N_NODES) ? x[(size_t)n * FIN + f] : 0.f;
    if (scale) v = fmaf(v, scale[f], shift[f]);
    xs[nd][f] = v;
  }
  __syncthreads();
  if (t < HD) {
    int col = t;
    float acc[NPB];
#pragma unroll
    for (int nd = 0; nd < NPB; nd++) acc[nd] = 0.f;
    for (int i = 0; i < FIN; i++) {
      float w = W[i * HD + col];
#pragma unroll
      for (int nd = 0; nd < NPB; nd++) acc[nd] = fmaf(xs[nd][i], w, acc[nd]);
    }
    float sa = aS[col], da = aD[col];
    int head = col / D;
    int laneInD = t & (D - 1);
#pragma unroll
    for (int nd = 0; nd < NPB; nd++) {
      int n = n0 + nd;
      if (n < N_NODES) hout[(size_t)n * HD + col] = acc[nd];
      float ps = acc[nd] * sa, pd = acc[nd] * da;
#pragma unroll
      for (int off = D / 2; off; off >>= 1) {
        ps += __shfl_xor(ps, off);
        pd += __shfl_xor(pd, off);
      }
      if (laneInD == 0 && n < N_NODES) {
        as_[n * NH + head] = ps;
        ad_[n * NH + head] = pd;
      }
    }
  }
}

// ---------------- fused softmax-weight + gather-aggregate (wave per node) ----------------
// Weights computed lane-parallel (one latency hit per 64 edges), broadcast via shfl.
// No max-subtraction: logits here are bounded (|.| < ~6), exp is safe in fp32, and
// the normalization makes the result mathematically identical to the ref.
template <int D>
__global__ __launch_bounds__(256) void k_agg(const int* __restrict__ indptr, const int* __restrict__ esrc,
                                             const float* __restrict__ h,
                                             const float4* __restrict__ as4,
                                             const float4* __restrict__ ad4,
                                             const float* __restrict__ bias,
                                             float* __restrict__ tout) {
  int lane = threadIdx.x & 63;
  int n = blockIdx.x * 4 + (threadIdx.x >> 6);
  if (n >= N_NODES) return;
  int e0 = indptr[n], e1 = indptr[n + 1];
  float4 ad = ad4[n];
  int d = lane & 31, hi = lane >> 5;  // D==32 mapping
  float s0 = 0.f, s1 = 0.f, s2 = 0.f, s3 = 0.f;
  float a0 = 0.f, a1 = 0.f, a2 = 0.f, a3 = 0.f;
  for (int c = e0; c < e1; c += 64) {
    int nc = min(64, e1 - c);
    int sidx = 0;
    float w0 = 0.f, w1 = 0.f, w2 = 0.f, w3 = 0.f;
    if (lane < nc) {
      sidx = esrc[c + lane];
      float4 av = as4[sidx];
      w0 = __expf(lrelu(av.x + ad.x));
      w1 = __expf(lrelu(av.y + ad.y));
      w2 = __expf(lrelu(av.z + ad.z));
      w3 = __expf(lrelu(av.w + ad.w));
      s0 += w0; s1 += w1; s2 += w2; s3 += w3;
    }
    if constexpr (D == 64) {
#pragma unroll 4
      for (int i = 0; i < nc; i++) {
        int s = __shfl(sidx, i);
        float b0 = __shfl(w0, i), b1 = __shfl(w1, i);
        float b2 = __shfl(w2, i), b3 = __shfl(w3, i);
        const float* hr = h + (size_t)s * 256;
        a0 = fmaf(b0, hr[lane], a0);
        a1 = fmaf(b1, hr[64 + lane], a1);
        a2 = fmaf(b2, hr[128 + lane], a2);
        a3 = fmaf(b3, hr[192 + lane], a3);
      }
    } else {
#pragma unroll 4
      for (int i = 0; i < nc; i++) {
        int s = __shfl(sidx, i);
        float b0 = __shfl(w0, i), b1 = __shfl(w1, i);
        float b2 = __shfl(w2, i), b3 = __shfl(w3, i);
        float wa = hi ? b2 : b0, wb = hi ? b3 : b1;
        const float* hr = h + (size_t)s * 128 + hi * 64 + d;
        a0 = fmaf(wa, hr[0], a0);
        a1 = fmaf(wb, hr[32], a1);
      }
    }
  }
  s0 = wredsum(s0); s1 = wredsum(s1); s2 = wredsum(s2); s3 = wredsum(s3);
  float r0 = 1.f / (s0 + 1e-16f), r1 = 1.f / (s1 + 1e-16f);
  float r2 = 1.f / (s2 + 1e-16f), r3 = 1.f / (s3 + 1e-16f);
  if constexpr (D == 64) {
    float v = (a0 * r0 + a1 * r1 + a2 * r2 + a3 * r3) * 0.25f + bias[lane];
    tout[(size_t)n * 64 + lane] = fmaxf(v, 0.f);  // fused ReLU
  } else {
    float ra = hi ? r2 : r0, rb = hi ? r3 : r1;
    float v = a0 * ra + a1 * rb;
    v += __shfl_xor(v, 32);
    if (lane < 32) tout[(size_t)n * 32 + d] = fmaxf(v * 0.25f + bias[d], 0.f);
  }
}

// ---------------- batch norm stats ----------------
template <int C>
__global__ __launch_bounds__(256) void k_bnstat(const float* __restrict__ x, float* __restrict__ part) {
  const int RG = 256 / C;
  int col = threadIdx.x & (C - 1);
  int rg = threadIdx.x / C;
  int rows = (N_NODES + gridDim.x - 1) / gridDim.x;
  int r0 = blockIdx.x * rows;
  int r1 = min(N_NODES, r0 + rows);
  float s = 0.f, q = 0.f;
  for (int r = r0 + rg; r < r1; r += RG) {
    float v = x[(size_t)r * C + col];
    s += v;
    q = fmaf(v, v, q);
  }
  __shared__ float sh[512];
  sh[threadIdx.x] = s;
  sh[256 + threadIdx.x] = q;
  __syncthreads();
  for (int step = 128; step >= C; step >>= 1) {
    if (threadIdx.x < step) {
      sh[threadIdx.x] += sh[threadIdx.x + step];
      sh[256 + threadIdx.x] += sh[256 + threadIdx.x + step];
    }
    __syncthreads();
  }
  if (threadIdx.x < C) {
    part[blockIdx.x * 2 * C + threadIdx.x] = sh[threadIdx.x];
    part[blockIdx.x * 2 * C + C + threadIdx.x] = sh[256 + threadIdx.x];
  }
}

template <int C>
__global__ void k_bnfinal(const float* __restrict__ part, const float* __restrict__ g,
                          const float* __restrict__ be, float* __restrict__ scale,
                          float* __restrict__ shift) {
  int c = threadIdx.x;
  if (c >= C) return;
  float s = 0.f, q = 0.f;
  for (int b = 0; b < 256; b++) {
    s += part[b * 2 * C + c];
    q += part[b * 2 * C + C + c];
  }
  float mean = s / (float)N_NODES;
  float var = q / (float)N_NODES - mean * mean;
  float sc = g[c] * rsqrtf(var + 1e-5f);
  scale[c] = sc;
  shift[c] = be[c] - mean * sc;
}

// ---------------- pooling (applies layer-3 BN on load; batch sorted) ----------------
__global__ __launch_bounds__(256) void k_pool(const float* __restrict__ f3,
                                              const int* __restrict__ batch,
                                              const float* __restrict__ scale,
                                              const float* __restrict__ shift,
                                              float* __restrict__ pool,
                                              float* __restrict__ cntg) {
  __shared__ float acc[NG][33];
  int t = threadIdx.x;
  for (int i = t; i < NG * 33; i += 256) ((float*)acc)[i] = 0.f;
  __syncthreads();
  int c = t & 31, rg = t >> 5;
  float sc = scale[c], sh = shift[c];
  int n0 = blockIdx.x * POOL_NPB;
  int n1 = min(N_NODES, n0 + POOL_NPB);
  float r = 0.f, rc = 0.f;
  int gcur = -1;
  for (int n = n0 + rg; n < n1; n += 8) {
    int g = batch[n];
    if (g != gcur) {
      if (gcur >= 0) {
        atomicAdd(&acc[gcur][c], r);
        if (c == 0) atomicAdd(&acc[gcur][32], rc);
      }
      gcur = g;
      r = 0.f;
      rc = 0.f;
    }
    r += fmaf(f3[(size_t)n * 32 + c], sc, sh);
    rc += 1.f;
  }
  if (gcur >= 0) {
    atomicAdd(&acc[gcur][c], r);
    if (c == 0) atomicAdd(&acc[gcur][32], rc);
  }
  __syncthreads();
  for (int i = t; i < NG * 32; i += 256) {
    int g = i >> 5, cc = i & 31;
    float v = acc[g][cc];
    if (v != 0.f) atomicAdd(&pool[i], v);
  }
  for (int g = t; g < NG; g += 256) {
    float v = acc[g][32];
    if (v != 0.f) atomicAdd(&cntg[g], v);
  }
}

__global__ void k_mlp(const float* __restrict__ pool, const float* __restrict__ cntg,
                      const float* __restrict__ Wp1, const float* __restrict__ bp1,
                      const float* __restrict__ Wp2, const float* __restrict__ bp2,
                      float* __restrict__ out) {
  int g = threadIdx.x;
  if (g >= NG) return;
  float inv = 1.f / fmaxf(cntg[g], 1.f);
  float p[32];
#pragma unroll
  for (int c = 0; c < 32; c++) p[c] = pool[g * 32 + c] * inv;
  float o = bp2[0];
  for (int j = 0; j < 16; j++) {
    float hsum = bp1[j];
#pragma unroll
    for (int c = 0; c < 32; c++) hsum = fmaf(p[c], Wp1[c * 16 + j], hsum);
    o = fmaf(fmaxf(hsum, 0.f), Wp2[j], o);
  }
  out[g] = o;
}

extern "C" void kernel_launch(void* const* d_in, const int* in_sizes, int n_in,
                              void* d_out, int out_size, void* d_ws, size_t ws_size,
                              hipStream_t stream) {
  const float* x = (const float*)d_in[0];
  const int* ei = (const int*)d_in[1];
  const int* batch = (const int*)d_in[2];
  const float* W1 = (const float*)d_in[3];
  const float* aS1 = (const float*)d_in[4];
  const float* aD1 = (const float*)d_in[5];
  const float* b1 = (const float*)d_in[6];
  const float* g1 = (const float*)d_in[7];
  const float* be1 = (const float*)d_in[8];
  const float* W2 = (const float*)d_in[9];
  const float* aS2 = (const float*)d_in[10];
  const float* aD2 = (const float*)d_in[11];
  const float* b2 = (const float*)d_in[12];
  const float* g2 = (const float*)d_in[13];
  const float* be2 = (const float*)d_in[14];
  const float* W3 = (const float*)d_in[15];
  const float* aS3 = (const float*)d_in[16];
  const float* aD3 = (const float*)d_in[17];
  const float* b3 = (const float*)d_in[18];
  const float* g3 = (const float*)d_in[19];
  const float* be3 = (const float*)d_in[20];
  const float* Wp1 = (const float*)d_in[21];
  const float* bp1 = (const float*)d_in[22];
  const float* Wp2 = (const float*)d_in[23];
  const float* bp2 = (const float*)d_in[24];
  float* out = (float*)d_out;

  size_t off = 0;
  auto alloc = [&](size_t bytes) -> void* {
    void* p = (char*)d_ws + off;
    off += (bytes + 255) & ~(size_t)255;
    return p;
  };
  int* cnt = (int*)alloc((size_t)N_NODES * 4);
  int* indptr = (int*)alloc((size_t)(N_NODES + 1) * 4);
  int* epos = (int*)alloc((size_t)N_NODES * 4);
  int* esrc = (int*)alloc((size_t)EP * 4);
  int* bsum = (int*)alloc((size_t)256 * 4);
  float* hbuf = (float*)alloc((size_t)N_NODES * 256 * 4);
  float* as_ = (float*)alloc((size_t)N_NODES * 4 * 4);
  float* ad_ = (float*)alloc((size_t)N_NODES * 4 * 4);
  float* tbuf = (float*)alloc((size_t)N_NODES * 64 * 4);
  float* part = (float*)alloc((size_t)256 * 128 * 4);
  float* scale = (float*)alloc(64 * 4);
  float* shift = (float*)alloc(64 * 4);
  float* pool = (float*)alloc((size_t)NG * 32 * 4);
  float* cntg = (float*)alloc((size_t)NG * 4);
  if (off > ws_size) return;

  hipMemsetAsync(cnt, 0, (size_t)N_NODES * 4, stream);
  hipMemsetAsync(epos, 0, (size_t)N_NODES * 4, stream);
  hipMemsetAsync(pool, 0, (size_t)NG * 32 * 4, stream);
  hipMemsetAsync(cntg, 0, (size_t)NG * 4, stream);

  int nscan = cdiv(N_NODES, SCAN_CHUNK);
  k_count<<<cdiv(EP, 256), 256, 0, stream>>>(ei, cnt);
  k_scan_partial<<<nscan, SCAN_CHUNK, 0, stream>>>(cnt, bsum);
  k_scan_bsum<<<1, 256, 0, stream>>>(bsum, nscan);
  k_scan_final<<<nscan, SCAN_CHUNK, 0, stream>>>(cnt, bsum, indptr);
  k_scatter<<<cdiv(EP, 256), 256, 0, stream>>>(ei, indptr, epos, esrc);

  int nblk = cdiv(N_NODES, 4);

  // ---- layer 1: 8 -> 64, D=64 ----
  k_lin<8, 256, 64, 8><<<cdiv(N_NODES, 8), 256, 0, stream>>>(x, W1, nullptr, nullptr, aS1, aD1,
                                                             hbuf, as_, ad_);
  k_agg<64><<<nblk, 256, 0, stream>>>(indptr, esrc, hbuf, (const float4*)as_,
                                      (const float4*)ad_, b1, tbuf);
  k_bnstat<64><<<256, 256, 0, stream>>>(tbuf, part);
  k_bnfinal<64><<<1, 64, 0, stream>>>(part, g1, be1, scale, shift);

  // ---- layer 2: 64 -> 64, D=64 (BN1 applied on load) ----
  k_lin<64, 256, 64, 8><<<cdiv(N_NODES, 8), 256, 0, stream>>>(tbuf, W2, scale, shift, aS2, aD2,
                                                              hbuf, as_, ad_);
  k_agg<64><<<nblk, 256, 0, stream>>>(indptr, esrc, hbuf, (const float4*)as_,
                                      (const float4*)ad_, b2, tbuf);
  k_bnstat<64><<<256, 256, 0, stream>>>(tbuf, part);
  k_bnfinal<64><<<1, 64, 0, stream>>>(part, g2, be2, scale, shift);

  // ---- layer 3: 64 -> 32, D=32 (BN2 applied on load) ----
  k_lin<64, 128, 32, 8><<<cdiv(N_NODES, 8), 256, 0, stream>>>(tbuf, W3, scale, shift, aS3, aD3,
                                                              hbuf, as_, ad_);
  k_agg<32><<<nblk, 256, 0, stream>>>(indptr, esrc, hbuf, (const float4*)as_,
                                      (const float4*)ad_, b3, tbuf);
  k_bnstat<32><<<256, 256, 0, stream>>>(tbuf, part);
  k_bnfinal<32><<<1, 32, 0, stream>>>(part, g3, be3, scale, shift);

  // ---- pool (BN3 on load) + MLP ----
  k_pool<<<cdiv(N_NODES, POOL_NPB), 256, 0, stream>>>(tbuf, batch, scale, shift, pool, cntg);
  k_mlp<<<1, 64, 0, stream>>>(pool, cntg, Wp1, bp1, Wp2, bp2, out);
}

// Round 5
// 984.422 us; speedup vs baseline: 2.3634x; 1.2522x over previous
//
#include <hip/hip_runtime.h>
#include <hip/hip_fp16.h>

#define N_NODES 100000
#define N_EDGES 1600000
#define EP (N_EDGES + N_NODES)
#define NG 64
#define NH 4
#define SCAN_CHUNK 512
#define POOL_NPB 2048

static inline int cdiv(int a, int b) { return (a + b - 1) / b; }

__device__ __forceinline__ float lrelu(float x) { return x >= 0.f ? x : 0.2f * x; }

__device__ __forceinline__ float wredsum(float v) {
#pragma unroll
  for (int off = 32; off; off >>= 1) v += __shfl_xor(v, off);
  return v;
}

__device__ __forceinline__ float bcast_f(float v, int i) {
  return __int_as_float(__builtin_amdgcn_readlane(__float_as_int(v), i));
}

// ---------------- CSR build ----------------
__global__ void k_count(const int* __restrict__ ei, int* __restrict__ cnt) {
  int e = blockIdx.x * blockDim.x + threadIdx.x;
  if (e < N_EDGES) atomicAdd(&cnt[ei[N_EDGES + e]], 1);
  else if (e < EP) atomicAdd(&cnt[e - N_EDGES], 1);  // self loop
}

__global__ __launch_bounds__(512) void k_scan_partial(const int* __restrict__ cnt,
                                                      int* __restrict__ bsum) {
  __shared__ int sh[SCAN_CHUNK];
  int t = threadIdx.x;
  int idx = blockIdx.x * SCAN_CHUNK + t;
  sh[t] = (idx < N_NODES) ? cnt[idx] : 0;
  __syncthreads();
  for (int s = SCAN_CHUNK / 2; s; s >>= 1) {
    if (t < s) sh[t] += sh[t + s];
    __syncthreads();
  }
  if (t == 0) bsum[blockIdx.x] = sh[0];
}

__global__ void k_scan_bsum(int* __restrict__ bsum, int nb) {
  __shared__ int sh[256];
  int t = threadIdx.x;
  int v = (t < nb) ? bsum[t] : 0;
  sh[t] = v;
  __syncthreads();
  for (int off = 1; off < 256; off <<= 1) {
    int add = (t >= off) ? sh[t - off] : 0;
    __syncthreads();
    sh[t] += add;
    __syncthreads();
  }
  if (t < nb) bsum[t] = sh[t] - v;  // exclusive
}

__global__ __launch_bounds__(512) void k_scan_final(const int* __restrict__ cnt,
                                                    const int* __restrict__ bsum,
                                                    int* __restrict__ indptr) {
  __shared__ int sh[SCAN_CHUNK];
  int t = threadIdx.x;
  int idx = blockIdx.x * SCAN_CHUNK + t;
  sh[t] = (idx < N_NODES) ? cnt[idx] : 0;
  __syncthreads();
  for (int off = 1; off < SCAN_CHUNK; off <<= 1) {
    int add = (t >= off) ? sh[t - off] : 0;
    __syncthreads();
    sh[t] += add;
    __syncthreads();
  }
  if (idx < N_NODES) indptr[idx + 1] = bsum[blockIdx.x] + sh[t];
  if (idx == 0) indptr[0] = 0;
}

__global__ void k_scatter(const int* __restrict__ ei, const int* __restrict__ indptr,
                          int* __restrict__ epos, int* __restrict__ esrc) {
  int e = blockIdx.x * blockDim.x + threadIdx.x;
  if (e < N_EDGES) {
    int d = ei[N_EDGES + e], s = ei[e];
    int p = atomicAdd(&epos[d], 1);
    esrc[indptr[d] + p] = s;
  } else if (e < EP) {
    int nn = e - N_EDGES;
    int p = atomicAdd(&epos[nn], 1);
    esrc[indptr[nn] + p] = nn;
  }
}

// ---------------- h = BN(x) @ W (fp16 out), fused per-node attention dots ----------------
template <int FIN, int HD, int D, int NPB>
__global__ __launch_bounds__(256) void k_lin(const float* __restrict__ x, const float* __restrict__ W,
                                             const float* __restrict__ scale,
                                             const float* __restrict__ shift,
                                             const float* __restrict__ aS,
                                             const float* __restrict__ aD,
                                             __half* __restrict__ hout,
                                             float* __restrict__ as_, float* __restrict__ ad_) {
  __shared__ float xs[NPB][FIN];
  int n0 = blockIdx.x * NPB;
  int t = threadIdx.x;
  for (int i = t; i < NPB * FIN; i += 256) {
    int nd = i / FIN, f = i - nd * FIN;
    int n = n0 + nd;
    float v = (n < N_NODES) ? x[(size_t)n * FIN + f] : 0.f;
    if (scale) v = fmaf(v, scale[f], shift[f]);
    xs[nd][f] = v;
  }
  __syncthreads();
  if (t < HD) {
    int col = t;
    float acc[NPB];
#pragma unroll
    for (int nd = 0; nd < NPB; nd++) acc[nd] = 0.f;
    for (int i = 0; i < FIN; i++) {
      float w = W[i * HD + col];
#pragma unroll
      for (int nd = 0; nd < NPB; nd++) acc[nd] = fmaf(xs[nd][i], w, acc[nd]);
    }
    float sa = aS[col], da = aD[col];
    int head = col / D;
    int laneInD = t & (D - 1);
#pragma unroll
    for (int nd = 0; nd < NPB; nd++) {
      int n = n0 + nd;
      if (n < N_NODES) hout[(size_t)n * HD + col] = __float2half(acc[nd]);
      float ps = acc[nd] * sa, pd = acc[nd] * da;
#pragma unroll
      for (int off = D / 2; off; off >>= 1) {
        ps += __shfl_xor(ps, off);
        pd += __shfl_xor(pd, off);
      }
      if (laneInD == 0 && n < N_NODES) {
        as_[n * NH + head] = ps;
        ad_[n * NH + head] = pd;
      }
    }
  }
}

// ---------------- fused softmax-weight + fp16 gather-aggregate (wave per node) ----------------
// Weights computed lane-parallel, broadcast via v_readlane (SGPR, no LDS pipe).
// No max-subtraction: logits bounded, exp safe in fp32; normalization keeps result identical.
template <int D>
__global__ __launch_bounds__(256) void k_agg(const int* __restrict__ indptr, const int* __restrict__ esrc,
                                             const __half2* __restrict__ h2,
                                             const float4* __restrict__ as4,
                                             const float4* __restrict__ ad4,
                                             const float* __restrict__ bias,
                                             float* __restrict__ tout) {
  int lane = threadIdx.x & 63;
  int n = blockIdx.x * 4 + (threadIdx.x >> 6);
  if (n >= N_NODES) return;
  int e0 = indptr[n], e1 = indptr[n + 1];
  float4 ad = ad4[n];
  float s0 = 0.f, s1 = 0.f, s2 = 0.f, s3 = 0.f;
  float ax = 0.f, ay = 0.f, bx = 0.f, by = 0.f;
  for (int c = e0; c < e1; c += 64) {
    int nc = min(64, e1 - c);
    int sidx = 0;
    float w0 = 0.f, w1 = 0.f, w2 = 0.f, w3 = 0.f;
    if (lane < nc) {
      sidx = esrc[c + lane];
      float4 av = as4[sidx];
      w0 = __expf(lrelu(av.x + ad.x));
      w1 = __expf(lrelu(av.y + ad.y));
      w2 = __expf(lrelu(av.z + ad.z));
      w3 = __expf(lrelu(av.w + ad.w));
      s0 += w0; s1 += w1; s2 += w2; s3 += w3;
    }
#pragma unroll 4
    for (int i = 0; i < nc; i++) {
      int s = __builtin_amdgcn_readlane(sidx, i);
      float u0 = bcast_f(w0, i), u1 = bcast_f(w1, i);
      float u2 = bcast_f(w2, i), u3 = bcast_f(w3, i);
      if constexpr (D == 64) {
        const __half2* hr = h2 + (size_t)s * 128;
        float2 fa = __half22float2(hr[lane]);       // heads 0/1 half-row
        float2 fb = __half22float2(hr[64 + lane]);  // heads 2/3 half-row
        float wa = lane < 32 ? u0 : u1;
        float wb = lane < 32 ? u2 : u3;
        ax = fmaf(wa, fa.x, ax); ay = fmaf(wa, fa.y, ay);
        bx = fmaf(wb, fb.x, bx); by = fmaf(wb, fb.y, by);
      } else {
        const __half2* hr = h2 + (size_t)s * 64;
        float2 f = __half22float2(hr[lane]);  // whole row, head = lane>>4
        int hsel = lane >> 4;
        float wl = hsel == 0 ? u0 : hsel == 1 ? u1 : hsel == 2 ? u2 : u3;
        ax = fmaf(wl, f.x, ax); ay = fmaf(wl, f.y, ay);
      }
    }
  }
  s0 = wredsum(s0); s1 = wredsum(s1); s2 = wredsum(s2); s3 = wredsum(s3);
  float r0 = 1.f / (s0 + 1e-16f), r1 = 1.f / (s1 + 1e-16f);
  float r2 = 1.f / (s2 + 1e-16f), r3 = 1.f / (s3 + 1e-16f);
  if constexpr (D == 64) {
    float ra = lane < 32 ? r0 : r1;
    float rb = lane < 32 ? r2 : r3;
    float vx = ax * ra + bx * rb;
    float vy = ay * ra + by * rb;
    vx += __shfl_xor(vx, 32);
    vy += __shfl_xor(vy, 32);
    if (lane < 32) {
      float2 bb = ((const float2*)bias)[lane];
      float2 o;
      o.x = fmaxf(fmaf(vx, 0.25f, bb.x), 0.f);
      o.y = fmaxf(fmaf(vy, 0.25f, bb.y), 0.f);
      ((float2*)tout)[(size_t)n * 32 + lane] = o;  // dims 2*lane, 2*lane+1
    }
  } else {
    int hsel = lane >> 4;
    float rl = hsel == 0 ? r0 : hsel == 1 ? r1 : hsel == 2 ? r2 : r3;
    float vx = ax * rl, vy = ay * rl;
    vx += __shfl_xor(vx, 16); vy += __shfl_xor(vy, 16);
    vx += __shfl_xor(vx, 32); vy += __shfl_xor(vy, 32);
    if (lane < 16) {
      float2 bb = ((const float2*)bias)[lane];
      float2 o;
      o.x = fmaxf(fmaf(vx, 0.25f, bb.x), 0.f);
      o.y = fmaxf(fmaf(vy, 0.25f, bb.y), 0.f);
      ((float2*)tout)[(size_t)n * 16 + lane] = o;
    }
  }
}

// ---------------- batch norm stats ----------------
template <int C>
__global__ __launch_bounds__(256) void k_bnstat(const float* __restrict__ x, float* __restrict__ part) {
  const int RG = 256 / C;
  int col = threadIdx.x & (C - 1);
  int rg = threadIdx.x / C;
  int rows = (N_NODES + gridDim.x - 1) / gridDim.x;
  int r0 = blockIdx.x * rows;
  int r1 = min(N_NODES, r0 + rows);
  float s = 0.f, q = 0.f;
  for (int r = r0 + rg; r < r1; r += RG) {
    float v = x[(size_t)r * C + col];
    s += v;
    q = fmaf(v, v, q);
  }
  __shared__ float sh[512];
  sh[threadIdx.x] = s;
  sh[256 + threadIdx.x] = q;
  __syncthreads();
  for (int step = 128; step >= C; step >>= 1) {
    if (threadIdx.x < step) {
      sh[threadIdx.x] += sh[threadIdx.x + step];
      sh[256 + threadIdx.x] += sh[256 + threadIdx.x + step];
    }
    __syncthreads();
  }
  if (threadIdx.x < C) {
    part[blockIdx.x * 2 * C + threadIdx.x] = sh[threadIdx.x];
    part[blockIdx.x * 2 * C + C + threadIdx.x] = sh[256 + threadIdx.x];
  }
}

template <int C>
__global__ void k_bnfinal(const float* __restrict__ part, const float* __restrict__ g,
                          const float* __restrict__ be, float* __restrict__ scale,
                          float* __restrict__ shift) {
  int c = threadIdx.x;
  if (c >= C) return;
  float s = 0.f, q = 0.f;
  for (int b = 0; b < 256; b++) {
    s += part[b * 2 * C + c];
    q += part[b * 2 * C + C + c];
  }
  float mean = s / (float)N_NODES;
  float var = q / (float)N_NODES - mean * mean;
  float sc = g[c] * rsqrtf(var + 1e-5f);
  scale[c] = sc;
  shift[c] = be[c] - mean * sc;
}

// ---------------- pooling (applies layer-3 BN on load; batch sorted) ----------------
__global__ __launch_bounds__(256) void k_pool(const float* __restrict__ f3,
                                              const int* __restrict__ batch,
                                              const float* __restrict__ scale,
                                              const float* __restrict__ shift,
                                              float* __restrict__ pool,
                                              float* __restrict__ cntg) {
  __shared__ float acc[NG][33];
  int t = threadIdx.x;
  for (int i = t; i < NG * 33; i += 256) ((float*)acc)[i] = 0.f;
  __syncthreads();
  int c = t & 31, rg = t >> 5;
  float sc = scale[c], sh = shift[c];
  int n0 = blockIdx.x * POOL_NPB;
  int n1 = min(N_NODES, n0 + POOL_NPB);
  float r = 0.f, rc = 0.f;
  int gcur = -1;
  for (int n = n0 + rg; n < n1; n += 8) {
    int g = batch[n];
    if (g != gcur) {
      if (gcur >= 0) {
        atomicAdd(&acc[gcur][c], r);
        if (c == 0) atomicAdd(&acc[gcur][32], rc);
      }
      gcur = g;
      r = 0.f;
      rc = 0.f;
    }
    r += fmaf(f3[(size_t)n * 32 + c], sc, sh);
    rc += 1.f;
  }
  if (gcur >= 0) {
    atomicAdd(&acc[gcur][c], r);
    if (c == 0) atomicAdd(&acc[gcur][32], rc);
  }
  __syncthreads();
  for (int i = t; i < NG * 32; i += 256) {
    int g = i >> 5, cc = i & 31;
    float v = acc[g][cc];
    if (v != 0.f) atomicAdd(&pool[i], v);
  }
  for (int g = t; g < NG; g += 256) {
    float v = acc[g][32];
    if (v != 0.f) atomicAdd(&cntg[g], v);
  }
}

__global__ void k_mlp(const float* __restrict__ pool, const float* __restrict__ cntg,
                      const float* __restrict__ Wp1, const float* __restrict__ bp1,
                      const float* __restrict__ Wp2, const float* __restrict__ bp2,
                      float* __restrict__ out) {
  int g = threadIdx.x;
  if (g >= NG) return;
  float inv = 1.f / fmaxf(cntg[g], 1.f);
  float p[32];
#pragma unroll
  for (int c = 0; c < 32; c++) p[c] = pool[g * 32 + c] * inv;
  float o = bp2[0];
  for (int j = 0; j < 16; j++) {
    float hsum = bp1[j];
#pragma unroll
    for (int c = 0; c < 32; c++) hsum = fmaf(p[c], Wp1[c * 16 + j], hsum);
    o = fmaf(fmaxf(hsum, 0.f), Wp2[j], o);
  }
  out[g] = o;
}

extern "C" void kernel_launch(void* const* d_in, const int* in_sizes, int n_in,
                              void* d_out, int out_size, void* d_ws, size_t ws_size,
                              hipStream_t stream) {
  const float* x = (const float*)d_in[0];
  const int* ei = (const int*)d_in[1];
  const int* batch = (const int*)d_in[2];
  const float* W1 = (const float*)d_in[3];
  const float* aS1 = (const float*)d_in[4];
  const float* aD1 = (const float*)d_in[5];
  const float* b1 = (const float*)d_in[6];
  const float* g1 = (const float*)d_in[7];
  const float* be1 = (const float*)d_in[8];
  const float* W2 = (const float*)d_in[9];
  const float* aS2 = (const float*)d_in[10];
  const float* aD2 = (const float*)d_in[11];
  const float* b2 = (const float*)d_in[12];
  const float* g2 = (const float*)d_in[13];
  const float* be2 = (const float*)d_in[14];
  const float* W3 = (const float*)d_in[15];
  const float* aS3 = (const float*)d_in[16];
  const float* aD3 = (const float*)d_in[17];
  const float* b3 = (const float*)d_in[18];
  const float* g3 = (const float*)d_in[19];
  const float* be3 = (const float*)d_in[20];
  const float* Wp1 = (const float*)d_in[21];
  const float* bp1 = (const float*)d_in[22];
  const float* Wp2 = (const float*)d_in[23];
  const float* bp2 = (const float*)d_in[24];
  float* out = (float*)d_out;

  size_t off = 0;
  auto alloc = [&](size_t bytes) -> void* {
    void* p = (char*)d_ws + off;
    off += (bytes + 255) & ~(size_t)255;
    return p;
  };
  int* cnt = (int*)alloc((size_t)N_NODES * 4);
  int* indptr = (int*)alloc((size_t)(N_NODES + 1) * 4);
  int* epos = (int*)alloc((size_t)N_NODES * 4);
  int* esrc = (int*)alloc((size_t)EP * 4);
  int* bsum = (int*)alloc((size_t)256 * 4);
  __half* h16 = (__half*)alloc((size_t)N_NODES * 256 * 2);
  float* as_ = (float*)alloc((size_t)N_NODES * 4 * 4);
  float* ad_ = (float*)alloc((size_t)N_NODES * 4 * 4);
  float* tbuf = (float*)alloc((size_t)N_NODES * 64 * 4);
  float* part = (float*)alloc((size_t)256 * 128 * 4);
  float* scale = (float*)alloc(64 * 4);
  float* shift = (float*)alloc(64 * 4);
  float* pool = (float*)alloc((size_t)NG * 32 * 4);
  float* cntg = (float*)alloc((size_t)NG * 4);
  if (off > ws_size) return;

  hipMemsetAsync(cnt, 0, (size_t)N_NODES * 4, stream);
  hipMemsetAsync(epos, 0, (size_t)N_NODES * 4, stream);
  hipMemsetAsync(pool, 0, (size_t)NG * 32 * 4, stream);
  hipMemsetAsync(cntg, 0, (size_t)NG * 4, stream);

  int nscan = cdiv(N_NODES, SCAN_CHUNK);
  k_count<<<cdiv(EP, 256), 256, 0, stream>>>(ei, cnt);
  k_scan_partial<<<nscan, SCAN_CHUNK, 0, stream>>>(cnt, bsum);
  k_scan_bsum<<<1, 256, 0, stream>>>(bsum, nscan);
  k_scan_final<<<nscan, SCAN_CHUNK, 0, stream>>>(cnt, bsum, indptr);
  k_scatter<<<cdiv(EP, 256), 256, 0, stream>>>(ei, indptr, epos, esrc);

  int nblk = cdiv(N_NODES, 4);

  // ---- layer 1: 8 -> 64, D=64 ----
  k_lin<8, 256, 64, 8><<<cdiv(N_NODES, 8), 256, 0, stream>>>(x, W1, nullptr, nullptr, aS1, aD1,
                                                             h16, as_, ad_);
  k_agg<64><<<nblk, 256, 0, stream>>>(indptr, esrc, (const __half2*)h16, (const float4*)as_,
                                      (const float4*)ad_, b1, tbuf);
  k_bnstat<64><<<256, 256, 0, stream>>>(tbuf, part);
  k_bnfinal<64><<<1, 64, 0, stream>>>(part, g1, be1, scale, shift);

  // ---- layer 2: 64 -> 64, D=64 (BN1 applied on load) ----
  k_lin<64, 256, 64, 8><<<cdiv(N_NODES, 8), 256, 0, stream>>>(tbuf, W2, scale, shift, aS2, aD2,
                                                              h16, as_, ad_);
  k_agg<64><<<nblk, 256, 0, stream>>>(indptr, esrc, (const __half2*)h16, (const float4*)as_,
                                      (const float4*)ad_, b2, tbuf);
  k_bnstat<64><<<256, 256, 0, stream>>>(tbuf, part);
  k_bnfinal<64><<<1, 64, 0, stream>>>(part, g2, be2, scale, shift);

  // ---- layer 3: 64 -> 32, D=32 (BN2 applied on load) ----
  k_lin<64, 128, 32, 8><<<cdiv(N_NODES, 8), 256, 0, stream>>>(tbuf, W3, scale, shift, aS3, aD3,
                                                              h16, as_, ad_);
  k_agg<32><<<nblk, 256, 0, stream>>>(indptr, esrc, (const __half2*)h16, (const float4*)as_,
                                      (const float4*)ad_, b3, tbuf);
  k_bnstat<32><<<256, 256, 0, stream>>>(tbuf, part);
  k_bnfinal<32><<<1, 32, 0, stream>>>(part, g3, be3, scale, shift);

  // ---- pool (BN3 on load) + MLP ----
  k_pool<<<cdiv(N_NODES, POOL_NPB), 256, 0, stream>>>(tbuf, batch, scale, shift, pool, cntg);
  k_mlp<<<1, 64, 0, stream>>>(pool, cntg, Wp1, bp1, Wp2, bp2, out);
}

// Round 6
// 971.609 us; speedup vs baseline: 2.3946x; 1.0132x over previous
//
#include <hip/hip_runtime.h>
#include <hip/hip_fp16.h>

#define N_NODES 100000
#define N_EDGES 1600000
#define EP (N_EDGES + N_NODES)
#define NG 64
#define NH 4
#define SCAN_CHUNK 512
#define POOL_NPB 2048

static inline int cdiv(int a, int b) { return (a + b - 1) / b; }

__device__ __forceinline__ float lrelu(float x) { return x >= 0.f ? x : 0.2f * x; }

__device__ __forceinline__ float wredsum(float v) {
#pragma unroll
  for (int off = 32; off; off >>= 1) v += __shfl_xor(v, off);
  return v;
}

__device__ __forceinline__ float bcast_f(float v, int i) {
  return __int_as_float(__builtin_amdgcn_readlane(__float_as_int(v), i));
}

// ---------------- CSR build ----------------
__global__ void k_count(const int* __restrict__ ei, int* __restrict__ cnt) {
  int e = blockIdx.x * blockDim.x + threadIdx.x;
  if (e < N_EDGES) atomicAdd(&cnt[ei[N_EDGES + e]], 1);
  else if (e < EP) atomicAdd(&cnt[e - N_EDGES], 1);  // self loop
}

__global__ __launch_bounds__(512) void k_scan_partial(const int* __restrict__ cnt,
                                                      int* __restrict__ bsum) {
  __shared__ int sh[SCAN_CHUNK];
  int t = threadIdx.x;
  int idx = blockIdx.x * SCAN_CHUNK + t;
  sh[t] = (idx < N_NODES) ? cnt[idx] : 0;
  __syncthreads();
  for (int s = SCAN_CHUNK / 2; s; s >>= 1) {
    if (t < s) sh[t] += sh[t + s];
    __syncthreads();
  }
  if (t == 0) bsum[blockIdx.x] = sh[0];
}

__global__ void k_scan_bsum(int* __restrict__ bsum, int nb) {
  __shared__ int sh[256];
  int t = threadIdx.x;
  int v = (t < nb) ? bsum[t] : 0;
  sh[t] = v;
  __syncthreads();
  for (int off = 1; off < 256; off <<= 1) {
    int add = (t >= off) ? sh[t - off] : 0;
    __syncthreads();
    sh[t] += add;
    __syncthreads();
  }
  if (t < nb) bsum[t] = sh[t] - v;  // exclusive
}

__global__ __launch_bounds__(512) void k_scan_final(const int* __restrict__ cnt,
                                                    const int* __restrict__ bsum,
                                                    int* __restrict__ indptr) {
  __shared__ int sh[SCAN_CHUNK];
  int t = threadIdx.x;
  int idx = blockIdx.x * SCAN_CHUNK + t;
  sh[t] = (idx < N_NODES) ? cnt[idx] : 0;
  __syncthreads();
  for (int off = 1; off < SCAN_CHUNK; off <<= 1) {
    int add = (t >= off) ? sh[t - off] : 0;
    __syncthreads();
    sh[t] += add;
    __syncthreads();
  }
  if (idx < N_NODES) indptr[idx + 1] = bsum[blockIdx.x] + sh[t];
  if (idx == 0) indptr[0] = 0;
}

__global__ void k_scatter(const int* __restrict__ ei, const int* __restrict__ indptr,
                          int* __restrict__ epos, int* __restrict__ esrc) {
  int e = blockIdx.x * blockDim.x + threadIdx.x;
  if (e < N_EDGES) {
    int d = ei[N_EDGES + e], s = ei[e];
    int p = atomicAdd(&epos[d], 1);
    esrc[indptr[d] + p] = s;
  } else if (e < EP) {
    int nn = e - N_EDGES;
    int p = atomicAdd(&epos[nn], 1);
    esrc[indptr[nn] + p] = nn;
  }
}

// ---------------- wS[h] = W_h @ aS_h (folds attention dots to input space) ----------------
template <int FIN, int D>
__global__ void k_wvec(const float* __restrict__ W, const float* __restrict__ aS,
                       const float* __restrict__ aD, float* __restrict__ wS,
                       float* __restrict__ wD) {
  int t = threadIdx.x;
  if (t >= 4 * FIN) return;
  int h = t / FIN, k = t % FIN;
  float ss = 0.f, dd = 0.f;
  for (int d = 0; d < D; d++) {
    float w = W[k * (4 * D) + h * D + d];
    ss = fmaf(w, aS[h * D + d], ss);
    dd = fmaf(w, aD[h * D + d], dd);
  }
  wS[h * FIN + k] = ss;
  wD[h * FIN + k] = dd;
}

// ---------------- layer-1 attention dots from raw x (FIN=8) ----------------
__global__ void k_attdots1(const float* __restrict__ x, const float* __restrict__ wS,
                           const float* __restrict__ wD, float4* __restrict__ as4,
                           float4* __restrict__ ad4) {
  int n = blockIdx.x * blockDim.x + threadIdx.x;
  if (n >= N_NODES) return;
  float4 s = {0, 0, 0, 0}, d = {0, 0, 0, 0};
#pragma unroll
  for (int k = 0; k < 8; k++) {
    float xv = x[(size_t)n * 8 + k];
    s.x = fmaf(xv, wS[k], s.x);
    s.y = fmaf(xv, wS[8 + k], s.y);
    s.z = fmaf(xv, wS[16 + k], s.z);
    s.w = fmaf(xv, wS[24 + k], s.w);
    d.x = fmaf(xv, wD[k], d.x);
    d.y = fmaf(xv, wD[8 + k], d.y);
    d.z = fmaf(xv, wD[16 + k], d.z);
    d.w = fmaf(xv, wD[24 + k], d.w);
  }
  as4[n] = s;
  ad4[n] = d;
}

// ---------------- BN-apply + fp16 cast + attention dots (FIN=64) ----------------
__global__ __launch_bounds__(256) void k_bnx(const float* __restrict__ tbuf,
                                             const float* __restrict__ scale,
                                             const float* __restrict__ shift,
                                             const float* __restrict__ wS,
                                             const float* __restrict__ wD,
                                             __half* __restrict__ xhat,
                                             float4* __restrict__ as4, float4* __restrict__ ad4) {
  int lane = threadIdx.x & 63;
  int n = blockIdx.x * 4 + (threadIdx.x >> 6);
  if (n >= N_NODES) return;
  float v = fmaf(tbuf[(size_t)n * 64 + lane], scale[lane], shift[lane]);
  xhat[(size_t)n * 64 + lane] = __float2half(v);
  float p0 = v * wS[lane], p1 = v * wS[64 + lane], p2 = v * wS[128 + lane], p3 = v * wS[192 + lane];
  float q0 = v * wD[lane], q1 = v * wD[64 + lane], q2 = v * wD[128 + lane], q3 = v * wD[192 + lane];
  p0 = wredsum(p0); p1 = wredsum(p1); p2 = wredsum(p2); p3 = wredsum(p3);
  q0 = wredsum(q0); q1 = wredsum(q1); q2 = wredsum(q2); q3 = wredsum(q3);
  if (lane == 0) {
    as4[n] = make_float4(p0, p1, p2, p3);
    ad4[n] = make_float4(q0, q1, q2, q3);
  }
}

// ---------------- fused softmax-weight + INPUT gather (wave per node) ----------------
// Gathers x-hat (DIN fp16/fp32) instead of h (4*D fp16): 4x fewer bytes, small table.
// acc16 layout: [N][DIN][4 heads] (half4 per (n,dim) -> one 8B store/lane).
template <int DIN, typename TX>
__global__ __launch_bounds__(256) void k_agg(const int* __restrict__ indptr,
                                             const int* __restrict__ esrc,
                                             const TX* __restrict__ xg,
                                             const float4* __restrict__ as4,
                                             const float4* __restrict__ ad4,
                                             __half* __restrict__ acc16) {
  int lane = threadIdx.x & 63;
  int n = blockIdx.x * 4 + (threadIdx.x >> 6);
  if (n >= N_NODES) return;
  int e0 = indptr[n], e1 = indptr[n + 1];
  float4 ad = ad4[n];
  int ld = lane & (DIN - 1);
  float s0 = 0.f, s1 = 0.f, s2 = 0.f, s3 = 0.f;
  float a0 = 0.f, a1 = 0.f, a2 = 0.f, a3 = 0.f;
  for (int c = e0; c < e1; c += 64) {
    int nc = min(64, e1 - c);
    int sidx = 0;
    float w0 = 0.f, w1 = 0.f, w2 = 0.f, w3 = 0.f;
    if (lane < nc) {
      sidx = esrc[c + lane];
      float4 av = as4[sidx];
      w0 = __expf(lrelu(av.x + ad.x));
      w1 = __expf(lrelu(av.y + ad.y));
      w2 = __expf(lrelu(av.z + ad.z));
      w3 = __expf(lrelu(av.w + ad.w));
      s0 += w0; s1 += w1; s2 += w2; s3 += w3;
    }
#pragma unroll 4
    for (int i = 0; i < nc; i++) {
      int s = __builtin_amdgcn_readlane(sidx, i);
      float u0 = bcast_f(w0, i), u1 = bcast_f(w1, i);
      float u2 = bcast_f(w2, i), u3 = bcast_f(w3, i);
      float xv;
      if constexpr (sizeof(TX) == 2) xv = __half2float(xg[(size_t)s * DIN + ld]);
      else xv = xg[(size_t)s * DIN + ld];
      a0 = fmaf(u0, xv, a0);
      a1 = fmaf(u1, xv, a1);
      a2 = fmaf(u2, xv, a2);
      a3 = fmaf(u3, xv, a3);
    }
  }
  s0 = wredsum(s0); s1 = wredsum(s1); s2 = wredsum(s2); s3 = wredsum(s3);
  float r0 = 1.f / (s0 + 1e-16f), r1 = 1.f / (s1 + 1e-16f);
  float r2 = 1.f / (s2 + 1e-16f), r3 = 1.f / (s3 + 1e-16f);
  if (lane < DIN) {
    __half2 h01 = __floats2half2_rn(a0 * r0, a1 * r1);
    __half2 h23 = __floats2half2_rn(a2 * r2, a3 * r3);
    uint2 pk = make_uint2(*(const unsigned int*)&h01, *(const unsigned int*)&h23);
    *(uint2*)(acc16 + ((size_t)n * DIN + ld) * 4) = pk;
  }
}

// ---------------- per-node projection: tbuf = relu(mean_h(acc_h @ W_h) + bias) ----------------
template <int DIN, int DOUT, int NPB>
__global__ __launch_bounds__(256) void k_post(const __half* __restrict__ acc16,
                                              const float* __restrict__ W,
                                              const float* __restrict__ bias,
                                              float* __restrict__ tbuf) {
  __shared__ float accs[NPB][4 * DIN];  // layout r = k*4 + head
  __shared__ float olds[NPB][4][DOUT];
  int n0 = blockIdx.x * NPB;
  int t = threadIdx.x;
  const unsigned int* ap = (const unsigned int*)acc16;
  for (int i = t; i < NPB * 2 * DIN; i += 256) {
    int nd = i / (2 * DIN), r2 = i % (2 * DIN);
    int n = n0 + nd;
    unsigned int v = (n < N_NODES) ? ap[(size_t)n * 2 * DIN + r2] : 0u;
    __half2 hv = *(const __half2*)&v;
    float2 f = __half22float2(hv);
    accs[nd][2 * r2] = f.x;
    accs[nd][2 * r2 + 1] = f.y;
  }
  __syncthreads();
  constexpr int ACT = 4 * DOUT;
  if (t < ACT) {
    int head = t / DOUT;
    float o[NPB];
#pragma unroll
    for (int nd = 0; nd < NPB; nd++) o[nd] = 0.f;
    for (int k = 0; k < DIN; k++) {
      float w = W[k * ACT + t];
#pragma unroll
      for (int nd = 0; nd < NPB; nd++) o[nd] = fmaf(accs[nd][k * 4 + head], w, o[nd]);
    }
    int j = t - head * DOUT;
#pragma unroll
    for (int nd = 0; nd < NPB; nd++) olds[nd][head][j] = o[nd];
  }
  __syncthreads();
  for (int i = t; i < NPB * DOUT; i += 256) {
    int nd = i / DOUT, j = i % DOUT;
    int n = n0 + nd;
    if (n < N_NODES) {
      float v = 0.25f * (olds[nd][0][j] + olds[nd][1][j] + olds[nd][2][j] + olds[nd][3][j]) + bias[j];
      tbuf[(size_t)n * DOUT + j] = fmaxf(v, 0.f);
    }
  }
}

// ---------------- batch norm stats ----------------
template <int C>
__global__ __launch_bounds__(256) void k_bnstat(const float* __restrict__ x, float* __restrict__ part) {
  const int RG = 256 / C;
  int col = threadIdx.x & (C - 1);
  int rg = threadIdx.x / C;
  int rows = (N_NODES + gridDim.x - 1) / gridDim.x;
  int r0 = blockIdx.x * rows;
  int r1 = min(N_NODES, r0 + rows);
  float s = 0.f, q = 0.f;
  for (int r = r0 + rg; r < r1; r += RG) {
    float v = x[(size_t)r * C + col];
    s += v;
    q = fmaf(v, v, q);
  }
  __shared__ float sh[512];
  sh[threadIdx.x] = s;
  sh[256 + threadIdx.x] = q;
  __syncthreads();
  for (int step = 128; step >= C; step >>= 1) {
    if (threadIdx.x < step) {
      sh[threadIdx.x] += sh[threadIdx.x + step];
      sh[256 + threadIdx.x] += sh[256 + threadIdx.x + step];
    }
    __syncthreads();
  }
  if (threadIdx.x < C) {
    part[blockIdx.x * 2 * C + threadIdx.x] = sh[threadIdx.x];
    part[blockIdx.x * 2 * C + C + threadIdx.x] = sh[256 + threadIdx.x];
  }
}

template <int C>
__global__ void k_bnfinal(const float* __restrict__ part, const float* __restrict__ g,
                          const float* __restrict__ be, float* __restrict__ scale,
                          float* __restrict__ shift) {
  int c = threadIdx.x;
  if (c >= C) return;
  float s = 0.f, q = 0.f;
  for (int b = 0; b < 256; b++) {
    s += part[b * 2 * C + c];
    q += part[b * 2 * C + C + c];
  }
  float mean = s / (float)N_NODES;
  float var = q / (float)N_NODES - mean * mean;
  float sc = g[c] * rsqrtf(var + 1e-5f);
  scale[c] = sc;
  shift[c] = be[c] - mean * sc;
}

// ---------------- pooling (applies layer-3 BN on load; batch sorted) ----------------
__global__ __launch_bounds__(256) void k_pool(const float* __restrict__ f3,
                                              const int* __restrict__ batch,
                                              const float* __restrict__ scale,
                                              const float* __restrict__ shift,
                                              float* __restrict__ pool,
                                              float* __restrict__ cntg) {
  __shared__ float acc[NG][33];
  int t = threadIdx.x;
  for (int i = t; i < NG * 33; i += 256) ((float*)acc)[i] = 0.f;
  __syncthreads();
  int c = t & 31, rg = t >> 5;
  float sc = scale[c], sh = shift[c];
  int n0 = blockIdx.x * POOL_NPB;
  int n1 = min(N_NODES, n0 + POOL_NPB);
  float r = 0.f, rc = 0.f;
  int gcur = -1;
  for (int n = n0 + rg; n < n1; n += 8) {
    int g = batch[n];
    if (g != gcur) {
      if (gcur >= 0) {
        atomicAdd(&acc[gcur][c], r);
        if (c == 0) atomicAdd(&acc[gcur][32], rc);
      }
      gcur = g;
      r = 0.f;
      rc = 0.f;
    }
    r += fmaf(f3[(size_t)n * 32 + c], sc, sh);
    rc += 1.f;
  }
  if (gcur >= 0) {
    atomicAdd(&acc[gcur][c], r);
    if (c == 0) atomicAdd(&acc[gcur][32], rc);
  }
  __syncthreads();
  for (int i = t; i < NG * 32; i += 256) {
    int g = i >> 5, cc = i & 31;
    float v = acc[g][cc];
    if (v != 0.f) atomicAdd(&pool[i], v);
  }
  for (int g = t; g < NG; g += 256) {
    float v = acc[g][32];
    if (v != 0.f) atomicAdd(&cntg[g], v);
  }
}

__global__ void k_mlp(const float* __restrict__ pool, const float* __restrict__ cntg,
                      const float* __restrict__ Wp1, const float* __restrict__ bp1,
                      const float* __restrict__ Wp2, const float* __restrict__ bp2,
                      float* __restrict__ out) {
  int g = threadIdx.x;
  if (g >= NG) return;
  float inv = 1.f / fmaxf(cntg[g], 1.f);
  float p[32];
#pragma unroll
  for (int c = 0; c < 32; c++) p[c] = pool[g * 32 + c] * inv;
  float o = bp2[0];
  for (int j = 0; j < 16; j++) {
    float hsum = bp1[j];
#pragma unroll
    for (int c = 0; c < 32; c++) hsum = fmaf(p[c], Wp1[c * 16 + j], hsum);
    o = fmaf(fmaxf(hsum, 0.f), Wp2[j], o);
  }
  out[g] = o;
}

extern "C" void kernel_launch(void* const* d_in, const int* in_sizes, int n_in,
                              void* d_out, int out_size, void* d_ws, size_t ws_size,
                              hipStream_t stream) {
  const float* x = (const float*)d_in[0];
  const int* ei = (const int*)d_in[1];
  const int* batch = (const int*)d_in[2];
  const float* W1 = (const float*)d_in[3];
  const float* aS1 = (const float*)d_in[4];
  const float* aD1 = (const float*)d_in[5];
  const float* b1 = (const float*)d_in[6];
  const float* g1 = (const float*)d_in[7];
  const float* be1 = (const float*)d_in[8];
  const float* W2 = (const float*)d_in[9];
  const float* aS2 = (const float*)d_in[10];
  const float* aD2 = (const float*)d_in[11];
  const float* b2 = (const float*)d_in[12];
  const float* g2 = (const float*)d_in[13];
  const float* be2 = (const float*)d_in[14];
  const float* W3 = (const float*)d_in[15];
  const float* aS3 = (const float*)d_in[16];
  const float* aD3 = (const float*)d_in[17];
  const float* b3 = (const float*)d_in[18];
  const float* g3 = (const float*)d_in[19];
  const float* be3 = (const float*)d_in[20];
  const float* Wp1 = (const float*)d_in[21];
  const float* bp1 = (const float*)d_in[22];
  const float* Wp2 = (const float*)d_in[23];
  const float* bp2 = (const float*)d_in[24];
  float* out = (float*)d_out;

  size_t off = 0;
  auto alloc = [&](size_t bytes) -> void* {
    void* p = (char*)d_ws + off;
    off += (bytes + 255) & ~(size_t)255;
    return p;
  };
  int* cnt = (int*)alloc((size_t)N_NODES * 4);
  int* indptr = (int*)alloc((size_t)(N_NODES + 1) * 4);
  int* epos = (int*)alloc((size_t)N_NODES * 4);
  int* esrc = (int*)alloc((size_t)EP * 4);
  int* bsum = (int*)alloc((size_t)256 * 4);
  __half* xhat = (__half*)alloc((size_t)N_NODES * 64 * 2);
  __half* acc16 = (__half*)alloc((size_t)N_NODES * 256 * 2);
  float* as_ = (float*)alloc((size_t)N_NODES * 16);
  float* ad_ = (float*)alloc((size_t)N_NODES * 16);
  float* tbuf = (float*)alloc((size_t)N_NODES * 64 * 4);
  float* part = (float*)alloc((size_t)256 * 128 * 4);
  float* scale = (float*)alloc(64 * 4);
  float* shift = (float*)alloc(64 * 4);
  float* pool = (float*)alloc((size_t)NG * 32 * 4);
  float* cntg = (float*)alloc((size_t)NG * 4);
  float* wS1 = (float*)alloc(32 * 4);
  float* wD1 = (float*)alloc(32 * 4);
  float* wS2 = (float*)alloc(256 * 4);
  float* wD2 = (float*)alloc(256 * 4);
  float* wS3 = (float*)alloc(256 * 4);
  float* wD3 = (float*)alloc(256 * 4);
  if (off > ws_size) return;

  hipMemsetAsync(cnt, 0, (size_t)N_NODES * 4, stream);
  hipMemsetAsync(epos, 0, (size_t)N_NODES * 4, stream);
  hipMemsetAsync(pool, 0, (size_t)NG * 32 * 4, stream);
  hipMemsetAsync(cntg, 0, (size_t)NG * 4, stream);

  int nscan = cdiv(N_NODES, SCAN_CHUNK);
  k_count<<<cdiv(EP, 256), 256, 0, stream>>>(ei, cnt);
  k_scan_partial<<<nscan, SCAN_CHUNK, 0, stream>>>(cnt, bsum);
  k_scan_bsum<<<1, 256, 0, stream>>>(bsum, nscan);
  k_scan_final<<<nscan, SCAN_CHUNK, 0, stream>>>(cnt, bsum, indptr);
  k_scatter<<<cdiv(EP, 256), 256, 0, stream>>>(ei, indptr, epos, esrc);

  k_wvec<8, 64><<<1, 64, 0, stream>>>(W1, aS1, aD1, wS1, wD1);
  k_wvec<64, 64><<<1, 256, 0, stream>>>(W2, aS2, aD2, wS2, wD2);
  k_wvec<64, 32><<<1, 256, 0, stream>>>(W3, aS3, aD3, wS3, wD3);

  int nblk = cdiv(N_NODES, 4);

  // ---- layer 1: gather raw x (8 fp32), project with W1 ----
  k_attdots1<<<cdiv(N_NODES, 256), 256, 0, stream>>>(x, wS1, wD1, (float4*)as_, (float4*)ad_);
  k_agg<8, float><<<nblk, 256, 0, stream>>>(indptr, esrc, x, (const float4*)as_,
                                            (const float4*)ad_, acc16);
  k_post<8, 64, 8><<<cdiv(N_NODES, 8), 256, 0, stream>>>(acc16, W1, b1, tbuf);
  k_bnstat<64><<<256, 256, 0, stream>>>(tbuf, part);
  k_bnfinal<64><<<1, 64, 0, stream>>>(part, g1, be1, scale, shift);

  // ---- layer 2: gather xhat (64 fp16), project with W2 ----
  k_bnx<<<nblk, 256, 0, stream>>>(tbuf, scale, shift, wS2, wD2, xhat, (float4*)as_, (float4*)ad_);
  k_agg<64, __half><<<nblk, 256, 0, stream>>>(indptr, esrc, xhat, (const float4*)as_,
                                              (const float4*)ad_, acc16);
  k_post<64, 64, 8><<<cdiv(N_NODES, 8), 256, 0, stream>>>(acc16, W2, b2, tbuf);
  k_bnstat<64><<<256, 256, 0, stream>>>(tbuf, part);
  k_bnfinal<64><<<1, 64, 0, stream>>>(part, g2, be2, scale, shift);

  // ---- layer 3: gather xhat (64 fp16), project with W3 (DOUT=32) ----
  k_bnx<<<nblk, 256, 0, stream>>>(tbuf, scale, shift, wS3, wD3, xhat, (float4*)as_, (float4*)ad_);
  k_agg<64, __half><<<nblk, 256, 0, stream>>>(indptr, esrc, xhat, (const float4*)as_,
                                              (const float4*)ad_, acc16);
  k_post<64, 32, 8><<<cdiv(N_NODES, 8), 256, 0, stream>>>(acc16, W3, b3, tbuf);
  k_bnstat<32><<<256, 256, 0, stream>>>(tbuf, part);
  k_bnfinal<32><<<1, 32, 0, stream>>>(part, g3, be3, scale, shift);

  // ---- pool (BN3 on load) + MLP ----
  k_pool<<<cdiv(N_NODES, POOL_NPB), 256, 0, stream>>>(tbuf, batch, scale, shift, pool, cntg);
  k_mlp<<<1, 64, 0, stream>>>(pool, cntg, Wp1, bp1, Wp2, bp2, out);
}

// Round 7
// 868.839 us; speedup vs baseline: 2.6778x; 1.1183x over previous
//
#include <hip/hip_runtime.h>
#include <hip/hip_fp16.h>

#define N_NODES 100000
#define PAD_N (N_NODES + 64)
#define N_EDGES 1600000
#define EP (N_EDGES + N_NODES)
#define NG 64
#define NH 4
#define SCAN_CHUNK 512
#define POOL_NPB 2048

static inline int cdiv(int a, int b) { return (a + b - 1) / b; }

typedef _Float16 half8 __attribute__((ext_vector_type(8)));
typedef float f32x4 __attribute__((ext_vector_type(4)));

__device__ __forceinline__ float lrelu(float x) { return x >= 0.f ? x : 0.2f * x; }

__device__ __forceinline__ float wredsum(float v) {
#pragma unroll
  for (int off = 32; off; off >>= 1) v += __shfl_xor(v, off);
  return v;
}

__device__ __forceinline__ float bcast_f(float v, int i) {
  return __int_as_float(__builtin_amdgcn_readlane(__float_as_int(v), i));
}

// ---------------- CSR build ----------------
__global__ void k_count(const int* __restrict__ ei, int* __restrict__ cnt) {
  int e = blockIdx.x * blockDim.x + threadIdx.x;
  if (e < N_EDGES) atomicAdd(&cnt[ei[N_EDGES + e]], 1);
  else if (e < EP) atomicAdd(&cnt[e - N_EDGES], 1);  // self loop
}

__global__ __launch_bounds__(512) void k_scan_partial(const int* __restrict__ cnt,
                                                      int* __restrict__ bsum) {
  __shared__ int sh[SCAN_CHUNK];
  int t = threadIdx.x;
  int idx = blockIdx.x * SCAN_CHUNK + t;
  sh[t] = (idx < N_NODES) ? cnt[idx] : 0;
  __syncthreads();
  for (int s = SCAN_CHUNK / 2; s; s >>= 1) {
    if (t < s) sh[t] += sh[t + s];
    __syncthreads();
  }
  if (t == 0) bsum[blockIdx.x] = sh[0];
}

__global__ void k_scan_bsum(int* __restrict__ bsum, int nb) {
  __shared__ int sh[256];
  int t = threadIdx.x;
  int v = (t < nb) ? bsum[t] : 0;
  sh[t] = v;
  __syncthreads();
  for (int off = 1; off < 256; off <<= 1) {
    int add = (t >= off) ? sh[t - off] : 0;
    __syncthreads();
    sh[t] += add;
    __syncthreads();
  }
  if (t < nb) bsum[t] = sh[t] - v;  // exclusive
}

__global__ __launch_bounds__(512) void k_scan_final(const int* __restrict__ cnt,
                                                    const int* __restrict__ bsum,
                                                    int* __restrict__ indptr) {
  __shared__ int sh[SCAN_CHUNK];
  int t = threadIdx.x;
  int idx = blockIdx.x * SCAN_CHUNK + t;
  sh[t] = (idx < N_NODES) ? cnt[idx] : 0;
  __syncthreads();
  for (int off = 1; off < SCAN_CHUNK; off <<= 1) {
    int add = (t >= off) ? sh[t - off] : 0;
    __syncthreads();
    sh[t] += add;
    __syncthreads();
  }
  if (idx < N_NODES) indptr[idx + 1] = bsum[blockIdx.x] + sh[t];
  if (idx == 0) indptr[0] = 0;
}

__global__ void k_scatter(const int* __restrict__ ei, const int* __restrict__ indptr,
                          int* __restrict__ epos, int* __restrict__ esrc) {
  int e = blockIdx.x * blockDim.x + threadIdx.x;
  if (e < N_EDGES) {
    int d = ei[N_EDGES + e], s = ei[e];
    int p = atomicAdd(&epos[d], 1);
    esrc[indptr[d] + p] = s;
  } else if (e < EP) {
    int nn = e - N_EDGES;
    int p = atomicAdd(&epos[nn], 1);
    esrc[indptr[nn] + p] = nn;
  }
}

// ---------------- wS[h] = W_h @ aS_h (folds attention dots to input space) ----------------
template <int FIN, int D>
__global__ void k_wvec(const float* __restrict__ W, const float* __restrict__ aS,
                       const float* __restrict__ aD, float* __restrict__ wS,
                       float* __restrict__ wD) {
  int t = threadIdx.x;
  if (t >= 4 * FIN) return;
  int h = t / FIN, k = t % FIN;
  float ss = 0.f, dd = 0.f;
  for (int d = 0; d < D; d++) {
    float w = W[k * (4 * D) + h * D + d];
    ss = fmaf(w, aS[h * D + d], ss);
    dd = fmaf(w, aD[h * D + d], dd);
  }
  wS[h * FIN + k] = ss;
  wD[h * FIN + k] = dd;
}

// ---------------- pack W into MFMA B-fragment lane order (fp16) ----------------
// frag (h, ct, kt): lane l holds B[k = kt*32 + (l>>4)*8 + j][col = ct*16 + (l&15)], j=0..7
template <int DOUT>
__global__ void k_wcvt(const float* __restrict__ W, __half* __restrict__ wfrag) {
  constexpr int NCT = DOUT / 16;
  int tid = blockIdx.x * blockDim.x + threadIdx.x;
  if (tid >= 4 * NCT * 2 * 64) return;
  int frag = tid >> 6, l = tid & 63;
  int kt = frag & 1;
  int ct = (frag >> 1) % NCT;
  int h = (frag >> 1) / NCT;
  int k0 = kt * 32 + (l >> 4) * 8;
  int col = ct * 16 + (l & 15);
  half8 v;
#pragma unroll
  for (int j = 0; j < 8; j++) v[j] = (_Float16)W[(k0 + j) * (4 * DOUT) + h * DOUT + col];
  *(half8*)(wfrag + (size_t)frag * 512 + l * 8) = v;
}

// ---------------- layer-1 attention dots from raw x (FIN=8) ----------------
__global__ void k_attdots1(const float* __restrict__ x, const float* __restrict__ wS,
                           const float* __restrict__ wD, float4* __restrict__ as4,
                           float4* __restrict__ ad4) {
  int n = blockIdx.x * blockDim.x + threadIdx.x;
  if (n >= N_NODES) return;
  float4 s = {0, 0, 0, 0}, d = {0, 0, 0, 0};
#pragma unroll
  for (int k = 0; k < 8; k++) {
    float xv = x[(size_t)n * 8 + k];
    s.x = fmaf(xv, wS[k], s.x);
    s.y = fmaf(xv, wS[8 + k], s.y);
    s.z = fmaf(xv, wS[16 + k], s.z);
    s.w = fmaf(xv, wS[24 + k], s.w);
    d.x = fmaf(xv, wD[k], d.x);
    d.y = fmaf(xv, wD[8 + k], d.y);
    d.z = fmaf(xv, wD[16 + k], d.z);
    d.w = fmaf(xv, wD[24 + k], d.w);
  }
  as4[n] = s;
  ad4[n] = d;
}

// ---------------- BN-apply + fp16 cast + attention dots (FIN=64) ----------------
__global__ __launch_bounds__(256) void k_bnx(const float* __restrict__ tbuf,
                                             const float* __restrict__ scale,
                                             const float* __restrict__ shift,
                                             const float* __restrict__ wS,
                                             const float* __restrict__ wD,
                                             __half* __restrict__ xhat,
                                             float4* __restrict__ as4, float4* __restrict__ ad4) {
  int lane = threadIdx.x & 63;
  int n = blockIdx.x * 4 + (threadIdx.x >> 6);
  if (n >= N_NODES) return;
  float v = fmaf(tbuf[(size_t)n * 64 + lane], scale[lane], shift[lane]);
  xhat[(size_t)n * 64 + lane] = __float2half(v);
  float p0 = v * wS[lane], p1 = v * wS[64 + lane], p2 = v * wS[128 + lane], p3 = v * wS[192 + lane];
  float q0 = v * wD[lane], q1 = v * wD[64 + lane], q2 = v * wD[128 + lane], q3 = v * wD[192 + lane];
  p0 = wredsum(p0); p1 = wredsum(p1); p2 = wredsum(p2); p3 = wredsum(p3);
  q0 = wredsum(q0); q1 = wredsum(q1); q2 = wredsum(q2); q3 = wredsum(q3);
  if (lane == 0) {
    as4[n] = make_float4(p0, p1, p2, p3);
    ad4[n] = make_float4(q0, q1, q2, q3);
  }
}

// ---------------- fused softmax-weight + INPUT gather (wave per node) ----------------
// int32 byte-offset addressing; per-edge values broadcast via v_readlane (uniform -> SGPR).
// PLANES=true stores per-head planes [h][n][k] fp16 for the MFMA k_post; else interleaved.
template <int DIN, typename TX, bool PLANES>
__global__ __launch_bounds__(256) void k_agg(const int* __restrict__ indptr,
                                             const int* __restrict__ esrc,
                                             const TX* __restrict__ xg,
                                             const float4* __restrict__ as4,
                                             const float4* __restrict__ ad4,
                                             __half* __restrict__ acc_out, int pstride) {
  int lane = threadIdx.x & 63;
  int n = blockIdx.x * 4 + (threadIdx.x >> 6);
  if (n >= N_NODES) return;
  int e0 = indptr[n], e1 = indptr[n + 1];
  float4 ad = ad4[n];
  constexpr int SH = (sizeof(TX) == 2) ? 7 : 5;  // row byte stride: 64*2 or 8*4
  int ld = lane & (DIN - 1);
  const char* xbase = (const char*)xg + ld * (int)sizeof(TX);
  float s0 = 0.f, s1 = 0.f, s2 = 0.f, s3 = 0.f;
  float a0 = 0.f, a1 = 0.f, a2 = 0.f, a3 = 0.f;
  for (int c = e0; c < e1; c += 64) {
    int nc = min(64, e1 - c);
    int sB = 0;
    float w0 = 0.f, w1 = 0.f, w2 = 0.f, w3 = 0.f;
    if (lane < nc) {
      int sidx = esrc[c + lane];
      float4 av = as4[sidx];
      w0 = __expf(lrelu(av.x + ad.x));
      w1 = __expf(lrelu(av.y + ad.y));
      w2 = __expf(lrelu(av.z + ad.z));
      w3 = __expf(lrelu(av.w + ad.w));
      s0 += w0; s1 += w1; s2 += w2; s3 += w3;
      sB = sidx << SH;
    }
#pragma unroll 4
    for (int i = 0; i < nc; i++) {
      int sb = __builtin_amdgcn_readlane(sB, i);  // uniform byte offset
      float u0 = bcast_f(w0, i), u1 = bcast_f(w1, i);
      float u2 = bcast_f(w2, i), u3 = bcast_f(w3, i);
      float xv;
      if constexpr (sizeof(TX) == 2) xv = __half2float(*(const __half*)(xbase + sb));
      else xv = *(const float*)(xbase + sb);
      a0 = fmaf(u0, xv, a0);
      a1 = fmaf(u1, xv, a1);
      a2 = fmaf(u2, xv, a2);
      a3 = fmaf(u3, xv, a3);
    }
  }
  s0 = wredsum(s0); s1 = wredsum(s1); s2 = wredsum(s2); s3 = wredsum(s3);
  float r0 = 1.f / (s0 + 1e-16f), r1 = 1.f / (s1 + 1e-16f);
  float r2 = 1.f / (s2 + 1e-16f), r3 = 1.f / (s3 + 1e-16f);
  if constexpr (PLANES) {
    int base = n * 64 + lane;
    acc_out[base] = __float2half(a0 * r0);
    acc_out[pstride + base] = __float2half(a1 * r1);
    acc_out[2 * pstride + base] = __float2half(a2 * r2);
    acc_out[3 * pstride + base] = __float2half(a3 * r3);
  } else {
    if (lane < DIN) {
      __half2 h01 = __floats2half2_rn(a0 * r0, a1 * r1);
      __half2 h23 = __floats2half2_rn(a2 * r2, a3 * r3);
      uint2 pk = make_uint2(*(const unsigned int*)&h01, *(const unsigned int*)&h23);
      *(uint2*)(acc_out + ((size_t)n * DIN + ld) * 4) = pk;
    }
  }
}

// ---------------- MFMA projection: tbuf = relu(mean_h(acc_h @ W_h) + bias) ----------------
// wave = 16-node tile; C-frags accumulate over heads and K-tiles.
template <int DOUT>
__global__ __launch_bounds__(256) void k_post_mfma(const __half* __restrict__ accp, int pstride,
                                                   const __half* __restrict__ wfrag,
                                                   const float* __restrict__ bias,
                                                   float* __restrict__ tbuf) {
  constexpr int NCT = DOUT / 16;
  int l = threadIdx.x & 63;
  int n0 = (blockIdx.x * 4 + (threadIdx.x >> 6)) * 16;
  int m = l & 15, kg = l >> 4;
  f32x4 c[NCT];
#pragma unroll
  for (int ct = 0; ct < NCT; ct++) c[ct] = (f32x4){0.f, 0.f, 0.f, 0.f};
#pragma unroll
  for (int h = 0; h < 4; h++) {
#pragma unroll
    for (int kt = 0; kt < 2; kt++) {
      half8 a = *(const half8*)(accp + h * pstride + (n0 + m) * 64 + kt * 32 + kg * 8);
#pragma unroll
      for (int ct = 0; ct < NCT; ct++) {
        half8 b = *(const half8*)(wfrag + (((h * NCT + ct) * 2 + kt) * 64 + l) * 8);
        c[ct] = __builtin_amdgcn_mfma_f32_16x16x32_f16(a, b, c[ct], 0, 0, 0);
      }
    }
  }
#pragma unroll
  for (int ct = 0; ct < NCT; ct++) {
    float bv = bias[ct * 16 + m];
#pragma unroll
    for (int j = 0; j < 4; j++) {
      int n = n0 + kg * 4 + j;
      if (n < N_NODES) tbuf[(size_t)n * DOUT + ct * 16 + m] = fmaxf(fmaf(c[ct][j], 0.25f, bv), 0.f);
    }
  }
}

// ---------------- VALU projection (layer 1 only, DIN=8) ----------------
template <int DIN, int DOUT, int NPB>
__global__ __launch_bounds__(256) void k_post(const __half* __restrict__ acc16,
                                              const float* __restrict__ W,
                                              const float* __restrict__ bias,
                                              float* __restrict__ tbuf) {
  __shared__ float accs[NPB][4 * DIN];
  __shared__ float olds[NPB][4][DOUT];
  int n0 = blockIdx.x * NPB;
  int t = threadIdx.x;
  const unsigned int* ap = (const unsigned int*)acc16;
  for (int i = t; i < NPB * 2 * DIN; i += 256) {
    int nd = i / (2 * DIN), r2 = i % (2 * DIN);
    int n = n0 + nd;
    unsigned int v = (n < N_NODES) ? ap[(size_t)n * 2 * DIN + r2] : 0u;
    __half2 hv = *(const __half2*)&v;
    float2 f = __half22float2(hv);
    accs[nd][2 * r2] = f.x;
    accs[nd][2 * r2 + 1] = f.y;
  }
  __syncthreads();
  constexpr int ACT = 4 * DOUT;
  if (t < ACT) {
    int head = t / DOUT;
    float o[NPB];
#pragma unroll
    for (int nd = 0; nd < NPB; nd++) o[nd] = 0.f;
    for (int k = 0; k < DIN; k++) {
      float w = W[k * ACT + t];
#pragma unroll
      for (int nd = 0; nd < NPB; nd++) o[nd] = fmaf(accs[nd][k * 4 + head], w, o[nd]);
    }
    int j = t - head * DOUT;
#pragma unroll
    for (int nd = 0; nd < NPB; nd++) olds[nd][head][j] = o[nd];
  }
  __syncthreads();
  for (int i = t; i < NPB * DOUT; i += 256) {
    int nd = i / DOUT, j = i % DOUT;
    int n = n0 + nd;
    if (n < N_NODES) {
      float v = 0.25f * (olds[nd][0][j] + olds[nd][1][j] + olds[nd][2][j] + olds[nd][3][j]) + bias[j];
      tbuf[(size_t)n * DOUT + j] = fmaxf(v, 0.f);
    }
  }
}

// ---------------- batch norm stats ----------------
template <int C>
__global__ __launch_bounds__(256) void k_bnstat(const float* __restrict__ x, float* __restrict__ part) {
  const int RG = 256 / C;
  int col = threadIdx.x & (C - 1);
  int rg = threadIdx.x / C;
  int rows = (N_NODES + gridDim.x - 1) / gridDim.x;
  int r0 = blockIdx.x * rows;
  int r1 = min(N_NODES, r0 + rows);
  float s = 0.f, q = 0.f;
  for (int r = r0 + rg; r < r1; r += RG) {
    float v = x[(size_t)r * C + col];
    s += v;
    q = fmaf(v, v, q);
  }
  __shared__ float sh[512];
  sh[threadIdx.x] = s;
  sh[256 + threadIdx.x] = q;
  __syncthreads();
  for (int step = 128; step >= C; step >>= 1) {
    if (threadIdx.x < step) {
      sh[threadIdx.x] += sh[threadIdx.x + step];
      sh[256 + threadIdx.x] += sh[256 + threadIdx.x + step];
    }
    __syncthreads();
  }
  if (threadIdx.x < C) {
    part[blockIdx.x * 2 * C + threadIdx.x] = sh[threadIdx.x];
    part[blockIdx.x * 2 * C + C + threadIdx.x] = sh[256 + threadIdx.x];
  }
}

template <int C>
__global__ void k_bnfinal(const float* __restrict__ part, const float* __restrict__ g,
                          const float* __restrict__ be, float* __restrict__ scale,
                          float* __restrict__ shift) {
  int c = threadIdx.x;
  if (c >= C) return;
  float s = 0.f, q = 0.f;
  for (int b = 0; b < 256; b++) {
    s += part[b * 2 * C + c];
    q += part[b * 2 * C + C + c];
  }
  float mean = s / (float)N_NODES;
  float var = q / (float)N_NODES - mean * mean;
  float sc = g[c] * rsqrtf(var + 1e-5f);
  scale[c] = sc;
  shift[c] = be[c] - mean * sc;
}

// ---------------- pooling (applies layer-3 BN on load; batch sorted) ----------------
__global__ __launch_bounds__(256) void k_pool(const float* __restrict__ f3,
                                              const int* __restrict__ batch,
                                              const float* __restrict__ scale,
                                              const float* __restrict__ shift,
                                              float* __restrict__ pool,
                                              float* __restrict__ cntg) {
  __shared__ float acc[NG][33];
  int t = threadIdx.x;
  for (int i = t; i < NG * 33; i += 256) ((float*)acc)[i] = 0.f;
  __syncthreads();
  int c = t & 31, rg = t >> 5;
  float sc = scale[c], sh = shift[c];
  int n0 = blockIdx.x * POOL_NPB;
  int n1 = min(N_NODES, n0 + POOL_NPB);
  float r = 0.f, rc = 0.f;
  int gcur = -1;
  for (int n = n0 + rg; n < n1; n += 8) {
    int g = batch[n];
    if (g != gcur) {
      if (gcur >= 0) {
        atomicAdd(&acc[gcur][c], r);
        if (c == 0) atomicAdd(&acc[gcur][32], rc);
      }
      gcur = g;
      r = 0.f;
      rc = 0.f;
    }
    r += fmaf(f3[(size_t)n * 32 + c], sc, sh);
    rc += 1.f;
  }
  if (gcur >= 0) {
    atomicAdd(&acc[gcur][c], r);
    if (c == 0) atomicAdd(&acc[gcur][32], rc);
  }
  __syncthreads();
  for (int i = t; i < NG * 32; i += 256) {
    int g = i >> 5, cc = i & 31;
    float v = acc[g][cc];
    if (v != 0.f) atomicAdd(&pool[i], v);
  }
  for (int g = t; g < NG; g += 256) {
    float v = acc[g][32];
    if (v != 0.f) atomicAdd(&cntg[g], v);
  }
}

__global__ void k_mlp(const float* __restrict__ pool, const float* __restrict__ cntg,
                      const float* __restrict__ Wp1, const float* __restrict__ bp1,
                      const float* __restrict__ Wp2, const float* __restrict__ bp2,
                      float* __restrict__ out) {
  int g = threadIdx.x;
  if (g >= NG) return;
  float inv = 1.f / fmaxf(cntg[g], 1.f);
  float p[32];
#pragma unroll
  for (int c = 0; c < 32; c++) p[c] = pool[g * 32 + c] * inv;
  float o = bp2[0];
  for (int j = 0; j < 16; j++) {
    float hsum = bp1[j];
#pragma unroll
    for (int c = 0; c < 32; c++) hsum = fmaf(p[c], Wp1[c * 16 + j], hsum);
    o = fmaf(fmaxf(hsum, 0.f), Wp2[j], o);
  }
  out[g] = o;
}

extern "C" void kernel_launch(void* const* d_in, const int* in_sizes, int n_in,
                              void* d_out, int out_size, void* d_ws, size_t ws_size,
                              hipStream_t stream) {
  const float* x = (const float*)d_in[0];
  const int* ei = (const int*)d_in[1];
  const int* batch = (const int*)d_in[2];
  const float* W1 = (const float*)d_in[3];
  const float* aS1 = (const float*)d_in[4];
  const float* aD1 = (const float*)d_in[5];
  const float* b1 = (const float*)d_in[6];
  const float* g1 = (const float*)d_in[7];
  const float* be1 = (const float*)d_in[8];
  const float* W2 = (const float*)d_in[9];
  const float* aS2 = (const float*)d_in[10];
  const float* aD2 = (const float*)d_in[11];
  const float* b2 = (const float*)d_in[12];
  const float* g2 = (const float*)d_in[13];
  const float* be2 = (const float*)d_in[14];
  const float* W3 = (const float*)d_in[15];
  const float* aS3 = (const float*)d_in[16];
  const float* aD3 = (const float*)d_in[17];
  const float* b3 = (const float*)d_in[18];
  const float* g3 = (const float*)d_in[19];
  const float* be3 = (const float*)d_in[20];
  const float* Wp1 = (const float*)d_in[21];
  const float* bp1 = (const float*)d_in[22];
  const float* Wp2 = (const float*)d_in[23];
  const float* bp2 = (const float*)d_in[24];
  float* out = (float*)d_out;

  size_t off = 0;
  auto alloc = [&](size_t bytes) -> void* {
    void* p = (char*)d_ws + off;
    off += (bytes + 255) & ~(size_t)255;
    return p;
  };
  int* cnt = (int*)alloc((size_t)N_NODES * 4);
  int* indptr = (int*)alloc((size_t)(N_NODES + 1) * 4);
  int* epos = (int*)alloc((size_t)N_NODES * 4);
  int* esrc = (int*)alloc((size_t)EP * 4);
  int* bsum = (int*)alloc((size_t)256 * 4);
  __half* xhat = (__half*)alloc((size_t)N_NODES * 64 * 2);
  __half* acc16 = (__half*)alloc((size_t)N_NODES * 8 * 4 * 2);  // layer-1 interleaved
  __half* accp = (__half*)alloc((size_t)4 * PAD_N * 64 * 2);    // per-head planes
  float* as_ = (float*)alloc((size_t)N_NODES * 16);
  float* ad_ = (float*)alloc((size_t)N_NODES * 16);
  float* tbuf = (float*)alloc((size_t)N_NODES * 64 * 4);
  float* part = (float*)alloc((size_t)256 * 128 * 4);
  float* scale = (float*)alloc(64 * 4);
  float* shift = (float*)alloc(64 * 4);
  float* pool = (float*)alloc((size_t)NG * 32 * 4);
  float* cntg = (float*)alloc((size_t)NG * 4);
  float* wS1 = (float*)alloc(32 * 4);
  float* wD1 = (float*)alloc(32 * 4);
  float* wS2 = (float*)alloc(256 * 4);
  float* wD2 = (float*)alloc(256 * 4);
  float* wS3 = (float*)alloc(256 * 4);
  float* wD3 = (float*)alloc(256 * 4);
  __half* wfrag2 = (__half*)alloc((size_t)32 * 512 * 2);
  __half* wfrag3 = (__half*)alloc((size_t)16 * 512 * 2);
  if (off > ws_size) return;

  const int PSTR = PAD_N * 64;

  hipMemsetAsync(cnt, 0, (size_t)N_NODES * 4, stream);
  hipMemsetAsync(epos, 0, (size_t)N_NODES * 4, stream);
  hipMemsetAsync(pool, 0, (size_t)NG * 32 * 4, stream);
  hipMemsetAsync(cntg, 0, (size_t)NG * 4, stream);

  int nscan = cdiv(N_NODES, SCAN_CHUNK);
  k_count<<<cdiv(EP, 256), 256, 0, stream>>>(ei, cnt);
  k_scan_partial<<<nscan, SCAN_CHUNK, 0, stream>>>(cnt, bsum);
  k_scan_bsum<<<1, 256, 0, stream>>>(bsum, nscan);
  k_scan_final<<<nscan, SCAN_CHUNK, 0, stream>>>(cnt, bsum, indptr);
  k_scatter<<<cdiv(EP, 256), 256, 0, stream>>>(ei, indptr, epos, esrc);

  k_wvec<8, 64><<<1, 64, 0, stream>>>(W1, aS1, aD1, wS1, wD1);
  k_wvec<64, 64><<<1, 256, 0, stream>>>(W2, aS2, aD2, wS2, wD2);
  k_wvec<64, 32><<<1, 256, 0, stream>>>(W3, aS3, aD3, wS3, wD3);
  k_wcvt<64><<<8, 256, 0, stream>>>(W2, wfrag2);
  k_wcvt<32><<<4, 256, 0, stream>>>(W3, wfrag3);

  int nblk = cdiv(N_NODES, 4);
  int npost = cdiv(N_NODES, 64);

  // ---- layer 1: gather raw x (8 fp32), VALU projection ----
  k_attdots1<<<cdiv(N_NODES, 256), 256, 0, stream>>>(x, wS1, wD1, (float4*)as_, (float4*)ad_);
  k_agg<8, float, false><<<nblk, 256, 0, stream>>>(indptr, esrc, x, (const float4*)as_,
                                                   (const float4*)ad_, acc16, 0);
  k_post<8, 64, 8><<<cdiv(N_NODES, 8), 256, 0, stream>>>(acc16, W1, b1, tbuf);
  k_bnstat<64><<<256, 256, 0, stream>>>(tbuf, part);
  k_bnfinal<64><<<1, 64, 0, stream>>>(part, g1, be1, scale, shift);

  // ---- layer 2: gather xhat (64 fp16), MFMA projection ----
  k_bnx<<<nblk, 256, 0, stream>>>(tbuf, scale, shift, wS2, wD2, xhat, (float4*)as_, (float4*)ad_);
  k_agg<64, __half, true><<<nblk, 256, 0, stream>>>(indptr, esrc, xhat, (const float4*)as_,
                                                    (const float4*)ad_, accp, PSTR);
  k_post_mfma<64><<<npost, 256, 0, stream>>>(accp, PSTR, wfrag2, b2, tbuf);
  k_bnstat<64><<<256, 256, 0, stream>>>(tbuf, part);
  k_bnfinal<64><<<1, 64, 0, stream>>>(part, g2, be2, scale, shift);

  // ---- layer 3: gather xhat (64 fp16), MFMA projection (DOUT=32) ----
  k_bnx<<<nblk, 256, 0, stream>>>(tbuf, scale, shift, wS3, wD3, xhat, (float4*)as_, (float4*)ad_);
  k_agg<64, __half, true><<<nblk, 256, 0, stream>>>(indptr, esrc, xhat, (const float4*)as_,
                                                    (const float4*)ad_, accp, PSTR);
  k_post_mfma<32><<<npost, 256, 0, stream>>>(accp, PSTR, wfrag3, b3, tbuf);
  k_bnstat<32><<<256, 256, 0, stream>>>(tbuf, part);
  k_bnfinal<32><<<1, 32, 0, stream>>>(part, g3, be3, scale, shift);

  // ---- pool (BN3 on load) + MLP ----
  k_pool<<<cdiv(N_NODES, POOL_NPB), 256, 0, stream>>>(tbuf, batch, scale, shift, pool, cntg);
  k_mlp<<<1, 64, 0, stream>>>(pool, cntg, Wp1, bp1, Wp2, bp2, out);
}

// Round 8
// 674.545 us; speedup vs baseline: 3.4492x; 1.2880x over previous
//
#include <hip/hip_runtime.h>
#include <hip/hip_fp16.h>

#define N_NODES 100000
#define N_EDGES 1600000
#define EP (N_EDGES + N_NODES)
#define NG 64
#define NH 4
#define SCAN_CHUNK 512
#define POOL_NPB 2048

static inline int cdiv(int a, int b) { return (a + b - 1) / b; }

typedef _Float16 half8 __attribute__((ext_vector_type(8)));
typedef float f32x4 __attribute__((ext_vector_type(4)));

__device__ __forceinline__ float lrelu(float x) { return x >= 0.f ? x : 0.2f * x; }

// ---------------- CSR build ----------------
__global__ void k_count(const int* __restrict__ ei, int* __restrict__ cnt) {
  int e = blockIdx.x * blockDim.x + threadIdx.x;
  if (e < N_EDGES) atomicAdd(&cnt[ei[N_EDGES + e]], 1);
  else if (e < EP) atomicAdd(&cnt[e - N_EDGES], 1);  // self loop
}

__global__ __launch_bounds__(512) void k_scan_partial(const int* __restrict__ cnt,
                                                      int* __restrict__ bsum) {
  __shared__ int sh[SCAN_CHUNK];
  int t = threadIdx.x;
  int idx = blockIdx.x * SCAN_CHUNK + t;
  sh[t] = (idx < N_NODES) ? cnt[idx] : 0;
  __syncthreads();
  for (int s = SCAN_CHUNK / 2; s; s >>= 1) {
    if (t < s) sh[t] += sh[t + s];
    __syncthreads();
  }
  if (t == 0) bsum[blockIdx.x] = sh[0];
}

__global__ void k_scan_bsum(int* __restrict__ bsum, int nb) {
  __shared__ int sh[256];
  int t = threadIdx.x;
  int v = (t < nb) ? bsum[t] : 0;
  sh[t] = v;
  __syncthreads();
  for (int off = 1; off < 256; off <<= 1) {
    int add = (t >= off) ? sh[t - off] : 0;
    __syncthreads();
    sh[t] += add;
    __syncthreads();
  }
  if (t < nb) bsum[t] = sh[t] - v;  // exclusive
}

__global__ __launch_bounds__(512) void k_scan_final(const int* __restrict__ cnt,
                                                    const int* __restrict__ bsum,
                                                    int* __restrict__ indptr) {
  __shared__ int sh[SCAN_CHUNK];
  int t = threadIdx.x;
  int idx = blockIdx.x * SCAN_CHUNK + t;
  sh[t] = (idx < N_NODES) ? cnt[idx] : 0;
  __syncthreads();
  for (int off = 1; off < SCAN_CHUNK; off <<= 1) {
    int add = (t >= off) ? sh[t - off] : 0;
    __syncthreads();
    sh[t] += add;
    __syncthreads();
  }
  if (idx < N_NODES) indptr[idx + 1] = bsum[blockIdx.x] + sh[t];
  if (idx == 0) indptr[0] = 0;
}

__global__ void k_scatter(const int* __restrict__ ei, const int* __restrict__ indptr,
                          int* __restrict__ epos, int* __restrict__ esrc) {
  int e = blockIdx.x * blockDim.x + threadIdx.x;
  if (e < N_EDGES) {
    int d = ei[N_EDGES + e], s = ei[e];
    int p = atomicAdd(&epos[d], 1);
    esrc[indptr[d] + p] = s;
  } else if (e < EP) {
    int nn = e - N_EDGES;
    int p = atomicAdd(&epos[nn], 1);
    esrc[indptr[nn] + p] = nn;
  }
}

// ---------------- prep: attention-fold vectors + MFMA B-fragment packing ----------------
template <int FIN, int D>
__device__ void wvec_impl(const float* __restrict__ W, const float* __restrict__ aS,
                          const float* __restrict__ aD, float* __restrict__ wS,
                          float* __restrict__ wD, int t) {
  if (t >= 4 * FIN) return;
  int h = t / FIN, k = t % FIN;
  float ss = 0.f, dd = 0.f;
  for (int d = 0; d < D; d++) {
    float w = W[k * (4 * D) + h * D + d];
    ss = fmaf(w, aS[h * D + d], ss);
    dd = fmaf(w, aD[h * D + d], dd);
  }
  wS[h * FIN + k] = ss;
  wD[h * FIN + k] = dd;
}

// B-frag over kk = dim*4 + head contraction: lane l holds B[kk = kt*32+(l>>4)*8+j][col = ct*16+(l&15)]
template <int D>
__device__ void wcvt_frag(const float* __restrict__ W, __half* __restrict__ wf, int frag, int l) {
  constexpr int NCT = D / 16;
  int kt = frag / NCT, ct = frag % NCT;
  half8 v;
#pragma unroll
  for (int j = 0; j < 8; j++) {
    int kk = kt * 32 + (l >> 4) * 8 + j;
    int k = kk >> 2, h = kk & 3;
    v[j] = (_Float16)W[k * (4 * D) + h * D + ct * 16 + (l & 15)];
  }
  *(half8*)(wf + (size_t)frag * 512 + l * 8) = v;
}

__global__ __launch_bounds__(256) void k_prep(const float* W1, const float* aS1, const float* aD1,
                                              const float* W2, const float* aS2, const float* aD2,
                                              const float* W3, const float* aS3, const float* aD3,
                                              float* wS1, float* wD1, float* wS2, float* wD2,
                                              float* wS3, float* wD3,
                                              __half* wf1, __half* wf2, __half* wf3) {
  int b = blockIdx.x, t = threadIdx.x;
  int f = t >> 6, l = t & 63;
  if (b == 0) wvec_impl<8, 64>(W1, aS1, aD1, wS1, wD1, t);
  else if (b == 1) wvec_impl<64, 64>(W2, aS2, aD2, wS2, wD2, t);
  else if (b == 2) wvec_impl<64, 32>(W3, aS3, aD3, wS3, wD3, t);
  else if (b == 3) wcvt_frag<64>(W1, wf1, f, l);                    // FIN=8 -> 4 frags
  else if (b < 12) wcvt_frag<64>(W2, wf2, (b - 4) * 4 + f, l);      // 32 frags
  else wcvt_frag<32>(W3, wf3, (b - 12) * 4 + f, l);                 // 16 frags
}

// ---------------- layer-1 attention dots from raw x (FIN=8) ----------------
__global__ void k_attdots1(const float* __restrict__ x, const float* __restrict__ wS,
                           const float* __restrict__ wD, float4* __restrict__ as4,
                           float4* __restrict__ ad4) {
  int n = blockIdx.x * blockDim.x + threadIdx.x;
  if (n >= N_NODES) return;
  float4 s = {0, 0, 0, 0}, d = {0, 0, 0, 0};
#pragma unroll
  for (int k = 0; k < 8; k++) {
    float xv = x[(size_t)n * 8 + k];
    s.x = fmaf(xv, wS[k], s.x);
    s.y = fmaf(xv, wS[8 + k], s.y);
    s.z = fmaf(xv, wS[16 + k], s.z);
    s.w = fmaf(xv, wS[24 + k], s.w);
    d.x = fmaf(xv, wD[k], d.x);
    d.y = fmaf(xv, wD[8 + k], d.y);
    d.z = fmaf(xv, wD[16 + k], d.z);
    d.w = fmaf(xv, wD[24 + k], d.w);
  }
  as4[n] = s;
  ad4[n] = d;
}

// ---------------- BN-apply + fp16 cast + attention dots (FIN=64) ----------------
__global__ __launch_bounds__(256) void k_bnx(const float* __restrict__ tbuf,
                                             const float* __restrict__ scale,
                                             const float* __restrict__ shift,
                                             const float* __restrict__ wS,
                                             const float* __restrict__ wD,
                                             __half* __restrict__ xhat,
                                             float4* __restrict__ as4, float4* __restrict__ ad4) {
  int lane = threadIdx.x & 63;
  int n = blockIdx.x * 4 + (threadIdx.x >> 6);
  if (n >= N_NODES) return;
  float v = fmaf(tbuf[(size_t)n * 64 + lane], scale[lane], shift[lane]);
  xhat[(size_t)n * 64 + lane] = __float2half(v);
  float p0 = v * wS[lane], p1 = v * wS[64 + lane], p2 = v * wS[128 + lane], p3 = v * wS[192 + lane];
  float q0 = v * wD[lane], q1 = v * wD[64 + lane], q2 = v * wD[128 + lane], q3 = v * wD[192 + lane];
#pragma unroll
  for (int off = 32; off; off >>= 1) {
    p0 += __shfl_xor(p0, off); p1 += __shfl_xor(p1, off);
    p2 += __shfl_xor(p2, off); p3 += __shfl_xor(p3, off);
    q0 += __shfl_xor(q0, off); q1 += __shfl_xor(q1, off);
    q2 += __shfl_xor(q2, off); q3 += __shfl_xor(q3, off);
  }
  if (lane == 0) {
    as4[n] = make_float4(p0, p1, p2, p3);
    ad4[n] = make_float4(q0, q1, q2, q3);
  }
}

// ---------------- fused softmax-weight + gather (GL-lane group per node) ----------------
// Wave = 64/GL nodes concurrently. Per chunk of GL edges: lane-parallel weight computation
// staged to LDS (stride GL+1 to spread banks), then group-serial gather where each lane
// covers DIN/GL dims x 4 heads. Output: interleaved halves [n][kk = dim*4 + head].
template <int DIN, typename TX, int GSH>
__global__ __launch_bounds__(256) void k_agg(const int* __restrict__ indptr,
                                             const int* __restrict__ esrc,
                                             const TX* __restrict__ xg,
                                             const float4* __restrict__ as4,
                                             const float4* __restrict__ ad4,
                                             __half* __restrict__ accO) {
  constexpr int GL = 1 << GSH;       // lanes per group
  constexpr int NPW = 64 >> GSH;     // nodes per wave
  constexpr int DPL = DIN / GL;      // dims per lane (4 or 1)
  constexpr int SH = (sizeof(TX) == 2) ? 7 : 5;  // row byte shift (128B or 32B)
  constexpr int WB = NPW * (GL + 1); // per-wave LDS stride (bank spread)
  __shared__ int sOff[4 * WB];
  __shared__ float4 sW[4 * WB];
  int tid = threadIdx.x;
  int lane = tid & 63;
  int wv = tid >> 6;
  int q = lane & (GL - 1);
  int g = lane >> GSH;
  int n = blockIdx.x * (4 * NPW) + wv * NPW + g;
  if (n >= N_NODES) return;
  int e0 = indptr[n], e1 = indptr[n + 1];
  float4 ad = ad4[n];
  int lbase = wv * WB + g * (GL + 1);
  const char* xb = (const char*)xg + q * DPL * (int)sizeof(TX);
  float s0 = 0.f, s1 = 0.f, s2 = 0.f, s3 = 0.f;
  float a[DPL][4];
#pragma unroll
  for (int d = 0; d < DPL; d++)
#pragma unroll
    for (int h = 0; h < 4; h++) a[d][h] = 0.f;

  for (int c = e0; c < e1; c += GL) {
    int nc = min(GL, e1 - c);
    float w0 = 0.f, w1 = 0.f, w2 = 0.f, w3 = 0.f;
    int sB = 0;
    if (q < nc) {
      int sidx = esrc[c + q];
      float4 av = as4[sidx];
      w0 = __expf(lrelu(av.x + ad.x));
      w1 = __expf(lrelu(av.y + ad.y));
      w2 = __expf(lrelu(av.z + ad.z));
      w3 = __expf(lrelu(av.w + ad.w));
      sB = sidx << SH;
    }
    s0 += w0; s1 += w1; s2 += w2; s3 += w3;
    sOff[lbase + q] = sB;
    sW[lbase + q] = make_float4(w0, w1, w2, w3);
    __builtin_amdgcn_wave_barrier();
    for (int i = 0; i < nc; ++i) {
      float4 w = sW[lbase + i];
      int ob = sOff[lbase + i];
      if constexpr (DPL == 4) {
        uint2 px = *(const uint2*)(xb + ob);
        float2 f01 = __half22float2(*(const __half2*)&px.x);
        float2 f23 = __half22float2(*(const __half2*)&px.y);
        a[0][0] = fmaf(w.x, f01.x, a[0][0]); a[0][1] = fmaf(w.y, f01.x, a[0][1]);
        a[0][2] = fmaf(w.z, f01.x, a[0][2]); a[0][3] = fmaf(w.w, f01.x, a[0][3]);
        a[1][0] = fmaf(w.x, f01.y, a[1][0]); a[1][1] = fmaf(w.y, f01.y, a[1][1]);
        a[1][2] = fmaf(w.z, f01.y, a[1][2]); a[1][3] = fmaf(w.w, f01.y, a[1][3]);
        a[2][0] = fmaf(w.x, f23.x, a[2][0]); a[2][1] = fmaf(w.y, f23.x, a[2][1]);
        a[2][2] = fmaf(w.z, f23.x, a[2][2]); a[2][3] = fmaf(w.w, f23.x, a[2][3]);
        a[3][0] = fmaf(w.x, f23.y, a[3][0]); a[3][1] = fmaf(w.y, f23.y, a[3][1]);
        a[3][2] = fmaf(w.z, f23.y, a[3][2]); a[3][3] = fmaf(w.w, f23.y, a[3][3]);
      } else {
        float xv = *(const float*)(xb + ob);
        a[0][0] = fmaf(w.x, xv, a[0][0]);
        a[0][1] = fmaf(w.y, xv, a[0][1]);
        a[0][2] = fmaf(w.z, xv, a[0][2]);
        a[0][3] = fmaf(w.w, xv, a[0][3]);
      }
    }
    __builtin_amdgcn_wave_barrier();
  }
  // reduce sums within the group
#pragma unroll
  for (int off = 1; off < GL; off <<= 1) {
    s0 += __shfl_xor(s0, off);
    s1 += __shfl_xor(s1, off);
    s2 += __shfl_xor(s2, off);
    s3 += __shfl_xor(s3, off);
  }
  float r0 = 1.f / (s0 + 1e-16f), r1 = 1.f / (s1 + 1e-16f);
  float r2 = 1.f / (s2 + 1e-16f), r3 = 1.f / (s3 + 1e-16f);
  if constexpr (DPL == 4) {
    __half2 p[8];
#pragma unroll
    for (int d = 0; d < 4; d++) {
      p[2 * d] = __floats2half2_rn(a[d][0] * r0, a[d][1] * r1);
      p[2 * d + 1] = __floats2half2_rn(a[d][2] * r2, a[d][3] * r3);
    }
    uint4 lo = make_uint4(*(unsigned*)&p[0], *(unsigned*)&p[1], *(unsigned*)&p[2], *(unsigned*)&p[3]);
    uint4 hi = make_uint4(*(unsigned*)&p[4], *(unsigned*)&p[5], *(unsigned*)&p[6], *(unsigned*)&p[7]);
    *(uint4*)(accO + (size_t)n * 256 + q * 16) = lo;
    *(uint4*)(accO + (size_t)n * 256 + q * 16 + 8) = hi;
  } else {
    __half2 p01 = __floats2half2_rn(a[0][0] * r0, a[0][1] * r1);
    __half2 p23 = __floats2half2_rn(a[0][2] * r2, a[0][3] * r3);
    uint2 pk = make_uint2(*(unsigned*)&p01, *(unsigned*)&p23);
    *(uint2*)(accO + (size_t)n * 32 + q * 4) = pk;
  }
}

// ---------------- MFMA projection: tbuf = relu(0.25 * acc @ Bkk + bias) ----------------
// kk-contraction folds heads: A[n][kk=dim*4+h], B[kk][col] = W[dim][h*DOUT+col].
template <int DOUT, int NK>
__global__ __launch_bounds__(256) void k_post_mfma(const __half* __restrict__ accA,
                                                   const __half* __restrict__ wfrag,
                                                   const float* __restrict__ bias,
                                                   float* __restrict__ tbuf) {
  constexpr int NCT = DOUT / 16;
  constexpr int AS = NK * 32;
  int l = threadIdx.x & 63;
  int n0 = (blockIdx.x * 4 + (threadIdx.x >> 6)) * 16;
  int m = l & 15, kg = l >> 4;
  f32x4 c[NCT];
#pragma unroll
  for (int ct = 0; ct < NCT; ct++) c[ct] = (f32x4){0.f, 0.f, 0.f, 0.f};
#pragma unroll
  for (int kt = 0; kt < NK; kt++) {
    half8 a = *(const half8*)(accA + (size_t)(n0 + m) * AS + kt * 32 + kg * 8);
#pragma unroll
    for (int ct = 0; ct < NCT; ct++) {
      half8 b = *(const half8*)(wfrag + ((kt * NCT + ct) * 64 + l) * 8);
      c[ct] = __builtin_amdgcn_mfma_f32_16x16x32_f16(a, b, c[ct], 0, 0, 0);
    }
  }
#pragma unroll
  for (int ct = 0; ct < NCT; ct++) {
    float bv = bias[ct * 16 + m];
#pragma unroll
    for (int j = 0; j < 4; j++) {
      int n = n0 + kg * 4 + j;
      if (n < N_NODES) tbuf[(size_t)n * DOUT + ct * 16 + m] = fmaxf(fmaf(c[ct][j], 0.25f, bv), 0.f);
    }
  }
}

// ---------------- batch norm stats ----------------
template <int C>
__global__ __launch_bounds__(256) void k_bnstat(const float* __restrict__ x, float* __restrict__ part) {
  const int RG = 256 / C;
  int col = threadIdx.x & (C - 1);
  int rg = threadIdx.x / C;
  int rows = (N_NODES + gridDim.x - 1) / gridDim.x;
  int r0 = blockIdx.x * rows;
  int r1 = min(N_NODES, r0 + rows);
  float s = 0.f, q = 0.f;
  for (int r = r0 + rg; r < r1; r += RG) {
    float v = x[(size_t)r * C + col];
    s += v;
    q = fmaf(v, v, q);
  }
  __shared__ float sh[512];
  sh[threadIdx.x] = s;
  sh[256 + threadIdx.x] = q;
  __syncthreads();
  for (int step = 128; step >= C; step >>= 1) {
    if (threadIdx.x < step) {
      sh[threadIdx.x] += sh[threadIdx.x + step];
      sh[256 + threadIdx.x] += sh[256 + threadIdx.x + step];
    }
    __syncthreads();
  }
  if (threadIdx.x < C) {
    part[blockIdx.x * 2 * C + threadIdx.x] = sh[threadIdx.x];
    part[blockIdx.x * 2 * C + C + threadIdx.x] = sh[256 + threadIdx.x];
  }
}

template <int C>
__global__ void k_bnfinal(const float* __restrict__ part, const float* __restrict__ g,
                          const float* __restrict__ be, float* __restrict__ scale,
                          float* __restrict__ shift) {
  int c = threadIdx.x;
  if (c >= C) return;
  float s = 0.f, q = 0.f;
  for (int b = 0; b < 256; b++) {
    s += part[b * 2 * C + c];
    q += part[b * 2 * C + C + c];
  }
  float mean = s / (float)N_NODES;
  float var = q / (float)N_NODES - mean * mean;
  float sc = g[c] * rsqrtf(var + 1e-5f);
  scale[c] = sc;
  shift[c] = be[c] - mean * sc;
}

// ---------------- pooling (applies layer-3 BN on load; batch sorted) ----------------
__global__ __launch_bounds__(256) void k_pool(const float* __restrict__ f3,
                                              const int* __restrict__ batch,
                                              const float* __restrict__ scale,
                                              const float* __restrict__ shift,
                                              float* __restrict__ pool,
                                              float* __restrict__ cntg) {
  __shared__ float acc[NG][33];
  int t = threadIdx.x;
  for (int i = t; i < NG * 33; i += 256) ((float*)acc)[i] = 0.f;
  __syncthreads();
  int c = t & 31, rg = t >> 5;
  float sc = scale[c], sh = shift[c];
  int n0 = blockIdx.x * POOL_NPB;
  int n1 = min(N_NODES, n0 + POOL_NPB);
  float r = 0.f, rc = 0.f;
  int gcur = -1;
  for (int n = n0 + rg; n < n1; n += 8) {
    int g = batch[n];
    if (g != gcur) {
      if (gcur >= 0) {
        atomicAdd(&acc[gcur][c], r);
        if (c == 0) atomicAdd(&acc[gcur][32], rc);
      }
      gcur = g;
      r = 0.f;
      rc = 0.f;
    }
    r += fmaf(f3[(size_t)n * 32 + c], sc, sh);
    rc += 1.f;
  }
  if (gcur >= 0) {
    atomicAdd(&acc[gcur][c], r);
    if (c == 0) atomicAdd(&acc[gcur][32], rc);
  }
  __syncthreads();
  for (int i = t; i < NG * 32; i += 256) {
    int g = i >> 5, cc = i & 31;
    float v = acc[g][cc];
    if (v != 0.f) atomicAdd(&pool[i], v);
  }
  for (int g = t; g < NG; g += 256) {
    float v = acc[g][32];
    if (v != 0.f) atomicAdd(&cntg[g], v);
  }
}

__global__ void k_mlp(const float* __restrict__ pool, const float* __restrict__ cntg,
                      const float* __restrict__ Wp1, const float* __restrict__ bp1,
                      const float* __restrict__ Wp2, const float* __restrict__ bp2,
                      float* __restrict__ out) {
  int g = threadIdx.x;
  if (g >= NG) return;
  float inv = 1.f / fmaxf(cntg[g], 1.f);
  float p[32];
#pragma unroll
  for (int c = 0; c < 32; c++) p[c] = pool[g * 32 + c] * inv;
  float o = bp2[0];
  for (int j = 0; j < 16; j++) {
    float hsum = bp1[j];
#pragma unroll
    for (int c = 0; c < 32; c++) hsum = fmaf(p[c], Wp1[c * 16 + j], hsum);
    o = fmaf(fmaxf(hsum, 0.f), Wp2[j], o);
  }
  out[g] = o;
}

extern "C" void kernel_launch(void* const* d_in, const int* in_sizes, int n_in,
                              void* d_out, int out_size, void* d_ws, size_t ws_size,
                              hipStream_t stream) {
  const float* x = (const float*)d_in[0];
  const int* ei = (const int*)d_in[1];
  const int* batch = (const int*)d_in[2];
  const float* W1 = (const float*)d_in[3];
  const float* aS1 = (const float*)d_in[4];
  const float* aD1 = (const float*)d_in[5];
  const float* b1 = (const float*)d_in[6];
  const float* g1 = (const float*)d_in[7];
  const float* be1 = (const float*)d_in[8];
  const float* W2 = (const float*)d_in[9];
  const float* aS2 = (const float*)d_in[10];
  const float* aD2 = (const float*)d_in[11];
  const float* b2 = (const float*)d_in[12];
  const float* g2 = (const float*)d_in[13];
  const float* be2 = (const float*)d_in[14];
  const float* W3 = (const float*)d_in[15];
  const float* aS3 = (const float*)d_in[16];
  const float* aD3 = (const float*)d_in[17];
  const float* b3 = (const float*)d_in[18];
  const float* g3 = (const float*)d_in[19];
  const float* be3 = (const float*)d_in[20];
  const float* Wp1 = (const float*)d_in[21];
  const float* bp1 = (const float*)d_in[22];
  const float* Wp2 = (const float*)d_in[23];
  const float* bp2 = (const float*)d_in[24];
  float* out = (float*)d_out;

  size_t off = 0;
  auto alloc = [&](size_t bytes) -> void* {
    void* p = (char*)d_ws + off;
    off += (bytes + 255) & ~(size_t)255;
    return p;
  };
  // zeroed region (single memset): cnt, epos, pool, cntg
  int* cnt = (int*)alloc((size_t)N_NODES * 4);
  int* epos = (int*)alloc((size_t)N_NODES * 4);
  float* pool = (float*)alloc((size_t)NG * 32 * 4);
  float* cntg = (float*)alloc((size_t)NG * 4);
  size_t zbytes = off;
  int* indptr = (int*)alloc((size_t)(N_NODES + 1) * 4);
  int* esrc = (int*)alloc((size_t)EP * 4);
  int* bsum = (int*)alloc((size_t)256 * 4);
  __half* xhat = (__half*)alloc((size_t)N_NODES * 64 * 2);
  __half* acc16 = (__half*)alloc((size_t)(N_NODES + 16) * 256 * 2);  // interleaved [n][kk]
  float* as_ = (float*)alloc((size_t)N_NODES * 16);
  float* ad_ = (float*)alloc((size_t)N_NODES * 16);
  float* tbuf = (float*)alloc((size_t)N_NODES * 64 * 4);
  float* part = (float*)alloc((size_t)256 * 128 * 4);
  float* scale = (float*)alloc(64 * 4);
  float* shift = (float*)alloc(64 * 4);
  float* wS1 = (float*)alloc(32 * 4);
  float* wD1 = (float*)alloc(32 * 4);
  float* wS2 = (float*)alloc(256 * 4);
  float* wD2 = (float*)alloc(256 * 4);
  float* wS3 = (float*)alloc(256 * 4);
  float* wD3 = (float*)alloc(256 * 4);
  __half* wf1 = (__half*)alloc((size_t)4 * 512 * 2);
  __half* wf2 = (__half*)alloc((size_t)32 * 512 * 2);
  __half* wf3 = (__half*)alloc((size_t)16 * 512 * 2);
  if (off > ws_size) return;

  hipMemsetAsync(cnt, 0, zbytes, stream);

  int nscan = cdiv(N_NODES, SCAN_CHUNK);
  k_count<<<cdiv(EP, 256), 256, 0, stream>>>(ei, cnt);
  k_scan_partial<<<nscan, SCAN_CHUNK, 0, stream>>>(cnt, bsum);
  k_scan_bsum<<<1, 256, 0, stream>>>(bsum, nscan);
  k_scan_final<<<nscan, SCAN_CHUNK, 0, stream>>>(cnt, bsum, indptr);
  k_scatter<<<cdiv(EP, 256), 256, 0, stream>>>(ei, indptr, epos, esrc);

  k_prep<<<16, 256, 0, stream>>>(W1, aS1, aD1, W2, aS2, aD2, W3, aS3, aD3,
                                 wS1, wD1, wS2, wD2, wS3, wD3, wf1, wf2, wf3);

  int npost = cdiv(N_NODES, 64);

  // ---- layer 1: gather raw x (8 fp32, 8-lane groups), MFMA projection (NK=1) ----
  k_attdots1<<<cdiv(N_NODES, 256), 256, 0, stream>>>(x, wS1, wD1, (float4*)as_, (float4*)ad_);
  k_agg<8, float, 3><<<cdiv(N_NODES, 32), 256, 0, stream>>>(indptr, esrc, x, (const float4*)as_,
                                                            (const float4*)ad_, acc16);
  k_post_mfma<64, 1><<<npost, 256, 0, stream>>>(acc16, wf1, b1, tbuf);
  k_bnstat<64><<<256, 256, 0, stream>>>(tbuf, part);
  k_bnfinal<64><<<1, 64, 0, stream>>>(part, g1, be1, scale, shift);

  // ---- layer 2: gather xhat (64 fp16, 16-lane groups), MFMA projection (NK=8) ----
  k_bnx<<<cdiv(N_NODES, 4), 256, 0, stream>>>(tbuf, scale, shift, wS2, wD2, xhat,
                                              (float4*)as_, (float4*)ad_);
  k_agg<64, __half, 4><<<cdiv(N_NODES, 16), 256, 0, stream>>>(indptr, esrc, xhat,
                                                              (const float4*)as_,
                                                              (const float4*)ad_, acc16);
  k_post_mfma<64, 8><<<npost, 256, 0, stream>>>(acc16, wf2, b2, tbuf);
  k_bnstat<64><<<256, 256, 0, stream>>>(tbuf, part);
  k_bnfinal<64><<<1, 64, 0, stream>>>(part, g2, be2, scale, shift);

  // ---- layer 3: gather xhat (64 fp16), MFMA projection (DOUT=32, NK=8) ----
  k_bnx<<<cdiv(N_NODES, 4), 256, 0, stream>>>(tbuf, scale, shift, wS3, wD3, xhat,
                                              (float4*)as_, (float4*)ad_);
  k_agg<64, __half, 4><<<cdiv(N_NODES, 16), 256, 0, stream>>>(indptr, esrc, xhat,
                                                              (const float4*)as_,
                                                              (const float4*)ad_, acc16);
  k_post_mfma<32, 8><<<npost, 256, 0, stream>>>(acc16, wf3, b3, tbuf);
  k_bnstat<32><<<256, 256, 0, stream>>>(tbuf, part);
  k_bnfinal<32><<<1, 32, 0, stream>>>(part, g3, be3, scale, shift);

  // ---- pool (BN3 on load) + MLP ----
  k_pool<<<cdiv(N_NODES, POOL_NPB), 256, 0, stream>>>(tbuf, batch, scale, shift, pool, cntg);
  k_mlp<<<1, 64, 0, stream>>>(pool, cntg, Wp1, bp1, Wp2, bp2, out);
}

// Round 9
// 661.178 us; speedup vs baseline: 3.5189x; 1.0202x over previous
//
#include <hip/hip_runtime.h>
#include <hip/hip_fp16.h>

#define N_NODES 100000
#define N_EDGES 1600000
#define EP (N_EDGES + N_NODES)
#define NG 64
#define NH 4
#define SCAN_CHUNK 512
#define POOL_NPB 2048
#define NPART 8
#define PART_SZ 12500  // N_NODES / NPART

static inline int cdiv(int a, int b) { return (a + b - 1) / b; }

typedef _Float16 half8 __attribute__((ext_vector_type(8)));
typedef float f32x4 __attribute__((ext_vector_type(4)));

__device__ __forceinline__ float lrelu(float x) { return x >= 0.f ? x : 0.2f * x; }

// ---------------- CSR build (XCD-partitioned: group = blockIdx&7 owns a dst range) ----------------
__global__ __launch_bounds__(256) void k_count(const int* __restrict__ ei, int* __restrict__ cnt) {
  int grp = blockIdx.x & (NPART - 1);
  int lo = grp * PART_SZ, hi = lo + PART_SZ;  // last range covers exactly (100000 = 8*12500)
  int nb = gridDim.x >> 3;
  int bid = blockIdx.x >> 3;
  for (int e = bid * 256 + threadIdx.x; e < EP; e += nb * 256) {
    int d = (e < N_EDGES) ? ei[N_EDGES + e] : (e - N_EDGES);
    if (d >= lo && d < hi) atomicAdd(&cnt[d], 1);
  }
}

__global__ __launch_bounds__(512) void k_scan_partial(const int* __restrict__ cnt,
                                                      int* __restrict__ bsum) {
  __shared__ int sh[SCAN_CHUNK];
  int t = threadIdx.x;
  int idx = blockIdx.x * SCAN_CHUNK + t;
  sh[t] = (idx < N_NODES) ? cnt[idx] : 0;
  __syncthreads();
  for (int s = SCAN_CHUNK / 2; s; s >>= 1) {
    if (t < s) sh[t] += sh[t + s];
    __syncthreads();
  }
  if (t == 0) bsum[blockIdx.x] = sh[0];
}

__global__ void k_scan_bsum(int* __restrict__ bsum, int nb) {
  __shared__ int sh[256];
  int t = threadIdx.x;
  int v = (t < nb) ? bsum[t] : 0;
  sh[t] = v;
  __syncthreads();
  for (int off = 1; off < 256; off <<= 1) {
    int add = (t >= off) ? sh[t - off] : 0;
    __syncthreads();
    sh[t] += add;
    __syncthreads();
  }
  if (t < nb) bsum[t] = sh[t] - v;  // exclusive
}

__global__ __launch_bounds__(512) void k_scan_final(const int* __restrict__ cnt,
                                                    const int* __restrict__ bsum,
                                                    int* __restrict__ indptr) {
  __shared__ int sh[SCAN_CHUNK];
  int t = threadIdx.x;
  int idx = blockIdx.x * SCAN_CHUNK + t;
  sh[t] = (idx < N_NODES) ? cnt[idx] : 0;
  __syncthreads();
  for (int off = 1; off < SCAN_CHUNK; off <<= 1) {
    int add = (t >= off) ? sh[t - off] : 0;
    __syncthreads();
    sh[t] += add;
    __syncthreads();
  }
  if (idx < N_NODES) indptr[idx + 1] = bsum[blockIdx.x] + sh[t];
  if (idx == 0) indptr[0] = 0;
}

__global__ __launch_bounds__(256) void k_scatter(const int* __restrict__ ei,
                                                 const int* __restrict__ indptr,
                                                 int* __restrict__ epos, int* __restrict__ esrc) {
  int grp = blockIdx.x & (NPART - 1);
  int lo = grp * PART_SZ, hi = lo + PART_SZ;
  int nb = gridDim.x >> 3;
  int bid = blockIdx.x >> 3;
  for (int e = bid * 256 + threadIdx.x; e < EP; e += nb * 256) {
    if (e < N_EDGES) {
      int d = ei[N_EDGES + e];
      if (d >= lo && d < hi) {
        int s = ei[e];
        int p = atomicAdd(&epos[d], 1);
        esrc[indptr[d] + p] = s;
      }
    } else {
      int nn = e - N_EDGES;
      if (nn >= lo && nn < hi) {
        int p = atomicAdd(&epos[nn], 1);
        esrc[indptr[nn] + p] = nn;
      }
    }
  }
}

// ---------------- prep: attention-fold vectors + MFMA B-fragment packing ----------------
template <int FIN, int D>
__device__ void wvec_impl(const float* __restrict__ W, const float* __restrict__ aS,
                          const float* __restrict__ aD, float* __restrict__ wS,
                          float* __restrict__ wD, int t) {
  if (t >= 4 * FIN) return;
  int h = t / FIN, k = t % FIN;
  float ss = 0.f, dd = 0.f;
  for (int d = 0; d < D; d++) {
    float w = W[k * (4 * D) + h * D + d];
    ss = fmaf(w, aS[h * D + d], ss);
    dd = fmaf(w, aD[h * D + d], dd);
  }
  wS[h * FIN + k] = ss;
  wD[h * FIN + k] = dd;
}

// B-frag over kk = dim*4 + head contraction: lane l holds B[kk = kt*32+(l>>4)*8+j][col = ct*16+(l&15)]
template <int D>
__device__ void wcvt_frag(const float* __restrict__ W, __half* __restrict__ wf, int frag, int l) {
  constexpr int NCT = D / 16;
  int kt = frag / NCT, ct = frag % NCT;
  half8 v;
#pragma unroll
  for (int j = 0; j < 8; j++) {
    int kk = kt * 32 + (l >> 4) * 8 + j;
    int k = kk >> 2, h = kk & 3;
    v[j] = (_Float16)W[k * (4 * D) + h * D + ct * 16 + (l & 15)];
  }
  *(half8*)(wf + (size_t)frag * 512 + l * 8) = v;
}

__global__ __launch_bounds__(256) void k_prep(const float* W1, const float* aS1, const float* aD1,
                                              const float* W2, const float* aS2, const float* aD2,
                                              const float* W3, const float* aS3, const float* aD3,
                                              float* wS1, float* wD1, float* wS2, float* wD2,
                                              float* wS3, float* wD3,
                                              __half* wf1, __half* wf2, __half* wf3) {
  int b = blockIdx.x, t = threadIdx.x;
  int f = t >> 6, l = t & 63;
  if (b == 0) wvec_impl<8, 64>(W1, aS1, aD1, wS1, wD1, t);
  else if (b == 1) wvec_impl<64, 64>(W2, aS2, aD2, wS2, wD2, t);
  else if (b == 2) wvec_impl<64, 32>(W3, aS3, aD3, wS3, wD3, t);
  else if (b == 3) wcvt_frag<64>(W1, wf1, f, l);                    // FIN=8 -> 4 frags
  else if (b < 12) wcvt_frag<64>(W2, wf2, (b - 4) * 4 + f, l);      // 32 frags
  else wcvt_frag<32>(W3, wf3, (b - 12) * 4 + f, l);                 // 16 frags
}

// ---------------- layer-1 attention dots from raw x (FIN=8) ----------------
__global__ void k_attdots1(const float* __restrict__ x, const float* __restrict__ wS,
                           const float* __restrict__ wD, float4* __restrict__ as4,
                           float4* __restrict__ ad4) {
  int n = blockIdx.x * blockDim.x + threadIdx.x;
  if (n >= N_NODES) return;
  float4 s = {0, 0, 0, 0}, d = {0, 0, 0, 0};
#pragma unroll
  for (int k = 0; k < 8; k++) {
    float xv = x[(size_t)n * 8 + k];
    s.x = fmaf(xv, wS[k], s.x);
    s.y = fmaf(xv, wS[8 + k], s.y);
    s.z = fmaf(xv, wS[16 + k], s.z);
    s.w = fmaf(xv, wS[24 + k], s.w);
    d.x = fmaf(xv, wD[k], d.x);
    d.y = fmaf(xv, wD[8 + k], d.y);
    d.z = fmaf(xv, wD[16 + k], d.z);
    d.w = fmaf(xv, wD[24 + k], d.w);
  }
  as4[n] = s;
  ad4[n] = d;
}

// ---------------- BN-apply + fp16 cast + attention dots (FIN=64) ----------------
__global__ __launch_bounds__(256) void k_bnx(const float* __restrict__ tbuf,
                                             const float* __restrict__ scale,
                                             const float* __restrict__ shift,
                                             const float* __restrict__ wS,
                                             const float* __restrict__ wD,
                                             __half* __restrict__ xhat,
                                             float4* __restrict__ as4, float4* __restrict__ ad4) {
  int lane = threadIdx.x & 63;
  int n = blockIdx.x * 4 + (threadIdx.x >> 6);
  if (n >= N_NODES) return;
  float v = fmaf(tbuf[(size_t)n * 64 + lane], scale[lane], shift[lane]);
  xhat[(size_t)n * 64 + lane] = __float2half(v);
  float p0 = v * wS[lane], p1 = v * wS[64 + lane], p2 = v * wS[128 + lane], p3 = v * wS[192 + lane];
  float q0 = v * wD[lane], q1 = v * wD[64 + lane], q2 = v * wD[128 + lane], q3 = v * wD[192 + lane];
#pragma unroll
  for (int off = 32; off; off >>= 1) {
    p0 += __shfl_xor(p0, off); p1 += __shfl_xor(p1, off);
    p2 += __shfl_xor(p2, off); p3 += __shfl_xor(p3, off);
    q0 += __shfl_xor(q0, off); q1 += __shfl_xor(q1, off);
    q2 += __shfl_xor(q2, off); q3 += __shfl_xor(q3, off);
  }
  if (lane == 0) {
    as4[n] = make_float4(p0, p1, p2, p3);
    ad4[n] = make_float4(q0, q1, q2, q3);
  }
}

// ---------------- fused softmax-weight + gather (GL-lane group per node) ----------------
template <int DIN, typename TX, int GSH>
__global__ __launch_bounds__(256) void k_agg(const int* __restrict__ indptr,
                                             const int* __restrict__ esrc,
                                             const TX* __restrict__ xg,
                                             const float4* __restrict__ as4,
                                             const float4* __restrict__ ad4,
                                             __half* __restrict__ accO) {
  constexpr int GL = 1 << GSH;       // lanes per group
  constexpr int NPW = 64 >> GSH;     // nodes per wave
  constexpr int DPL = DIN / GL;      // dims per lane (4 or 1)
  constexpr int SH = (sizeof(TX) == 2) ? 7 : 5;  // row byte shift (128B or 32B)
  constexpr int WB = NPW * (GL + 1); // per-wave LDS stride (bank spread)
  __shared__ int sOff[4 * WB];
  __shared__ float4 sW[4 * WB];
  int tid = threadIdx.x;
  int lane = tid & 63;
  int wv = tid >> 6;
  int q = lane & (GL - 1);
  int g = lane >> GSH;
  int n = blockIdx.x * (4 * NPW) + wv * NPW + g;
  if (n >= N_NODES) return;
  int e0 = indptr[n], e1 = indptr[n + 1];
  float4 ad = ad4[n];
  int lbase = wv * WB + g * (GL + 1);
  const char* xb = (const char*)xg + q * DPL * (int)sizeof(TX);
  float s0 = 0.f, s1 = 0.f, s2 = 0.f, s3 = 0.f;
  float a[DPL][4];
#pragma unroll
  for (int d = 0; d < DPL; d++)
#pragma unroll
    for (int h = 0; h < 4; h++) a[d][h] = 0.f;

  for (int c = e0; c < e1; c += GL) {
    int nc = min(GL, e1 - c);
    float w0 = 0.f, w1 = 0.f, w2 = 0.f, w3 = 0.f;
    int sB = 0;
    if (q < nc) {
      int sidx = esrc[c + q];
      float4 av = as4[sidx];
      w0 = __expf(lrelu(av.x + ad.x));
      w1 = __expf(lrelu(av.y + ad.y));
      w2 = __expf(lrelu(av.z + ad.z));
      w3 = __expf(lrelu(av.w + ad.w));
      sB = sidx << SH;
    }
    s0 += w0; s1 += w1; s2 += w2; s3 += w3;
    sOff[lbase + q] = sB;
    sW[lbase + q] = make_float4(w0, w1, w2, w3);
    __builtin_amdgcn_wave_barrier();
    for (int i = 0; i < nc; ++i) {
      float4 w = sW[lbase + i];
      int ob = sOff[lbase + i];
      if constexpr (DPL == 4) {
        uint2 px = *(const uint2*)(xb + ob);
        float2 f01 = __half22float2(*(const __half2*)&px.x);
        float2 f23 = __half22float2(*(const __half2*)&px.y);
        a[0][0] = fmaf(w.x, f01.x, a[0][0]); a[0][1] = fmaf(w.y, f01.x, a[0][1]);
        a[0][2] = fmaf(w.z, f01.x, a[0][2]); a[0][3] = fmaf(w.w, f01.x, a[0][3]);
        a[1][0] = fmaf(w.x, f01.y, a[1][0]); a[1][1] = fmaf(w.y, f01.y, a[1][1]);
        a[1][2] = fmaf(w.z, f01.y, a[1][2]); a[1][3] = fmaf(w.w, f01.y, a[1][3]);
        a[2][0] = fmaf(w.x, f23.x, a[2][0]); a[2][1] = fmaf(w.y, f23.x, a[2][1]);
        a[2][2] = fmaf(w.z, f23.x, a[2][2]); a[2][3] = fmaf(w.w, f23.x, a[2][3]);
        a[3][0] = fmaf(w.x, f23.y, a[3][0]); a[3][1] = fmaf(w.y, f23.y, a[3][1]);
        a[3][2] = fmaf(w.z, f23.y, a[3][2]); a[3][3] = fmaf(w.w, f23.y, a[3][3]);
      } else {
        float xv = *(const float*)(xb + ob);
        a[0][0] = fmaf(w.x, xv, a[0][0]);
        a[0][1] = fmaf(w.y, xv, a[0][1]);
        a[0][2] = fmaf(w.z, xv, a[0][2]);
        a[0][3] = fmaf(w.w, xv, a[0][3]);
      }
    }
    __builtin_amdgcn_wave_barrier();
  }
#pragma unroll
  for (int off = 1; off < GL; off <<= 1) {
    s0 += __shfl_xor(s0, off);
    s1 += __shfl_xor(s1, off);
    s2 += __shfl_xor(s2, off);
    s3 += __shfl_xor(s3, off);
  }
  float r0 = 1.f / (s0 + 1e-16f), r1 = 1.f / (s1 + 1e-16f);
  float r2 = 1.f / (s2 + 1e-16f), r3 = 1.f / (s3 + 1e-16f);
  if constexpr (DPL == 4) {
    __half2 p[8];
#pragma unroll
    for (int d = 0; d < 4; d++) {
      p[2 * d] = __floats2half2_rn(a[d][0] * r0, a[d][1] * r1);
      p[2 * d + 1] = __floats2half2_rn(a[d][2] * r2, a[d][3] * r3);
    }
    uint4 lo = make_uint4(*(unsigned*)&p[0], *(unsigned*)&p[1], *(unsigned*)&p[2], *(unsigned*)&p[3]);
    uint4 hi = make_uint4(*(unsigned*)&p[4], *(unsigned*)&p[5], *(unsigned*)&p[6], *(unsigned*)&p[7]);
    *(uint4*)(accO + (size_t)n * 256 + q * 16) = lo;
    *(uint4*)(accO + (size_t)n * 256 + q * 16 + 8) = hi;
  } else {
    __half2 p01 = __floats2half2_rn(a[0][0] * r0, a[0][1] * r1);
    __half2 p23 = __floats2half2_rn(a[0][2] * r2, a[0][3] * r3);
    uint2 pk = make_uint2(*(unsigned*)&p01, *(unsigned*)&p23);
    *(uint2*)(accO + (size_t)n * 32 + q * 4) = pk;
  }
}

// ---------------- MFMA projection: tbuf = relu(0.25 * acc @ Bkk + bias) ----------------
template <int DOUT, int NK>
__global__ __launch_bounds__(256) void k_post_mfma(const __half* __restrict__ accA,
                                                   const __half* __restrict__ wfrag,
                                                   const float* __restrict__ bias,
                                                   float* __restrict__ tbuf) {
  constexpr int NCT = DOUT / 16;
  constexpr int AS = NK * 32;
  int l = threadIdx.x & 63;
  int n0 = (blockIdx.x * 4 + (threadIdx.x >> 6)) * 16;
  int m = l & 15, kg = l >> 4;
  f32x4 c[NCT];
#pragma unroll
  for (int ct = 0; ct < NCT; ct++) c[ct] = (f32x4){0.f, 0.f, 0.f, 0.f};
#pragma unroll
  for (int kt = 0; kt < NK; kt++) {
    half8 a = *(const half8*)(accA + (size_t)(n0 + m) * AS + kt * 32 + kg * 8);
#pragma unroll
    for (int ct = 0; ct < NCT; ct++) {
      half8 b = *(const half8*)(wfrag + ((kt * NCT + ct) * 64 + l) * 8);
      c[ct] = __builtin_amdgcn_mfma_f32_16x16x32_f16(a, b, c[ct], 0, 0, 0);
    }
  }
#pragma unroll
  for (int ct = 0; ct < NCT; ct++) {
    float bv = bias[ct * 16 + m];
#pragma unroll
    for (int j = 0; j < 4; j++) {
      int n = n0 + kg * 4 + j;
      if (n < N_NODES) tbuf[(size_t)n * DOUT + ct * 16 + m] = fmaxf(fmaf(c[ct][j], 0.25f, bv), 0.f);
    }
  }
}

// ---------------- batch norm stats ----------------
template <int C>
__global__ __launch_bounds__(256) void k_bnstat(const float* __restrict__ x, float* __restrict__ part) {
  const int RG = 256 / C;
  int col = threadIdx.x & (C - 1);
  int rg = threadIdx.x / C;
  int rows = (N_NODES + gridDim.x - 1) / gridDim.x;
  int r0 = blockIdx.x * rows;
  int r1 = min(N_NODES, r0 + rows);
  float s = 0.f, q = 0.f;
  for (int r = r0 + rg; r < r1; r += RG) {
    float v = x[(size_t)r * C + col];
    s += v;
    q = fmaf(v, v, q);
  }
  __shared__ float sh[512];
  sh[threadIdx.x] = s;
  sh[256 + threadIdx.x] = q;
  __syncthreads();
  for (int step = 128; step >= C; step >>= 1) {
    if (threadIdx.x < step) {
      sh[threadIdx.x] += sh[threadIdx.x + step];
      sh[256 + threadIdx.x] += sh[256 + threadIdx.x + step];
    }
    __syncthreads();
  }
  if (threadIdx.x < C) {
    part[blockIdx.x * 2 * C + threadIdx.x] = sh[threadIdx.x];
    part[blockIdx.x * 2 * C + C + threadIdx.x] = sh[256 + threadIdx.x];
  }
}

template <int C>
__global__ void k_bnfinal(const float* __restrict__ part, const float* __restrict__ g,
                          const float* __restrict__ be, float* __restrict__ scale,
                          float* __restrict__ shift) {
  int c = threadIdx.x;
  if (c >= C) return;
  float s = 0.f, q = 0.f;
  for (int b = 0; b < 256; b++) {
    s += part[b * 2 * C + c];
    q += part[b * 2 * C + C + c];
  }
  float mean = s / (float)N_NODES;
  float var = q / (float)N_NODES - mean * mean;
  float sc = g[c] * rsqrtf(var + 1e-5f);
  scale[c] = sc;
  shift[c] = be[c] - mean * sc;
}

// ---------------- pooling (applies layer-3 BN on load; batch sorted) ----------------
__global__ __launch_bounds__(256) void k_pool(const float* __restrict__ f3,
                                              const int* __restrict__ batch,
                                              const float* __restrict__ scale,
                                              const float* __restrict__ shift,
                                              float* __restrict__ pool,
                                              float* __restrict__ cntg) {
  __shared__ float acc[NG][33];
  int t = threadIdx.x;
  for (int i = t; i < NG * 33; i += 256) ((float*)acc)[i] = 0.f;
  __syncthreads();
  int c = t & 31, rg = t >> 5;
  float sc = scale[c], sh = shift[c];
  int n0 = blockIdx.x * POOL_NPB;
  int n1 = min(N_NODES, n0 + POOL_NPB);
  float r = 0.f, rc = 0.f;
  int gcur = -1;
  for (int n = n0 + rg; n < n1; n += 8) {
    int g = batch[n];
    if (g != gcur) {
      if (gcur >= 0) {
        atomicAdd(&acc[gcur][c], r);
        if (c == 0) atomicAdd(&acc[gcur][32], rc);
      }
      gcur = g;
      r = 0.f;
      rc = 0.f;
    }
    r += fmaf(f3[(size_t)n * 32 + c], sc, sh);
    rc += 1.f;
  }
  if (gcur >= 0) {
    atomicAdd(&acc[gcur][c], r);
    if (c == 0) atomicAdd(&acc[gcur][32], rc);
  }
  __syncthreads();
  for (int i = t; i < NG * 32; i += 256) {
    int g = i >> 5, cc = i & 31;
    float v = acc[g][cc];
    if (v != 0.f) atomicAdd(&pool[i], v);
  }
  for (int g = t; g < NG; g += 256) {
    float v = acc[g][32];
    if (v != 0.f) atomicAdd(&cntg[g], v);
  }
}

__global__ void k_mlp(const float* __restrict__ pool, const float* __restrict__ cntg,
                      const float* __restrict__ Wp1, const float* __restrict__ bp1,
                      const float* __restrict__ Wp2, const float* __restrict__ bp2,
                      float* __restrict__ out) {
  int g = threadIdx.x;
  if (g >= NG) return;
  float inv = 1.f / fmaxf(cntg[g], 1.f);
  float p[32];
#pragma unroll
  for (int c = 0; c < 32; c++) p[c] = pool[g * 32 + c] * inv;
  float o = bp2[0];
  for (int j = 0; j < 16; j++) {
    float hsum = bp1[j];
#pragma unroll
    for (int c = 0; c < 32; c++) hsum = fmaf(p[c], Wp1[c * 16 + j], hsum);
    o = fmaf(fmaxf(hsum, 0.f), Wp2[j], o);
  }
  out[g] = o;
}

extern "C" void kernel_launch(void* const* d_in, const int* in_sizes, int n_in,
                              void* d_out, int out_size, void* d_ws, size_t ws_size,
                              hipStream_t stream) {
  const float* x = (const float*)d_in[0];
  const int* ei = (const int*)d_in[1];
  const int* batch = (const int*)d_in[2];
  const float* W1 = (const float*)d_in[3];
  const float* aS1 = (const float*)d_in[4];
  const float* aD1 = (const float*)d_in[5];
  const float* b1 = (const float*)d_in[6];
  const float* g1 = (const float*)d_in[7];
  const float* be1 = (const float*)d_in[8];
  const float* W2 = (const float*)d_in[9];
  const float* aS2 = (const float*)d_in[10];
  const float* aD2 = (const float*)d_in[11];
  const float* b2 = (const float*)d_in[12];
  const float* g2 = (const float*)d_in[13];
  const float* be2 = (const float*)d_in[14];
  const float* W3 = (const float*)d_in[15];
  const float* aS3 = (const float*)d_in[16];
  const float* aD3 = (const float*)d_in[17];
  const float* b3 = (const float*)d_in[18];
  const float* g3 = (const float*)d_in[19];
  const float* be3 = (const float*)d_in[20];
  const float* Wp1 = (const float*)d_in[21];
  const float* bp1 = (const float*)d_in[22];
  const float* Wp2 = (const float*)d_in[23];
  const float* bp2 = (const float*)d_in[24];
  float* out = (float*)d_out;

  size_t off = 0;
  auto alloc = [&](size_t bytes) -> void* {
    void* p = (char*)d_ws + off;
    off += (bytes + 255) & ~(size_t)255;
    return p;
  };
  // zeroed region (single memset): cnt, epos, pool, cntg
  int* cnt = (int*)alloc((size_t)N_NODES * 4);
  int* epos = (int*)alloc((size_t)N_NODES * 4);
  float* pool = (float*)alloc((size_t)NG * 32 * 4);
  float* cntg = (float*)alloc((size_t)NG * 4);
  size_t zbytes = off;
  int* indptr = (int*)alloc((size_t)(N_NODES + 1) * 4);
  int* esrc = (int*)alloc((size_t)EP * 4);
  int* bsum = (int*)alloc((size_t)256 * 4);
  __half* xhat = (__half*)alloc((size_t)N_NODES * 64 * 2);
  __half* acc16 = (__half*)alloc((size_t)(N_NODES + 16) * 256 * 2);  // interleaved [n][kk]
  float* as_ = (float*)alloc((size_t)N_NODES * 16);
  float* ad_ = (float*)alloc((size_t)N_NODES * 16);
  float* tbuf = (float*)alloc((size_t)N_NODES * 64 * 4);
  float* part = (float*)alloc((size_t)256 * 128 * 4);
  float* scale = (float*)alloc(64 * 4);
  float* shift = (float*)alloc(64 * 4);
  float* wS1 = (float*)alloc(32 * 4);
  float* wD1 = (float*)alloc(32 * 4);
  float* wS2 = (float*)alloc(256 * 4);
  float* wD2 = (float*)alloc(256 * 4);
  float* wS3 = (float*)alloc(256 * 4);
  float* wD3 = (float*)alloc(256 * 4);
  __half* wf1 = (__half*)alloc((size_t)4 * 512 * 2);
  __half* wf2 = (__half*)alloc((size_t)32 * 512 * 2);
  __half* wf3 = (__half*)alloc((size_t)16 * 512 * 2);
  if (off > ws_size) return;

  hipMemsetAsync(cnt, 0, zbytes, stream);

  int nscan = cdiv(N_NODES, SCAN_CHUNK);
  k_count<<<512, 256, 0, stream>>>(ei, cnt);
  k_scan_partial<<<nscan, SCAN_CHUNK, 0, stream>>>(cnt, bsum);
  k_scan_bsum<<<1, 256, 0, stream>>>(bsum, nscan);
  k_scan_final<<<nscan, SCAN_CHUNK, 0, stream>>>(cnt, bsum, indptr);
  k_scatter<<<512, 256, 0, stream>>>(ei, indptr, epos, esrc);

  k_prep<<<16, 256, 0, stream>>>(W1, aS1, aD1, W2, aS2, aD2, W3, aS3, aD3,
                                 wS1, wD1, wS2, wD2, wS3, wD3, wf1, wf2, wf3);

  int npost = cdiv(N_NODES, 64);

  // ---- layer 1: gather raw x (8 fp32, 8-lane groups), MFMA projection (NK=1) ----
  k_attdots1<<<cdiv(N_NODES, 256), 256, 0, stream>>>(x, wS1, wD1, (float4*)as_, (float4*)ad_);
  k_agg<8, float, 3><<<cdiv(N_NODES, 32), 256, 0, stream>>>(indptr, esrc, x, (const float4*)as_,
                                                            (const float4*)ad_, acc16);
  k_post_mfma<64, 1><<<npost, 256, 0, stream>>>(acc16, wf1, b1, tbuf);
  k_bnstat<64><<<256, 256, 0, stream>>>(tbuf, part);
  k_bnfinal<64><<<1, 64, 0, stream>>>(part, g1, be1, scale, shift);

  // ---- layer 2: gather xhat (64 fp16, 16-lane groups), MFMA projection (NK=8) ----
  k_bnx<<<cdiv(N_NODES, 4), 256, 0, stream>>>(tbuf, scale, shift, wS2, wD2, xhat,
                                              (float4*)as_, (float4*)ad_);
  k_agg<64, __half, 4><<<cdiv(N_NODES, 16), 256, 0, stream>>>(indptr, esrc, xhat,
                                                              (const float4*)as_,
                                                              (const float4*)ad_, acc16);
  k_post_mfma<64, 8><<<npost, 256, 0, stream>>>(acc16, wf2, b2, tbuf);
  k_bnstat<64><<<256, 256, 0, stream>>>(tbuf, part);
  k_bnfinal<64><<<1, 64, 0, stream>>>(part, g2, be2, scale, shift);

  // ---- layer 3: gather xhat (64 fp16), MFMA projection (DOUT=32, NK=8) ----
  k_bnx<<<cdiv(N_NODES, 4), 256, 0, stream>>>(tbuf, scale, shift, wS3, wD3, xhat,
                                              (float4*)as_, (float4*)ad_);
  k_agg<64, __half, 4><<<cdiv(N_NODES, 16), 256, 0, stream>>>(indptr, esrc, xhat,
                                                              (const float4*)as_,
                                                              (const float4*)ad_, acc16);
  k_post_mfma<32, 8><<<npost, 256, 0, stream>>>(acc16, wf3, b3, tbuf);
  k_bnstat<32><<<256, 256, 0, stream>>>(tbuf, part);
  k_bnfinal<32><<<1, 32, 0, stream>>>(part, g3, be3, scale, shift);

  // ---- pool (BN3 on load) + MLP ----
  k_pool<<<cdiv(N_NODES, POOL_NPB), 256, 0, stream>>>(tbuf, batch, scale, shift, pool, cntg);
  k_mlp<<<1, 64, 0, stream>>>(pool, cntg, Wp1, bp1, Wp2, bp2, out);
}

// Round 10
// 590.901 us; speedup vs baseline: 3.9374x; 1.1189x over previous
//
#include <hip/hip_runtime.h>
#include <hip/hip_fp16.h>

#define N_NODES 100000
#define N_EDGES 1600000
#define EP (N_EDGES + N_NODES)
#define NG 64
#define NH 4
#define SCAN_CHUNK 512
#define POOL_NPB 256
#define NPART 8
#define PART_SZ 12500  // N_NODES / NPART

static inline int cdiv(int a, int b) { return (a + b - 1) / b; }

typedef _Float16 half8 __attribute__((ext_vector_type(8)));
typedef float f32x4 __attribute__((ext_vector_type(4)));

__device__ __forceinline__ float lrelu(float x) { return x >= 0.f ? x : 0.2f * x; }

// ---------------- CSR build (XCD-partitioned dst ranges + non-temporal edge stream) ----------------
__global__ __launch_bounds__(256) void k_count(const int* __restrict__ ei, int* __restrict__ cnt) {
  int grp = blockIdx.x & (NPART - 1);
  int lo = grp * PART_SZ, hi = lo + PART_SZ;
  int nb = gridDim.x >> 3;
  int bid = blockIdx.x >> 3;
  for (int e = bid * 256 + threadIdx.x; e < EP; e += nb * 256) {
    int d = (e < N_EDGES) ? __builtin_nontemporal_load(&ei[N_EDGES + e]) : (e - N_EDGES);
    if (d >= lo && d < hi) atomicAdd(&cnt[d], 1);
  }
}

__global__ __launch_bounds__(512) void k_scan_partial(const int* __restrict__ cnt,
                                                      int* __restrict__ bsum) {
  __shared__ int sh[SCAN_CHUNK];
  int t = threadIdx.x;
  int idx = blockIdx.x * SCAN_CHUNK + t;
  sh[t] = (idx < N_NODES) ? cnt[idx] : 0;
  __syncthreads();
  for (int s = SCAN_CHUNK / 2; s; s >>= 1) {
    if (t < s) sh[t] += sh[t + s];
    __syncthreads();
  }
  if (t == 0) bsum[blockIdx.x] = sh[0];
}

__global__ void k_scan_bsum(int* __restrict__ bsum, int nb) {
  __shared__ int sh[256];
  int t = threadIdx.x;
  int v = (t < nb) ? bsum[t] : 0;
  sh[t] = v;
  __syncthreads();
  for (int off = 1; off < 256; off <<= 1) {
    int add = (t >= off) ? sh[t - off] : 0;
    __syncthreads();
    sh[t] += add;
    __syncthreads();
  }
  if (t < nb) bsum[t] = sh[t] - v;  // exclusive
}

__global__ __launch_bounds__(512) void k_scan_final(const int* __restrict__ cnt,
                                                    const int* __restrict__ bsum,
                                                    int* __restrict__ indptr) {
  __shared__ int sh[SCAN_CHUNK];
  int t = threadIdx.x;
  int idx = blockIdx.x * SCAN_CHUNK + t;
  sh[t] = (idx < N_NODES) ? cnt[idx] : 0;
  __syncthreads();
  for (int off = 1; off < SCAN_CHUNK; off <<= 1) {
    int add = (t >= off) ? sh[t - off] : 0;
    __syncthreads();
    sh[t] += add;
    __syncthreads();
  }
  if (idx < N_NODES) indptr[idx + 1] = bsum[blockIdx.x] + sh[t];
  if (idx == 0) indptr[0] = 0;
}

__global__ __launch_bounds__(256) void k_scatter(const int* __restrict__ ei,
                                                 const int* __restrict__ indptr,
                                                 int* __restrict__ epos, int* __restrict__ esrc) {
  int grp = blockIdx.x & (NPART - 1);
  int lo = grp * PART_SZ, hi = lo + PART_SZ;
  int nb = gridDim.x >> 3;
  int bid = blockIdx.x >> 3;
  for (int e = bid * 256 + threadIdx.x; e < EP; e += nb * 256) {
    if (e < N_EDGES) {
      int d = __builtin_nontemporal_load(&ei[N_EDGES + e]);
      if (d >= lo && d < hi) {
        int s = __builtin_nontemporal_load(&ei[e]);
        int p = atomicAdd(&epos[d], 1);
        esrc[indptr[d] + p] = s;
      }
    } else {
      int nn = e - N_EDGES;
      if (nn >= lo && nn < hi) {
        int p = atomicAdd(&epos[nn], 1);
        esrc[indptr[nn] + p] = nn;
      }
    }
  }
}

// ---------------- prep: attention-fold vectors + MFMA B-fragment packing ----------------
template <int FIN, int D>
__device__ void wvec_impl(const float* __restrict__ W, const float* __restrict__ aS,
                          const float* __restrict__ aD, float* __restrict__ wS,
                          float* __restrict__ wD, int t) {
  if (t >= 4 * FIN) return;
  int h = t / FIN, k = t % FIN;
  float ss = 0.f, dd = 0.f;
  for (int d = 0; d < D; d++) {
    float w = W[k * (4 * D) + h * D + d];
    ss = fmaf(w, aS[h * D + d], ss);
    dd = fmaf(w, aD[h * D + d], dd);
  }
  wS[h * FIN + k] = ss;
  wD[h * FIN + k] = dd;
}

// B-frag over kk = dim*4 + head contraction: lane l holds B[kk = kt*32+(l>>4)*8+j][col = ct*16+(l&15)]
template <int D>
__device__ void wcvt_frag(const float* __restrict__ W, __half* __restrict__ wf, int frag, int l) {
  constexpr int NCT = D / 16;
  int kt = frag / NCT, ct = frag % NCT;
  half8 v;
#pragma unroll
  for (int j = 0; j < 8; j++) {
    int kk = kt * 32 + (l >> 4) * 8 + j;
    int k = kk >> 2, h = kk & 3;
    v[j] = (_Float16)W[k * (4 * D) + h * D + ct * 16 + (l & 15)];
  }
  *(half8*)(wf + (size_t)frag * 512 + l * 8) = v;
}

__global__ __launch_bounds__(256) void k_prep(const float* W1, const float* aS1, const float* aD1,
                                              const float* W2, const float* aS2, const float* aD2,
                                              const float* W3, const float* aS3, const float* aD3,
                                              float* wS1, float* wD1, float* wS2, float* wD2,
                                              float* wS3, float* wD3,
                                              __half* wf1, __half* wf2, __half* wf3) {
  int b = blockIdx.x, t = threadIdx.x;
  int f = t >> 6, l = t & 63;
  if (b == 0) wvec_impl<8, 64>(W1, aS1, aD1, wS1, wD1, t);
  else if (b == 1) wvec_impl<64, 64>(W2, aS2, aD2, wS2, wD2, t);
  else if (b == 2) wvec_impl<64, 32>(W3, aS3, aD3, wS3, wD3, t);
  else if (b == 3) wcvt_frag<64>(W1, wf1, f, l);                    // FIN=8 -> 4 frags
  else if (b < 12) wcvt_frag<64>(W2, wf2, (b - 4) * 4 + f, l);      // 32 frags
  else wcvt_frag<32>(W3, wf3, (b - 12) * 4 + f, l);                 // 16 frags
}

// ---------------- layer-1 attention dots from raw x (FIN=8) ----------------
__global__ void k_attdots1(const float* __restrict__ x, const float* __restrict__ wS,
                           const float* __restrict__ wD, float4* __restrict__ as4,
                           float4* __restrict__ ad4) {
  int n = blockIdx.x * blockDim.x + threadIdx.x;
  if (n >= N_NODES) return;
  float4 s = {0, 0, 0, 0}, d = {0, 0, 0, 0};
#pragma unroll
  for (int k = 0; k < 8; k++) {
    float xv = x[(size_t)n * 8 + k];
    s.x = fmaf(xv, wS[k], s.x);
    s.y = fmaf(xv, wS[8 + k], s.y);
    s.z = fmaf(xv, wS[16 + k], s.z);
    s.w = fmaf(xv, wS[24 + k], s.w);
    d.x = fmaf(xv, wD[k], d.x);
    d.y = fmaf(xv, wD[8 + k], d.y);
    d.z = fmaf(xv, wD[16 + k], d.z);
    d.w = fmaf(xv, wD[24 + k], d.w);
  }
  as4[n] = s;
  ad4[n] = d;
}

// ---------------- BN-apply + fp16 cast + attention dots (FIN=64) ----------------
__global__ __launch_bounds__(256) void k_bnx(const float* __restrict__ tbuf,
                                             const float* __restrict__ scale,
                                             const float* __restrict__ shift,
                                             const float* __restrict__ wS,
                                             const float* __restrict__ wD,
                                             __half* __restrict__ xhat,
                                             float4* __restrict__ as4, float4* __restrict__ ad4) {
  int lane = threadIdx.x & 63;
  int n = blockIdx.x * 4 + (threadIdx.x >> 6);
  if (n >= N_NODES) return;
  float v = fmaf(tbuf[(size_t)n * 64 + lane], scale[lane], shift[lane]);
  xhat[(size_t)n * 64 + lane] = __float2half(v);
  float p0 = v * wS[lane], p1 = v * wS[64 + lane], p2 = v * wS[128 + lane], p3 = v * wS[192 + lane];
  float q0 = v * wD[lane], q1 = v * wD[64 + lane], q2 = v * wD[128 + lane], q3 = v * wD[192 + lane];
#pragma unroll
  for (int off = 32; off; off >>= 1) {
    p0 += __shfl_xor(p0, off); p1 += __shfl_xor(p1, off);
    p2 += __shfl_xor(p2, off); p3 += __shfl_xor(p3, off);
    q0 += __shfl_xor(q0, off); q1 += __shfl_xor(q1, off);
    q2 += __shfl_xor(q2, off); q3 += __shfl_xor(q3, off);
  }
  if (lane == 0) {
    as4[n] = make_float4(p0, p1, p2, p3);
    ad4[n] = make_float4(q0, q1, q2, q3);
  }
}

// ---------------- fused softmax-weight + gather (GL-lane group per node) ----------------
template <int DIN, typename TX, int GSH>
__global__ __launch_bounds__(256) void k_agg(const int* __restrict__ indptr,
                                             const int* __restrict__ esrc,
                                             const TX* __restrict__ xg,
                                             const float4* __restrict__ as4,
                                             const float4* __restrict__ ad4,
                                             __half* __restrict__ accO) {
  constexpr int GL = 1 << GSH;       // lanes per group
  constexpr int NPW = 64 >> GSH;     // nodes per wave
  constexpr int DPL = DIN / GL;      // dims per lane (4 or 1)
  constexpr int SH = (sizeof(TX) == 2) ? 7 : 5;  // row byte shift (128B or 32B)
  constexpr int WB = NPW * (GL + 1); // per-wave LDS stride (bank spread)
  __shared__ int sOff[4 * WB];
  __shared__ float4 sW[4 * WB];
  int tid = threadIdx.x;
  int lane = tid & 63;
  int wv = tid >> 6;
  int q = lane & (GL - 1);
  int g = lane >> GSH;
  int n = blockIdx.x * (4 * NPW) + wv * NPW + g;
  if (n >= N_NODES) return;
  int e0 = indptr[n], e1 = indptr[n + 1];
  float4 ad = ad4[n];
  int lbase = wv * WB + g * (GL + 1);
  const char* xb = (const char*)xg + q * DPL * (int)sizeof(TX);
  float s0 = 0.f, s1 = 0.f, s2 = 0.f, s3 = 0.f;
  float a[DPL][4];
#pragma unroll
  for (int d = 0; d < DPL; d++)
#pragma unroll
    for (int h = 0; h < 4; h++) a[d][h] = 0.f;

  for (int c = e0; c < e1; c += GL) {
    int nc = min(GL, e1 - c);
    float w0 = 0.f, w1 = 0.f, w2 = 0.f, w3 = 0.f;
    int sB = 0;
    if (q < nc) {
      int sidx = esrc[c + q];
      float4 av = as4[sidx];
      w0 = __expf(lrelu(av.x + ad.x));
      w1 = __expf(lrelu(av.y + ad.y));
      w2 = __expf(lrelu(av.z + ad.z));
      w3 = __expf(lrelu(av.w + ad.w));
      sB = sidx << SH;
    }
    s0 += w0; s1 += w1; s2 += w2; s3 += w3;
    sOff[lbase + q] = sB;
    sW[lbase + q] = make_float4(w0, w1, w2, w3);
    __builtin_amdgcn_wave_barrier();
    for (int i = 0; i < nc; ++i) {
      float4 w = sW[lbase + i];
      int ob = sOff[lbase + i];
      if constexpr (DPL == 4) {
        uint2 px = *(const uint2*)(xb + ob);
        float2 f01 = __half22float2(*(const __half2*)&px.x);
        float2 f23 = __half22float2(*(const __half2*)&px.y);
        a[0][0] = fmaf(w.x, f01.x, a[0][0]); a[0][1] = fmaf(w.y, f01.x, a[0][1]);
        a[0][2] = fmaf(w.z, f01.x, a[0][2]); a[0][3] = fmaf(w.w, f01.x, a[0][3]);
        a[1][0] = fmaf(w.x, f01.y, a[1][0]); a[1][1] = fmaf(w.y, f01.y, a[1][1]);
        a[1][2] = fmaf(w.z, f01.y, a[1][2]); a[1][3] = fmaf(w.w, f01.y, a[1][3]);
        a[2][0] = fmaf(w.x, f23.x, a[2][0]); a[2][1] = fmaf(w.y, f23.x, a[2][1]);
        a[2][2] = fmaf(w.z, f23.x, a[2][2]); a[2][3] = fmaf(w.w, f23.x, a[2][3]);
        a[3][0] = fmaf(w.x, f23.y, a[3][0]); a[3][1] = fmaf(w.y, f23.y, a[3][1]);
        a[3][2] = fmaf(w.z, f23.y, a[3][2]); a[3][3] = fmaf(w.w, f23.y, a[3][3]);
      } else {
        float xv = *(const float*)(xb + ob);
        a[0][0] = fmaf(w.x, xv, a[0][0]);
        a[0][1] = fmaf(w.y, xv, a[0][1]);
        a[0][2] = fmaf(w.z, xv, a[0][2]);
        a[0][3] = fmaf(w.w, xv, a[0][3]);
      }
    }
    __builtin_amdgcn_wave_barrier();
  }
#pragma unroll
  for (int off = 1; off < GL; off <<= 1) {
    s0 += __shfl_xor(s0, off);
    s1 += __shfl_xor(s1, off);
    s2 += __shfl_xor(s2, off);
    s3 += __shfl_xor(s3, off);
  }
  float r0 = 1.f / (s0 + 1e-16f), r1 = 1.f / (s1 + 1e-16f);
  float r2 = 1.f / (s2 + 1e-16f), r3 = 1.f / (s3 + 1e-16f);
  if constexpr (DPL == 4) {
    __half2 p[8];
#pragma unroll
    for (int d = 0; d < 4; d++) {
      p[2 * d] = __floats2half2_rn(a[d][0] * r0, a[d][1] * r1);
      p[2 * d + 1] = __floats2half2_rn(a[d][2] * r2, a[d][3] * r3);
    }
    uint4 lo = make_uint4(*(unsigned*)&p[0], *(unsigned*)&p[1], *(unsigned*)&p[2], *(unsigned*)&p[3]);
    uint4 hi = make_uint4(*(unsigned*)&p[4], *(unsigned*)&p[5], *(unsigned*)&p[6], *(unsigned*)&p[7]);
    *(uint4*)(accO + (size_t)n * 256 + q * 16) = lo;
    *(uint4*)(accO + (size_t)n * 256 + q * 16 + 8) = hi;
  } else {
    __half2 p01 = __floats2half2_rn(a[0][0] * r0, a[0][1] * r1);
    __half2 p23 = __floats2half2_rn(a[0][2] * r2, a[0][3] * r3);
    uint2 pk = make_uint2(*(unsigned*)&p01, *(unsigned*)&p23);
    *(uint2*)(accO + (size_t)n * 32 + q * 4) = pk;
  }
}

// ---------------- MFMA projection: tbuf = relu(0.25 * acc @ Bkk + bias) ----------------
template <int DOUT, int NK>
__global__ __launch_bounds__(256) void k_post_mfma(const __half* __restrict__ accA,
                                                   const __half* __restrict__ wfrag,
                                                   const float* __restrict__ bias,
                                                   float* __restrict__ tbuf) {
  constexpr int NCT = DOUT / 16;
  constexpr int AS = NK * 32;
  int l = threadIdx.x & 63;
  int n0 = (blockIdx.x * 4 + (threadIdx.x >> 6)) * 16;
  int m = l & 15, kg = l >> 4;
  f32x4 c[NCT];
#pragma unroll
  for (int ct = 0; ct < NCT; ct++) c[ct] = (f32x4){0.f, 0.f, 0.f, 0.f};
#pragma unroll
  for (int kt = 0; kt < NK; kt++) {
    half8 a = *(const half8*)(accA + (size_t)(n0 + m) * AS + kt * 32 + kg * 8);
#pragma unroll
    for (int ct = 0; ct < NCT; ct++) {
      half8 b = *(const half8*)(wfrag + ((kt * NCT + ct) * 64 + l) * 8);
      c[ct] = __builtin_amdgcn_mfma_f32_16x16x32_f16(a, b, c[ct], 0, 0, 0);
    }
  }
#pragma unroll
  for (int ct = 0; ct < NCT; ct++) {
    float bv = bias[ct * 16 + m];
#pragma unroll
    for (int j = 0; j < 4; j++) {
      int n = n0 + kg * 4 + j;
      if (n < N_NODES) tbuf[(size_t)n * DOUT + ct * 16 + m] = fmaxf(fmaf(c[ct][j], 0.25f, bv), 0.f);
    }
  }
}

// ---------------- batch norm stats ----------------
template <int C>
__global__ __launch_bounds__(256) void k_bnstat(const float* __restrict__ x, float* __restrict__ part) {
  const int RG = 256 / C;
  int col = threadIdx.x & (C - 1);
  int rg = threadIdx.x / C;
  int rows = (N_NODES + gridDim.x - 1) / gridDim.x;
  int r0 = blockIdx.x * rows;
  int r1 = min(N_NODES, r0 + rows);
  float s = 0.f, q = 0.f;
  for (int r = r0 + rg; r < r1; r += RG) {
    float v = x[(size_t)r * C + col];
    s += v;
    q = fmaf(v, v, q);
  }
  __shared__ float sh[512];
  sh[threadIdx.x] = s;
  sh[256 + threadIdx.x] = q;
  __syncthreads();
  for (int step = 128; step >= C; step >>= 1) {
    if (threadIdx.x < step) {
      sh[threadIdx.x] += sh[threadIdx.x + step];
      sh[256 + threadIdx.x] += sh[256 + threadIdx.x + step];
    }
    __syncthreads();
  }
  if (threadIdx.x < C) {
    part[blockIdx.x * 2 * C + threadIdx.x] = sh[threadIdx.x];
    part[blockIdx.x * 2 * C + C + threadIdx.x] = sh[256 + threadIdx.x];
  }
}

template <int C>
__global__ void k_bnfinal(const float* __restrict__ part, const float* __restrict__ g,
                          const float* __restrict__ be, float* __restrict__ scale,
                          float* __restrict__ shift) {
  int c = threadIdx.x;
  if (c >= C) return;
  float s = 0.f, q = 0.f;
  for (int b = 0; b < 256; b++) {
    s += part[b * 2 * C + c];
    q += part[b * 2 * C + C + c];
  }
  float mean = s / (float)N_NODES;
  float var = q / (float)N_NODES - mean * mean;
  float sc = g[c] * rsqrtf(var + 1e-5f);
  scale[c] = sc;
  shift[c] = be[c] - mean * sc;
}

// ---------------- pooling (applies layer-3 BN on load; batch sorted) ----------------
__global__ __launch_bounds__(256) void k_pool(const float* __restrict__ f3,
                                              const int* __restrict__ batch,
                                              const float* __restrict__ scale,
                                              const float* __restrict__ shift,
                                              float* __restrict__ pool,
                                              float* __restrict__ cntg) {
  __shared__ float acc[NG][33];
  int t = threadIdx.x;
  for (int i = t; i < NG * 33; i += 256) ((float*)acc)[i] = 0.f;
  __syncthreads();
  int c = t & 31, rg = t >> 5;
  float sc = scale[c], sh = shift[c];
  int n0 = blockIdx.x * POOL_NPB;
  int n1 = min(N_NODES, n0 + POOL_NPB);
  float r = 0.f, rc = 0.f;
  int gcur = -1;
  for (int n = n0 + rg; n < n1; n += 8) {
    int g = batch[n];
    if (g != gcur) {
      if (gcur >= 0) {
        atomicAdd(&acc[gcur][c], r);
        if (c == 0) atomicAdd(&acc[gcur][32], rc);
      }
      gcur = g;
      r = 0.f;
      rc = 0.f;
    }
    r += fmaf(f3[(size_t)n * 32 + c], sc, sh);
    rc += 1.f;
  }
  if (gcur >= 0) {
    atomicAdd(&acc[gcur][c], r);
    if (c == 0) atomicAdd(&acc[gcur][32], rc);
  }
  __syncthreads();
  for (int i = t; i < NG * 32; i += 256) {
    int g = i >> 5, cc = i & 31;
    float v = acc[g][cc];
    if (v != 0.f) atomicAdd(&pool[i], v);
  }
  for (int g = t; g < NG; g += 256) {
    float v = acc[g][32];
    if (v != 0.f) atomicAdd(&cntg[g], v);
  }
}

__global__ void k_mlp(const float* __restrict__ pool, const float* __restrict__ cntg,
                      const float* __restrict__ Wp1, const float* __restrict__ bp1,
                      const float* __restrict__ Wp2, const float* __restrict__ bp2,
                      float* __restrict__ out) {
  int g = threadIdx.x;
  if (g >= NG) return;
  float inv = 1.f / fmaxf(cntg[g], 1.f);
  float p[32];
#pragma unroll
  for (int c = 0; c < 32; c++) p[c] = pool[g * 32 + c] * inv;
  float o = bp2[0];
  for (int j = 0; j < 16; j++) {
    float hsum = bp1[j];
#pragma unroll
    for (int c = 0; c < 32; c++) hsum = fmaf(p[c], Wp1[c * 16 + j], hsum);
    o = fmaf(fmaxf(hsum, 0.f), Wp2[j], o);
  }
  out[g] = o;
}

extern "C" void kernel_launch(void* const* d_in, const int* in_sizes, int n_in,
                              void* d_out, int out_size, void* d_ws, size_t ws_size,
                              hipStream_t stream) {
  const float* x = (const float*)d_in[0];
  const int* ei = (const int*)d_in[1];
  const int* batch = (const int*)d_in[2];
  const float* W1 = (const float*)d_in[3];
  const float* aS1 = (const float*)d_in[4];
  const float* aD1 = (const float*)d_in[5];
  const float* b1 = (const float*)d_in[6];
  const float* g1 = (const float*)d_in[7];
  const float* be1 = (const float*)d_in[8];
  const float* W2 = (const float*)d_in[9];
  const float* aS2 = (const float*)d_in[10];
  const float* aD2 = (const float*)d_in[11];
  const float* b2 = (const float*)d_in[12];
  const float* g2 = (const float*)d_in[13];
  const float* be2 = (const float*)d_in[14];
  const float* W3 = (const float*)d_in[15];
  const float* aS3 = (const float*)d_in[16];
  const float* aD3 = (const float*)d_in[17];
  const float* b3 = (const float*)d_in[18];
  const float* g3 = (const float*)d_in[19];
  const float* be3 = (const float*)d_in[20];
  const float* Wp1 = (const float*)d_in[21];
  const float* bp1 = (const float*)d_in[22];
  const float* Wp2 = (const float*)d_in[23];
  const float* bp2 = (const float*)d_in[24];
  float* out = (float*)d_out;

  size_t off = 0;
  auto alloc = [&](size_t bytes) -> void* {
    void* p = (char*)d_ws + off;
    off += (bytes + 255) & ~(size_t)255;
    return p;
  };
  // zeroed region (single memset): cnt, epos, pool, cntg
  int* cnt = (int*)alloc((size_t)N_NODES * 4);
  int* epos = (int*)alloc((size_t)N_NODES * 4);
  float* pool = (float*)alloc((size_t)NG * 32 * 4);
  float* cntg = (float*)alloc((size_t)NG * 4);
  size_t zbytes = off;
  int* indptr = (int*)alloc((size_t)(N_NODES + 1) * 4);
  int* esrc = (int*)alloc((size_t)EP * 4);
  int* bsum = (int*)alloc((size_t)256 * 4);
  __half* xhat = (__half*)alloc((size_t)N_NODES * 64 * 2);
  __half* acc16 = (__half*)alloc((size_t)(N_NODES + 16) * 256 * 2);  // interleaved [n][kk]
  float* as_ = (float*)alloc((size_t)N_NODES * 16);
  float* ad_ = (float*)alloc((size_t)N_NODES * 16);
  float* tbuf = (float*)alloc((size_t)N_NODES * 64 * 4);
  float* part = (float*)alloc((size_t)256 * 128 * 4);
  float* scale = (float*)alloc(64 * 4);
  float* shift = (float*)alloc(64 * 4);
  float* wS1 = (float*)alloc(32 * 4);
  float* wD1 = (float*)alloc(32 * 4);
  float* wS2 = (float*)alloc(256 * 4);
  float* wD2 = (float*)alloc(256 * 4);
  float* wS3 = (float*)alloc(256 * 4);
  float* wD3 = (float*)alloc(256 * 4);
  __half* wf1 = (__half*)alloc((size_t)4 * 512 * 2);
  __half* wf2 = (__half*)alloc((size_t)32 * 512 * 2);
  __half* wf3 = (__half*)alloc((size_t)16 * 512 * 2);
  if (off > ws_size) return;

  hipMemsetAsync(cnt, 0, zbytes, stream);

  int nscan = cdiv(N_NODES, SCAN_CHUNK);
  k_count<<<1024, 256, 0, stream>>>(ei, cnt);
  k_scan_partial<<<nscan, SCAN_CHUNK, 0, stream>>>(cnt, bsum);
  k_scan_bsum<<<1, 256, 0, stream>>>(bsum, nscan);
  k_scan_final<<<nscan, SCAN_CHUNK, 0, stream>>>(cnt, bsum, indptr);
  k_scatter<<<1024, 256, 0, stream>>>(ei, indptr, epos, esrc);

  k_prep<<<16, 256, 0, stream>>>(W1, aS1, aD1, W2, aS2, aD2, W3, aS3, aD3,
                                 wS1, wD1, wS2, wD2, wS3, wD3, wf1, wf2, wf3);

  int npost = cdiv(N_NODES, 64);

  // ---- layer 1: gather raw x (8 fp32, 8-lane groups), MFMA projection (NK=1) ----
  k_attdots1<<<cdiv(N_NODES, 256), 256, 0, stream>>>(x, wS1, wD1, (float4*)as_, (float4*)ad_);
  k_agg<8, float, 3><<<cdiv(N_NODES, 32), 256, 0, stream>>>(indptr, esrc, x, (const float4*)as_,
                                                            (const float4*)ad_, acc16);
  k_post_mfma<64, 1><<<npost, 256, 0, stream>>>(acc16, wf1, b1, tbuf);
  k_bnstat<64><<<256, 256, 0, stream>>>(tbuf, part);
  k_bnfinal<64><<<1, 64, 0, stream>>>(part, g1, be1, scale, shift);

  // ---- layer 2: gather xhat (64 fp16, 16-lane groups), MFMA projection (NK=8) ----
  k_bnx<<<cdiv(N_NODES, 4), 256, 0, stream>>>(tbuf, scale, shift, wS2, wD2, xhat,
                                              (float4*)as_, (float4*)ad_);
  k_agg<64, __half, 4><<<cdiv(N_NODES, 16), 256, 0, stream>>>(indptr, esrc, xhat,
                                                              (const float4*)as_,
                                                              (const float4*)ad_, acc16);
  k_post_mfma<64, 8><<<npost, 256, 0, stream>>>(acc16, wf2, b2, tbuf);
  k_bnstat<64><<<256, 256, 0, stream>>>(tbuf, part);
  k_bnfinal<64><<<1, 64, 0, stream>>>(part, g2, be2, scale, shift);

  // ---- layer 3: gather xhat (64 fp16), MFMA projection (DOUT=32, NK=8) ----
  k_bnx<<<cdiv(N_NODES, 4), 256, 0, stream>>>(tbuf, scale, shift, wS3, wD3, xhat,
                                              (float4*)as_, (float4*)ad_);
  k_agg<64, __half, 4><<<cdiv(N_NODES, 16), 256, 0, stream>>>(indptr, esrc, xhat,
                                                              (const float4*)as_,
                                                              (const float4*)ad_, acc16);
  k_post_mfma<32, 8><<<npost, 256, 0, stream>>>(acc16, wf3, b3, tbuf);
  k_bnstat<32><<<256, 256, 0, stream>>>(tbuf, part);
  k_bnfinal<32><<<1, 32, 0, stream>>>(part, g3, be3, scale, shift);

  // ---- pool (BN3 on load) + MLP ----
  k_pool<<<cdiv(N_NODES, POOL_NPB), 256, 0, stream>>>(tbuf, batch, scale, shift, pool, cntg);
  k_mlp<<<1, 64, 0, stream>>>(pool, cntg, Wp1, bp1, Wp2, bp2, out);
}

// Round 11
// 454.650 us; speedup vs baseline: 5.1174x; 1.2997x over previous
//
#include <hip/hip_runtime.h>
#include <hip/hip_fp16.h>

#define N_NODES 100000
#define N_EDGES 1600000
#define EP (N_EDGES + N_NODES)
#define NG 64
#define NH 4
#define POOL_NPB 256
#define BSHIFT 7
#define BNODES 128
#define NBUCK 782   // cdiv(N_NODES, 128)
#define BCAP 3072   // per-bucket capacity (mean 2176, overflow ~20 sigma away)
#define BCHUNK 4096 // edges per k_bucket block (16 per thread)

static inline int cdiv(int a, int b) { return (a + b - 1) / b; }

typedef _Float16 half8 __attribute__((ext_vector_type(8)));
typedef float f32x4 __attribute__((ext_vector_type(4)));

__device__ __forceinline__ float lrelu(float x) { return x >= 0.f ? x : 0.2f * x; }

// ---------------- CSR build: bucket sort (coalesced writes, randomness in LDS) ----------------
// pass 1: bin edges into padded 128-node buckets as packed u32 (src<<7 | dst&127)
__global__ __launch_bounds__(256) void k_bucket(const int* __restrict__ ei,
                                                int* __restrict__ gCursor,
                                                unsigned int* __restrict__ pairs) {
  __shared__ int cnt[NBUCK];
  __shared__ int base[NBUCK];
  int tid = threadIdx.x;
  for (int b = tid; b < NBUCK; b += 256) cnt[b] = 0;
  __syncthreads();
  int e0 = blockIdx.x * BCHUNK;
  unsigned int stV[16];
  int stB[16];
#pragma unroll
  for (int i = 0; i < 16; i++) {
    int e = e0 + i * 256 + tid;
    stB[i] = -1;
    if (e < EP) {
      int d, s;
      if (e < N_EDGES) {
        d = __builtin_nontemporal_load(&ei[N_EDGES + e]);
        s = __builtin_nontemporal_load(&ei[e]);
      } else {
        d = s = e - N_EDGES;
      }
      int b = d >> BSHIFT;
      stV[i] = ((unsigned int)s << BSHIFT) | (unsigned int)(d & (BNODES - 1));
      stB[i] = b;
      atomicAdd(&cnt[b], 1);
    }
  }
  __syncthreads();
  for (int b = tid; b < NBUCK; b += 256) {
    base[b] = atomicAdd(&gCursor[b], cnt[b]);
    cnt[b] = 0;  // reuse as cursor
  }
  __syncthreads();
#pragma unroll
  for (int i = 0; i < 16; i++) {
    if (stB[i] >= 0) {
      int r = atomicAdd(&cnt[stB[i]], 1);
      pairs[base[stB[i]] + r] = stV[i];
    }
  }
}

// pass 2: exclusive scan of bucket counts -> bstart[NBUCK+1]
__global__ __launch_bounds__(1024) void k_bscan(const int* __restrict__ gCursor,
                                                int* __restrict__ bstart) {
  __shared__ int sh[1024];
  int t = threadIdx.x;
  int v = (t < NBUCK) ? (gCursor[t] - t * BCAP) : 0;
  sh[t] = v;
  __syncthreads();
  for (int off = 1; off < 1024; off <<= 1) {
    int add = (t >= off) ? sh[t - off] : 0;
    __syncthreads();
    sh[t] += add;
    __syncthreads();
  }
  if (t < NBUCK) {
    bstart[t] = sh[t] - v;
    if (t == NBUCK - 1) bstart[NBUCK] = sh[t];
  }
}

// pass 3: per-bucket counting sort in LDS; coalesced indptr + esrc writes
__global__ __launch_bounds__(256) void k_build(const unsigned int* __restrict__ pairs,
                                               const int* __restrict__ bstart,
                                               int* __restrict__ indptr, int* __restrict__ esrc) {
  __shared__ int cnt[BNODES];
  __shared__ int exc[BNODES];
  __shared__ int ptr[BNODES];
  __shared__ int eLds[BCAP];
  int b = blockIdx.x;
  int tid = threadIdx.x;
  int obase = bstart[b];
  int nE = bstart[b + 1] - obase;
  int pbase = b * BCAP;
  if (tid < BNODES) cnt[tid] = 0;
  __syncthreads();
  unsigned int stV[12];
#pragma unroll
  for (int i = 0; i < 12; i++) {
    int idx = i * 256 + tid;
    stV[i] = 0xFFFFFFFFu;
    if (idx < nE) {
      unsigned int v = pairs[pbase + idx];
      stV[i] = v;
      atomicAdd(&cnt[v & (BNODES - 1)], 1);
    }
  }
  __syncthreads();
  if (tid < BNODES) ptr[tid] = cnt[tid];
  __syncthreads();
  for (int off = 1; off < BNODES; off <<= 1) {
    int add = (tid < BNODES && tid >= off) ? ptr[tid - off] : 0;
    __syncthreads();
    if (tid < BNODES) ptr[tid] += add;
    __syncthreads();
  }
  if (tid < BNODES) {
    exc[tid] = ptr[tid] - cnt[tid];
    int n = (b << BSHIFT) + tid;
    if (n < N_NODES) indptr[n] = obase + exc[tid];
    cnt[tid] = 0;  // reuse as cursor
  }
  if (b == NBUCK - 1 && tid == 0) indptr[N_NODES] = bstart[NBUCK];
  __syncthreads();
#pragma unroll
  for (int i = 0; i < 12; i++) {
    if (stV[i] != 0xFFFFFFFFu) {
      int ln = stV[i] & (BNODES - 1);
      int r = atomicAdd(&cnt[ln], 1);
      eLds[exc[ln] + r] = (int)(stV[i] >> BSHIFT);
    }
  }
  __syncthreads();
  for (int idx = tid; idx < nE; idx += 256) esrc[obase + idx] = eLds[idx];
}

// ---------------- prep: attention-fold vectors + MFMA B-fragment packing + cursor init ----------------
template <int FIN, int D>
__device__ void wvec_impl(const float* __restrict__ W, const float* __restrict__ aS,
                          const float* __restrict__ aD, float* __restrict__ wS,
                          float* __restrict__ wD, int t) {
  if (t >= 4 * FIN) return;
  int h = t / FIN, k = t % FIN;
  float ss = 0.f, dd = 0.f;
  for (int d = 0; d < D; d++) {
    float w = W[k * (4 * D) + h * D + d];
    ss = fmaf(w, aS[h * D + d], ss);
    dd = fmaf(w, aD[h * D + d], dd);
  }
  wS[h * FIN + k] = ss;
  wD[h * FIN + k] = dd;
}

// B-frag over kk = dim*4 + head contraction: lane l holds B[kk = kt*32+(l>>4)*8+j][col = ct*16+(l&15)]
template <int D>
__device__ void wcvt_frag(const float* __restrict__ W, __half* __restrict__ wf, int frag, int l) {
  constexpr int NCT = D / 16;
  int kt = frag / NCT, ct = frag % NCT;
  half8 v;
#pragma unroll
  for (int j = 0; j < 8; j++) {
    int kk = kt * 32 + (l >> 4) * 8 + j;
    int k = kk >> 2, h = kk & 3;
    v[j] = (_Float16)W[k * (4 * D) + h * D + ct * 16 + (l & 15)];
  }
  *(half8*)(wf + (size_t)frag * 512 + l * 8) = v;
}

__global__ __launch_bounds__(256) void k_prep(const float* W1, const float* aS1, const float* aD1,
                                              const float* W2, const float* aS2, const float* aD2,
                                              const float* W3, const float* aS3, const float* aD3,
                                              float* wS1, float* wD1, float* wS2, float* wD2,
                                              float* wS3, float* wD3,
                                              __half* wf1, __half* wf2, __half* wf3,
                                              int* gCursor) {
  int b = blockIdx.x, t = threadIdx.x;
  int f = t >> 6, l = t & 63;
  if (b == 0) wvec_impl<8, 64>(W1, aS1, aD1, wS1, wD1, t);
  else if (b == 1) wvec_impl<64, 64>(W2, aS2, aD2, wS2, wD2, t);
  else if (b == 2) wvec_impl<64, 32>(W3, aS3, aD3, wS3, wD3, t);
  else if (b == 3) wcvt_frag<64>(W1, wf1, f, l);                    // FIN=8 -> 4 frags
  else if (b < 12) wcvt_frag<64>(W2, wf2, (b - 4) * 4 + f, l);      // 32 frags
  else if (b < 16) wcvt_frag<32>(W3, wf3, (b - 12) * 4 + f, l);     // 16 frags
  else {
    int idx = (b - 16) * 256 + t;
    if (idx < NBUCK) gCursor[idx] = idx * BCAP;
  }
}

// ---------------- layer-1 attention dots from raw x (FIN=8) ----------------
__global__ void k_attdots1(const float* __restrict__ x, const float* __restrict__ wS,
                           const float* __restrict__ wD, float4* __restrict__ as4,
                           float4* __restrict__ ad4) {
  int n = blockIdx.x * blockDim.x + threadIdx.x;
  if (n >= N_NODES) return;
  float4 s = {0, 0, 0, 0}, d = {0, 0, 0, 0};
#pragma unroll
  for (int k = 0; k < 8; k++) {
    float xv = x[(size_t)n * 8 + k];
    s.x = fmaf(xv, wS[k], s.x);
    s.y = fmaf(xv, wS[8 + k], s.y);
    s.z = fmaf(xv, wS[16 + k], s.z);
    s.w = fmaf(xv, wS[24 + k], s.w);
    d.x = fmaf(xv, wD[k], d.x);
    d.y = fmaf(xv, wD[8 + k], d.y);
    d.z = fmaf(xv, wD[16 + k], d.z);
    d.w = fmaf(xv, wD[24 + k], d.w);
  }
  as4[n] = s;
  ad4[n] = d;
}

// ---------------- BN-apply + fp16 cast + attention dots (FIN=64) ----------------
__global__ __launch_bounds__(256) void k_bnx(const float* __restrict__ tbuf,
                                             const float* __restrict__ scale,
                                             const float* __restrict__ shift,
                                             const float* __restrict__ wS,
                                             const float* __restrict__ wD,
                                             __half* __restrict__ xhat,
                                             float4* __restrict__ as4, float4* __restrict__ ad4) {
  int lane = threadIdx.x & 63;
  int n = blockIdx.x * 4 + (threadIdx.x >> 6);
  if (n >= N_NODES) return;
  float v = fmaf(tbuf[(size_t)n * 64 + lane], scale[lane], shift[lane]);
  xhat[(size_t)n * 64 + lane] = __float2half(v);
  float p0 = v * wS[lane], p1 = v * wS[64 + lane], p2 = v * wS[128 + lane], p3 = v * wS[192 + lane];
  float q0 = v * wD[lane], q1 = v * wD[64 + lane], q2 = v * wD[128 + lane], q3 = v * wD[192 + lane];
#pragma unroll
  for (int off = 32; off; off >>= 1) {
    p0 += __shfl_xor(p0, off); p1 += __shfl_xor(p1, off);
    p2 += __shfl_xor(p2, off); p3 += __shfl_xor(p3, off);
    q0 += __shfl_xor(q0, off); q1 += __shfl_xor(q1, off);
    q2 += __shfl_xor(q2, off); q3 += __shfl_xor(q3, off);
  }
  if (lane == 0) {
    as4[n] = make_float4(p0, p1, p2, p3);
    ad4[n] = make_float4(q0, q1, q2, q3);
  }
}

// ---------------- fused softmax-weight + gather (GL-lane group per node) ----------------
template <int DIN, typename TX, int GSH>
__global__ __launch_bounds__(256) void k_agg(const int* __restrict__ indptr,
                                             const int* __restrict__ esrc,
                                             const TX* __restrict__ xg,
                                             const float4* __restrict__ as4,
                                             const float4* __restrict__ ad4,
                                             __half* __restrict__ accO) {
  constexpr int GL = 1 << GSH;       // lanes per group
  constexpr int NPW = 64 >> GSH;     // nodes per wave
  constexpr int DPL = DIN / GL;      // dims per lane (4 or 1)
  constexpr int SH = (sizeof(TX) == 2) ? 7 : 5;  // row byte shift (128B or 32B)
  constexpr int WB = NPW * (GL + 1); // per-wave LDS stride (bank spread)
  __shared__ int sOff[4 * WB];
  __shared__ float4 sW[4 * WB];
  int tid = threadIdx.x;
  int lane = tid & 63;
  int wv = tid >> 6;
  int q = lane & (GL - 1);
  int g = lane >> GSH;
  int n = blockIdx.x * (4 * NPW) + wv * NPW + g;
  if (n >= N_NODES) return;
  int e0 = indptr[n], e1 = indptr[n + 1];
  float4 ad = ad4[n];
  int lbase = wv * WB + g * (GL + 1);
  const char* xb = (const char*)xg + q * DPL * (int)sizeof(TX);
  float s0 = 0.f, s1 = 0.f, s2 = 0.f, s3 = 0.f;
  float a[DPL][4];
#pragma unroll
  for (int d = 0; d < DPL; d++)
#pragma unroll
    for (int h = 0; h < 4; h++) a[d][h] = 0.f;

  for (int c = e0; c < e1; c += GL) {
    int nc = min(GL, e1 - c);
    float w0 = 0.f, w1 = 0.f, w2 = 0.f, w3 = 0.f;
    int sB = 0;
    if (q < nc) {
      int sidx = esrc[c + q];
      float4 av = as4[sidx];
      w0 = __expf(lrelu(av.x + ad.x));
      w1 = __expf(lrelu(av.y + ad.y));
      w2 = __expf(lrelu(av.z + ad.z));
      w3 = __expf(lrelu(av.w + ad.w));
      sB = sidx << SH;
    }
    s0 += w0; s1 += w1; s2 += w2; s3 += w3;
    sOff[lbase + q] = sB;
    sW[lbase + q] = make_float4(w0, w1, w2, w3);
    __builtin_amdgcn_wave_barrier();
    for (int i = 0; i < nc; ++i) {
      float4 w = sW[lbase + i];
      int ob = sOff[lbase + i];
      if constexpr (DPL == 4) {
        uint2 px = *(const uint2*)(xb + ob);
        float2 f01 = __half22float2(*(const __half2*)&px.x);
        float2 f23 = __half22float2(*(const __half2*)&px.y);
        a[0][0] = fmaf(w.x, f01.x, a[0][0]); a[0][1] = fmaf(w.y, f01.x, a[0][1]);
        a[0][2] = fmaf(w.z, f01.x, a[0][2]); a[0][3] = fmaf(w.w, f01.x, a[0][3]);
        a[1][0] = fmaf(w.x, f01.y, a[1][0]); a[1][1] = fmaf(w.y, f01.y, a[1][1]);
        a[1][2] = fmaf(w.z, f01.y, a[1][2]); a[1][3] = fmaf(w.w, f01.y, a[1][3]);
        a[2][0] = fmaf(w.x, f23.x, a[2][0]); a[2][1] = fmaf(w.y, f23.x, a[2][1]);
        a[2][2] = fmaf(w.z, f23.x, a[2][2]); a[2][3] = fmaf(w.w, f23.x, a[2][3]);
        a[3][0] = fmaf(w.x, f23.y, a[3][0]); a[3][1] = fmaf(w.y, f23.y, a[3][1]);
        a[3][2] = fmaf(w.z, f23.y, a[3][2]); a[3][3] = fmaf(w.w, f23.y, a[3][3]);
      } else {
        float xv = *(const float*)(xb + ob);
        a[0][0] = fmaf(w.x, xv, a[0][0]);
        a[0][1] = fmaf(w.y, xv, a[0][1]);
        a[0][2] = fmaf(w.z, xv, a[0][2]);
        a[0][3] = fmaf(w.w, xv, a[0][3]);
      }
    }
    __builtin_amdgcn_wave_barrier();
  }
#pragma unroll
  for (int off = 1; off < GL; off <<= 1) {
    s0 += __shfl_xor(s0, off);
    s1 += __shfl_xor(s1, off);
    s2 += __shfl_xor(s2, off);
    s3 += __shfl_xor(s3, off);
  }
  float r0 = 1.f / (s0 + 1e-16f), r1 = 1.f / (s1 + 1e-16f);
  float r2 = 1.f / (s2 + 1e-16f), r3 = 1.f / (s3 + 1e-16f);
  if constexpr (DPL == 4) {
    __half2 p[8];
#pragma unroll
    for (int d = 0; d < 4; d++) {
      p[2 * d] = __floats2half2_rn(a[d][0] * r0, a[d][1] * r1);
      p[2 * d + 1] = __floats2half2_rn(a[d][2] * r2, a[d][3] * r3);
    }
    uint4 lo = make_uint4(*(unsigned*)&p[0], *(unsigned*)&p[1], *(unsigned*)&p[2], *(unsigned*)&p[3]);
    uint4 hi = make_uint4(*(unsigned*)&p[4], *(unsigned*)&p[5], *(unsigned*)&p[6], *(unsigned*)&p[7]);
    *(uint4*)(accO + (size_t)n * 256 + q * 16) = lo;
    *(uint4*)(accO + (size_t)n * 256 + q * 16 + 8) = hi;
  } else {
    __half2 p01 = __floats2half2_rn(a[0][0] * r0, a[0][1] * r1);
    __half2 p23 = __floats2half2_rn(a[0][2] * r2, a[0][3] * r3);
    uint2 pk = make_uint2(*(unsigned*)&p01, *(unsigned*)&p23);
    *(uint2*)(accO + (size_t)n * 32 + q * 4) = pk;
  }
}

// ---------------- MFMA projection: tbuf = relu(0.25 * acc @ Bkk + bias) ----------------
template <int DOUT, int NK>
__global__ __launch_bounds__(256) void k_post_mfma(const __half* __restrict__ accA,
                                                   const __half* __restrict__ wfrag,
                                                   const float* __restrict__ bias,
                                                   float* __restrict__ tbuf) {
  constexpr int NCT = DOUT / 16;
  constexpr int AS = NK * 32;
  int l = threadIdx.x & 63;
  int n0 = (blockIdx.x * 4 + (threadIdx.x >> 6)) * 16;
  int m = l & 15, kg = l >> 4;
  f32x4 c[NCT];
#pragma unroll
  for (int ct = 0; ct < NCT; ct++) c[ct] = (f32x4){0.f, 0.f, 0.f, 0.f};
#pragma unroll
  for (int kt = 0; kt < NK; kt++) {
    half8 a = *(const half8*)(accA + (size_t)(n0 + m) * AS + kt * 32 + kg * 8);
#pragma unroll
    for (int ct = 0; ct < NCT; ct++) {
      half8 b = *(const half8*)(wfrag + ((kt * NCT + ct) * 64 + l) * 8);
      c[ct] = __builtin_amdgcn_mfma_f32_16x16x32_f16(a, b, c[ct], 0, 0, 0);
    }
  }
#pragma unroll
  for (int ct = 0; ct < NCT; ct++) {
    float bv = bias[ct * 16 + m];
#pragma unroll
    for (int j = 0; j < 4; j++) {
      int n = n0 + kg * 4 + j;
      if (n < N_NODES) tbuf[(size_t)n * DOUT + ct * 16 + m] = fmaxf(fmaf(c[ct][j], 0.25f, bv), 0.f);
    }
  }
}

// ---------------- batch norm stats ----------------
template <int C>
__global__ __launch_bounds__(256) void k_bnstat(const float* __restrict__ x, float* __restrict__ part) {
  const int RG = 256 / C;
  int col = threadIdx.x & (C - 1);
  int rg = threadIdx.x / C;
  int rows = (N_NODES + gridDim.x - 1) / gridDim.x;
  int r0 = blockIdx.x * rows;
  int r1 = min(N_NODES, r0 + rows);
  float s = 0.f, q = 0.f;
  for (int r = r0 + rg; r < r1; r += RG) {
    float v = x[(size_t)r * C + col];
    s += v;
    q = fmaf(v, v, q);
  }
  __shared__ float sh[512];
  sh[threadIdx.x] = s;
  sh[256 + threadIdx.x] = q;
  __syncthreads();
  for (int step = 128; step >= C; step >>= 1) {
    if (threadIdx.x < step) {
      sh[threadIdx.x] += sh[threadIdx.x + step];
      sh[256 + threadIdx.x] += sh[256 + threadIdx.x + step];
    }
    __syncthreads();
  }
  if (threadIdx.x < C) {
    part[blockIdx.x * 2 * C + threadIdx.x] = sh[threadIdx.x];
    part[blockIdx.x * 2 * C + C + threadIdx.x] = sh[256 + threadIdx.x];
  }
}

template <int C>
__global__ void k_bnfinal(const float* __restrict__ part, const float* __restrict__ g,
                          const float* __restrict__ be, float* __restrict__ scale,
                          float* __restrict__ shift) {
  int c = threadIdx.x;
  if (c >= C) return;
  float s = 0.f, q = 0.f;
  for (int b = 0; b < 256; b++) {
    s += part[b * 2 * C + c];
    q += part[b * 2 * C + C + c];
  }
  float mean = s / (float)N_NODES;
  float var = q / (float)N_NODES - mean * mean;
  float sc = g[c] * rsqrtf(var + 1e-5f);
  scale[c] = sc;
  shift[c] = be[c] - mean * sc;
}

// ---------------- pooling (applies layer-3 BN on load; batch sorted) ----------------
__global__ __launch_bounds__(256) void k_pool(const float* __restrict__ f3,
                                              const int* __restrict__ batch,
                                              const float* __restrict__ scale,
                                              const float* __restrict__ shift,
                                              float* __restrict__ pool,
                                              float* __restrict__ cntg) {
  __shared__ float acc[NG][33];
  int t = threadIdx.x;
  for (int i = t; i < NG * 33; i += 256) ((float*)acc)[i] = 0.f;
  __syncthreads();
  int c = t & 31, rg = t >> 5;
  float sc = scale[c], sh = shift[c];
  int n0 = blockIdx.x * POOL_NPB;
  int n1 = min(N_NODES, n0 + POOL_NPB);
  float r = 0.f, rc = 0.f;
  int gcur = -1;
  for (int n = n0 + rg; n < n1; n += 8) {
    int g = batch[n];
    if (g != gcur) {
      if (gcur >= 0) {
        atomicAdd(&acc[gcur][c], r);
        if (c == 0) atomicAdd(&acc[gcur][32], rc);
      }
      gcur = g;
      r = 0.f;
      rc = 0.f;
    }
    r += fmaf(f3[(size_t)n * 32 + c], sc, sh);
    rc += 1.f;
  }
  if (gcur >= 0) {
    atomicAdd(&acc[gcur][c], r);
    if (c == 0) atomicAdd(&acc[gcur][32], rc);
  }
  __syncthreads();
  for (int i = t; i < NG * 32; i += 256) {
    int g = i >> 5, cc = i & 31;
    float v = acc[g][cc];
    if (v != 0.f) atomicAdd(&pool[i], v);
  }
  for (int g = t; g < NG; g += 256) {
    float v = acc[g][32];
    if (v != 0.f) atomicAdd(&cntg[g], v);
  }
}

__global__ void k_mlp(const float* __restrict__ pool, const float* __restrict__ cntg,
                      const float* __restrict__ Wp1, const float* __restrict__ bp1,
                      const float* __restrict__ Wp2, const float* __restrict__ bp2,
                      float* __restrict__ out) {
  int g = threadIdx.x;
  if (g >= NG) return;
  float inv = 1.f / fmaxf(cntg[g], 1.f);
  float p[32];
#pragma unroll
  for (int c = 0; c < 32; c++) p[c] = pool[g * 32 + c] * inv;
  float o = bp2[0];
  for (int j = 0; j < 16; j++) {
    float hsum = bp1[j];
#pragma unroll
    for (int c = 0; c < 32; c++) hsum = fmaf(p[c], Wp1[c * 16 + j], hsum);
    o = fmaf(fmaxf(hsum, 0.f), Wp2[j], o);
  }
  out[g] = o;
}

extern "C" void kernel_launch(void* const* d_in, const int* in_sizes, int n_in,
                              void* d_out, int out_size, void* d_ws, size_t ws_size,
                              hipStream_t stream) {
  const float* x = (const float*)d_in[0];
  const int* ei = (const int*)d_in[1];
  const int* batch = (const int*)d_in[2];
  const float* W1 = (const float*)d_in[3];
  const float* aS1 = (const float*)d_in[4];
  const float* aD1 = (const float*)d_in[5];
  const float* b1 = (const float*)d_in[6];
  const float* g1 = (const float*)d_in[7];
  const float* be1 = (const float*)d_in[8];
  const float* W2 = (const float*)d_in[9];
  const float* aS2 = (const float*)d_in[10];
  const float* aD2 = (const float*)d_in[11];
  const float* b2 = (const float*)d_in[12];
  const float* g2 = (const float*)d_in[13];
  const float* be2 = (const float*)d_in[14];
  const float* W3 = (const float*)d_in[15];
  const float* aS3 = (const float*)d_in[16];
  const float* aD3 = (const float*)d_in[17];
  const float* b3 = (const float*)d_in[18];
  const float* g3 = (const float*)d_in[19];
  const float* be3 = (const float*)d_in[20];
  const float* Wp1 = (const float*)d_in[21];
  const float* bp1 = (const float*)d_in[22];
  const float* Wp2 = (const float*)d_in[23];
  const float* bp2 = (const float*)d_in[24];
  float* out = (float*)d_out;

  size_t off = 0;
  auto alloc = [&](size_t bytes) -> void* {
    void* p = (char*)d_ws + off;
    off += (bytes + 255) & ~(size_t)255;
    return p;
  };
  // zeroed region (single memset): pool, cntg
  float* pool = (float*)alloc((size_t)NG * 32 * 4);
  float* cntg = (float*)alloc((size_t)NG * 4);
  size_t zbytes = off;
  int* gCursor = (int*)alloc((size_t)NBUCK * 4);
  int* bstart = (int*)alloc((size_t)(NBUCK + 1) * 4);
  unsigned int* pairs = (unsigned int*)alloc((size_t)NBUCK * BCAP * 4);
  int* indptr = (int*)alloc((size_t)(N_NODES + 1) * 4);
  int* esrc = (int*)alloc((size_t)EP * 4);
  __half* xhat = (__half*)alloc((size_t)N_NODES * 64 * 2);
  __half* acc16 = (__half*)alloc((size_t)(N_NODES + 16) * 256 * 2);  // interleaved [n][kk]
  float* as_ = (float*)alloc((size_t)N_NODES * 16);
  float* ad_ = (float*)alloc((size_t)N_NODES * 16);
  float* tbuf = (float*)alloc((size_t)N_NODES * 64 * 4);
  float* part = (float*)alloc((size_t)256 * 128 * 4);
  float* scale = (float*)alloc(64 * 4);
  float* shift = (float*)alloc(64 * 4);
  float* wS1 = (float*)alloc(32 * 4);
  float* wD1 = (float*)alloc(32 * 4);
  float* wS2 = (float*)alloc(256 * 4);
  float* wD2 = (float*)alloc(256 * 4);
  float* wS3 = (float*)alloc(256 * 4);
  float* wD3 = (float*)alloc(256 * 4);
  __half* wf1 = (__half*)alloc((size_t)4 * 512 * 2);
  __half* wf2 = (__half*)alloc((size_t)32 * 512 * 2);
  __half* wf3 = (__half*)alloc((size_t)16 * 512 * 2);
  if (off > ws_size) return;

  hipMemsetAsync(pool, 0, zbytes, stream);

  // prep (weights fold/pack + gCursor init), then bucket-sort CSR build
  k_prep<<<16 + cdiv(NBUCK, 256), 256, 0, stream>>>(W1, aS1, aD1, W2, aS2, aD2, W3, aS3, aD3,
                                                    wS1, wD1, wS2, wD2, wS3, wD3, wf1, wf2, wf3,
                                                    gCursor);
  k_bucket<<<cdiv(EP, BCHUNK), 256, 0, stream>>>(ei, gCursor, pairs);
  k_bscan<<<1, 1024, 0, stream>>>(gCursor, bstart);
  k_build<<<NBUCK, 256, 0, stream>>>(pairs, bstart, indptr, esrc);

  int npost = cdiv(N_NODES, 64);

  // ---- layer 1: gather raw x (8 fp32, 8-lane groups), MFMA projection (NK=1) ----
  k_attdots1<<<cdiv(N_NODES, 256), 256, 0, stream>>>(x, wS1, wD1, (float4*)as_, (float4*)ad_);
  k_agg<8, float, 3><<<cdiv(N_NODES, 32), 256, 0, stream>>>(indptr, esrc, x, (const float4*)as_,
                                                            (const float4*)ad_, acc16);
  k_post_mfma<64, 1><<<npost, 256, 0, stream>>>(acc16, wf1, b1, tbuf);
  k_bnstat<64><<<256, 256, 0, stream>>>(tbuf, part);
  k_bnfinal<64><<<1, 64, 0, stream>>>(part, g1, be1, scale, shift);

  // ---- layer 2: gather xhat (64 fp16, 16-lane groups), MFMA projection (NK=8) ----
  k_bnx<<<cdiv(N_NODES, 4), 256, 0, stream>>>(tbuf, scale, shift, wS2, wD2, xhat,
                                              (float4*)as_, (float4*)ad_);
  k_agg<64, __half, 4><<<cdiv(N_NODES, 16), 256, 0, stream>>>(indptr, esrc, xhat,
                                                              (const float4*)as_,
                                                              (const float4*)ad_, acc16);
  k_post_mfma<64, 8><<<npost, 256, 0, stream>>>(acc16, wf2, b2, tbuf);
  k_bnstat<64><<<256, 256, 0, stream>>>(tbuf, part);
  k_bnfinal<64><<<1, 64, 0, stream>>>(part, g2, be2, scale, shift);

  // ---- layer 3: gather xhat (64 fp16), MFMA projection (DOUT=32, NK=8) ----
  k_bnx<<<cdiv(N_NODES, 4), 256, 0, stream>>>(tbuf, scale, shift, wS3, wD3, xhat,
                                              (float4*)as_, (float4*)ad_);
  k_agg<64, __half, 4><<<cdiv(N_NODES, 16), 256, 0, stream>>>(indptr, esrc, xhat,
                                                              (const float4*)as_,
                                                              (const float4*)ad_, acc16);
  k_post_mfma<32, 8><<<npost, 256, 0, stream>>>(acc16, wf3, b3, tbuf);
  k_bnstat<32><<<256, 256, 0, stream>>>(tbuf, part);
  k_bnfinal<32><<<1, 32, 0, stream>>>(part, g3, be3, scale, shift);

  // ---- pool (BN3 on load) + MLP ----
  k_pool<<<cdiv(N_NODES, POOL_NPB), 256, 0, stream>>>(tbuf, batch, scale, shift, pool, cntg);
  k_mlp<<<1, 64, 0, stream>>>(pool, cntg, Wp1, bp1, Wp2, bp2, out);
}

// Round 12
// 427.553 us; speedup vs baseline: 5.4417x; 1.0634x over previous
//
#include <hip/hip_runtime.h>
#include <hip/hip_fp16.h>

#define N_NODES 100000
#define N_EDGES 1600000
#define EP (N_EDGES + N_NODES)
#define NG 64
#define NH 4
#define POOL_NPB 256
#define BSHIFT 7
#define BNODES 128
#define NBUCK 782   // cdiv(N_NODES, 128)
#define BCAP 3072   // per-bucket capacity (mean 2176, overflow ~20 sigma away)
#define BCHUNK 4096 // edges per k_bucket block (16 per thread)

static inline int cdiv(int a, int b) { return (a + b - 1) / b; }

typedef _Float16 half8 __attribute__((ext_vector_type(8)));
typedef float f32x4 __attribute__((ext_vector_type(4)));

__device__ __forceinline__ float lrelu(float x) { return x >= 0.f ? x : 0.2f * x; }

// ---------------- CSR build: bucket sort (coalesced writes, randomness in LDS) ----------------
__global__ __launch_bounds__(256) void k_bucket(const int* __restrict__ ei,
                                                int* __restrict__ gCursor,
                                                unsigned int* __restrict__ pairs) {
  __shared__ int cnt[NBUCK];
  __shared__ int base[NBUCK];
  int tid = threadIdx.x;
  for (int b = tid; b < NBUCK; b += 256) cnt[b] = 0;
  __syncthreads();
  int e0 = blockIdx.x * BCHUNK;
  unsigned int stV[16];
  int stB[16];
#pragma unroll
  for (int i = 0; i < 16; i++) {
    int e = e0 + i * 256 + tid;
    stB[i] = -1;
    if (e < EP) {
      int d, s;
      if (e < N_EDGES) {
        d = __builtin_nontemporal_load(&ei[N_EDGES + e]);
        s = __builtin_nontemporal_load(&ei[e]);
      } else {
        d = s = e - N_EDGES;
      }
      int b = d >> BSHIFT;
      stV[i] = ((unsigned int)s << BSHIFT) | (unsigned int)(d & (BNODES - 1));
      stB[i] = b;
      atomicAdd(&cnt[b], 1);
    }
  }
  __syncthreads();
  for (int b = tid; b < NBUCK; b += 256) {
    base[b] = atomicAdd(&gCursor[b], cnt[b]);
    cnt[b] = 0;  // reuse as cursor
  }
  __syncthreads();
#pragma unroll
  for (int i = 0; i < 16; i++) {
    if (stB[i] >= 0) {
      int r = atomicAdd(&cnt[stB[i]], 1);
      pairs[base[stB[i]] + r] = stV[i];
    }
  }
}

__global__ __launch_bounds__(1024) void k_bscan(const int* __restrict__ gCursor,
                                                int* __restrict__ bstart) {
  __shared__ int sh[1024];
  int t = threadIdx.x;
  int v = (t < NBUCK) ? (gCursor[t] - t * BCAP) : 0;
  sh[t] = v;
  __syncthreads();
  for (int off = 1; off < 1024; off <<= 1) {
    int add = (t >= off) ? sh[t - off] : 0;
    __syncthreads();
    sh[t] += add;
    __syncthreads();
  }
  if (t < NBUCK) {
    bstart[t] = sh[t] - v;
    if (t == NBUCK - 1) bstart[NBUCK] = sh[t];
  }
}

__global__ __launch_bounds__(256) void k_build(const unsigned int* __restrict__ pairs,
                                               const int* __restrict__ bstart,
                                               int* __restrict__ indptr, int* __restrict__ esrc) {
  __shared__ int cnt[BNODES];
  __shared__ int exc[BNODES];
  __shared__ int ptr[BNODES];
  __shared__ int eLds[BCAP];
  int b = blockIdx.x;
  int tid = threadIdx.x;
  int obase = bstart[b];
  int nE = bstart[b + 1] - obase;
  int pbase = b * BCAP;
  if (tid < BNODES) cnt[tid] = 0;
  __syncthreads();
  unsigned int stV[12];
#pragma unroll
  for (int i = 0; i < 12; i++) {
    int idx = i * 256 + tid;
    stV[i] = 0xFFFFFFFFu;
    if (idx < nE) {
      unsigned int v = pairs[pbase + idx];
      stV[i] = v;
      atomicAdd(&cnt[v & (BNODES - 1)], 1);
    }
  }
  __syncthreads();
  if (tid < BNODES) ptr[tid] = cnt[tid];
  __syncthreads();
  for (int off = 1; off < BNODES; off <<= 1) {
    int add = (tid < BNODES && tid >= off) ? ptr[tid - off] : 0;
    __syncthreads();
    if (tid < BNODES) ptr[tid] += add;
    __syncthreads();
  }
  if (tid < BNODES) {
    exc[tid] = ptr[tid] - cnt[tid];
    int n = (b << BSHIFT) + tid;
    if (n < N_NODES) indptr[n] = obase + exc[tid];
    cnt[tid] = 0;  // reuse as cursor
  }
  if (b == NBUCK - 1 && tid == 0) indptr[N_NODES] = bstart[NBUCK];
  __syncthreads();
#pragma unroll
  for (int i = 0; i < 12; i++) {
    if (stV[i] != 0xFFFFFFFFu) {
      int ln = stV[i] & (BNODES - 1);
      int r = atomicAdd(&cnt[ln], 1);
      eLds[exc[ln] + r] = (int)(stV[i] >> BSHIFT);
    }
  }
  __syncthreads();
  for (int idx = tid; idx < nE; idx += 256) esrc[obase + idx] = eLds[idx];
}

// ---------------- prep: attention-fold vectors + MFMA B-fragment packing + cursor init ----------------
template <int FIN, int D>
__device__ void wvec_impl(const float* __restrict__ W, const float* __restrict__ aS,
                          const float* __restrict__ aD, float* __restrict__ wS,
                          float* __restrict__ wD, int t) {
  if (t >= 4 * FIN) return;
  int h = t / FIN, k = t % FIN;
  float ss = 0.f, dd = 0.f;
  for (int d = 0; d < D; d++) {
    float w = W[k * (4 * D) + h * D + d];
    ss = fmaf(w, aS[h * D + d], ss);
    dd = fmaf(w, aD[h * D + d], dd);
  }
  wS[h * FIN + k] = ss;
  wD[h * FIN + k] = dd;
}

// B-frag over kk = dim*4 + head: lane l holds B[kk = kt*32+(l>>4)*8+j][col = ct*16+(l&15)]
template <int D>
__device__ void wcvt_frag(const float* __restrict__ W, __half* __restrict__ wf, int frag, int l) {
  constexpr int NCT = D / 16;
  int kt = frag / NCT, ct = frag % NCT;
  half8 v;
#pragma unroll
  for (int j = 0; j < 8; j++) {
    int kk = kt * 32 + (l >> 4) * 8 + j;
    int k = kk >> 2, h = kk & 3;
    v[j] = (_Float16)W[k * (4 * D) + h * D + ct * 16 + (l & 15)];
  }
  *(half8*)(wf + (size_t)frag * 512 + l * 8) = v;
}

__global__ __launch_bounds__(256) void k_prep(const float* W1, const float* aS1, const float* aD1,
                                              const float* W2, const float* aS2, const float* aD2,
                                              const float* W3, const float* aS3, const float* aD3,
                                              float* wS1, float* wD1, float* wS2, float* wD2,
                                              float* wS3, float* wD3,
                                              __half* wf1, __half* wf2, __half* wf3,
                                              int* gCursor) {
  int b = blockIdx.x, t = threadIdx.x;
  int f = t >> 6, l = t & 63;
  if (b == 0) wvec_impl<8, 64>(W1, aS1, aD1, wS1, wD1, t);
  else if (b == 1) wvec_impl<64, 64>(W2, aS2, aD2, wS2, wD2, t);
  else if (b == 2) wvec_impl<64, 32>(W3, aS3, aD3, wS3, wD3, t);
  else if (b == 3) wcvt_frag<64>(W1, wf1, f, l);                    // FIN=8 -> 4 frags
  else if (b < 12) wcvt_frag<64>(W2, wf2, (b - 4) * 4 + f, l);      // 32 frags
  else if (b < 16) wcvt_frag<32>(W3, wf3, (b - 12) * 4 + f, l);     // 16 frags
  else {
    int idx = (b - 16) * 256 + t;
    if (idx < NBUCK) gCursor[idx] = idx * BCAP;
  }
}

// ---------------- layer-1 attention dots from raw x (FIN=8) ----------------
__global__ void k_attdots1(const float* __restrict__ x, const float* __restrict__ wS,
                           const float* __restrict__ wD, float4* __restrict__ as4,
                           float4* __restrict__ ad4) {
  int n = blockIdx.x * blockDim.x + threadIdx.x;
  if (n >= N_NODES) return;
  float4 s = {0, 0, 0, 0}, d = {0, 0, 0, 0};
#pragma unroll
  for (int k = 0; k < 8; k++) {
    float xv = x[(size_t)n * 8 + k];
    s.x = fmaf(xv, wS[k], s.x);
    s.y = fmaf(xv, wS[8 + k], s.y);
    s.z = fmaf(xv, wS[16 + k], s.z);
    s.w = fmaf(xv, wS[24 + k], s.w);
    d.x = fmaf(xv, wD[k], d.x);
    d.y = fmaf(xv, wD[8 + k], d.y);
    d.z = fmaf(xv, wD[16 + k], d.z);
    d.w = fmaf(xv, wD[24 + k], d.w);
  }
  as4[n] = s;
  ad4[n] = d;
}

// ---------------- BN-apply + fp16 cast + attention dots (FIN=64) ----------------
__global__ __launch_bounds__(256) void k_bnx(const float* __restrict__ tbuf,
                                             const float* __restrict__ scale,
                                             const float* __restrict__ shift,
                                             const float* __restrict__ wS,
                                             const float* __restrict__ wD,
                                             __half* __restrict__ xhat,
                                             float4* __restrict__ as4, float4* __restrict__ ad4) {
  int lane = threadIdx.x & 63;
  int n = blockIdx.x * 4 + (threadIdx.x >> 6);
  if (n >= N_NODES) return;
  float v = fmaf(tbuf[(size_t)n * 64 + lane], scale[lane], shift[lane]);
  xhat[(size_t)n * 64 + lane] = __float2half(v);
  float p0 = v * wS[lane], p1 = v * wS[64 + lane], p2 = v * wS[128 + lane], p3 = v * wS[192 + lane];
  float q0 = v * wD[lane], q1 = v * wD[64 + lane], q2 = v * wD[128 + lane], q3 = v * wD[192 + lane];
#pragma unroll
  for (int off = 32; off; off >>= 1) {
    p0 += __shfl_xor(p0, off); p1 += __shfl_xor(p1, off);
    p2 += __shfl_xor(p2, off); p3 += __shfl_xor(p3, off);
    q0 += __shfl_xor(q0, off); q1 += __shfl_xor(q1, off);
    q2 += __shfl_xor(q2, off); q3 += __shfl_xor(q3, off);
  }
  if (lane == 0) {
    as4[n] = make_float4(p0, p1, p2, p3);
    ad4[n] = make_float4(q0, q1, q2, q3);
  }
}

// ---------------- layer-1 gather (8-lane groups, DIN=8 fp32) -> acc16 [n][32] ----------------
__global__ __launch_bounds__(256) void k_agg1(const int* __restrict__ indptr,
                                              const int* __restrict__ esrc,
                                              const float* __restrict__ xg,
                                              const float4* __restrict__ as4,
                                              const float4* __restrict__ ad4,
                                              __half* __restrict__ accO) {
  constexpr int GL = 8, NPW = 8, WB = NPW * (GL + 1);
  __shared__ int sOff[4 * WB];
  __shared__ float4 sW[4 * WB];
  int tid = threadIdx.x;
  int lane = tid & 63;
  int wv = tid >> 6;
  int q = lane & (GL - 1);
  int g = lane >> 3;
  int n = blockIdx.x * (4 * NPW) + wv * NPW + g;
  if (n >= N_NODES) return;
  int e0 = indptr[n], e1 = indptr[n + 1];
  float4 ad = ad4[n];
  int lbase = wv * WB + g * (GL + 1);
  const char* xb = (const char*)xg + q * 4;
  float s0 = 0.f, s1 = 0.f, s2 = 0.f, s3 = 0.f;
  float a0 = 0.f, a1 = 0.f, a2 = 0.f, a3 = 0.f;
  for (int c = e0; c < e1; c += GL) {
    int nc = min(GL, e1 - c);
    float w0 = 0.f, w1 = 0.f, w2 = 0.f, w3 = 0.f;
    int sB = 0;
    if (q < nc) {
      int sidx = esrc[c + q];
      float4 av = as4[sidx];
      w0 = __expf(lrelu(av.x + ad.x));
      w1 = __expf(lrelu(av.y + ad.y));
      w2 = __expf(lrelu(av.z + ad.z));
      w3 = __expf(lrelu(av.w + ad.w));
      sB = sidx << 5;
    }
    s0 += w0; s1 += w1; s2 += w2; s3 += w3;
    sOff[lbase + q] = sB;
    sW[lbase + q] = make_float4(w0, w1, w2, w3);
    __builtin_amdgcn_wave_barrier();
    for (int i = 0; i < nc; ++i) {
      float4 w = sW[lbase + i];
      int ob = sOff[lbase + i];
      float xv = *(const float*)(xb + ob);
      a0 = fmaf(w.x, xv, a0);
      a1 = fmaf(w.y, xv, a1);
      a2 = fmaf(w.z, xv, a2);
      a3 = fmaf(w.w, xv, a3);
    }
    __builtin_amdgcn_wave_barrier();
  }
#pragma unroll
  for (int off = 1; off < GL; off <<= 1) {
    s0 += __shfl_xor(s0, off);
    s1 += __shfl_xor(s1, off);
    s2 += __shfl_xor(s2, off);
    s3 += __shfl_xor(s3, off);
  }
  float r0 = 1.f / (s0 + 1e-16f), r1 = 1.f / (s1 + 1e-16f);
  float r2 = 1.f / (s2 + 1e-16f), r3 = 1.f / (s3 + 1e-16f);
  __half2 p01 = __floats2half2_rn(a0 * r0, a1 * r1);
  __half2 p23 = __floats2half2_rn(a2 * r2, a3 * r3);
  uint2 pk = make_uint2(*(unsigned*)&p01, *(unsigned*)&p23);
  *(uint2*)(accO + (size_t)n * 32 + q * 4) = pk;
}

// ---------------- fused gather + MFMA projection (layers 2/3; block = 16 nodes = 1 M-tile) ----------------
// Gather phase (16-lane groups) -> LDS A-tile [16][264 halves, padded] -> per-wave ct MFMA -> tbuf.
template <int DOUT>
__global__ __launch_bounds__(256) void k_aggp(const int* __restrict__ indptr,
                                              const int* __restrict__ esrc,
                                              const __half* __restrict__ xg,
                                              const float4* __restrict__ as4,
                                              const float4* __restrict__ ad4,
                                              const __half* __restrict__ wfrag,
                                              const float* __restrict__ bias,
                                              float* __restrict__ tbuf) {
  constexpr int NCT = DOUT / 16;
  constexpr int GL = 16, NPW = 4, WB = NPW * (GL + 1);  // 68
  __shared__ int sOff[4 * WB];
  __shared__ float4 sW[4 * WB];
  __shared__ __align__(16) __half aT[16 * 264];  // padded row stride 264 halves (528 B)
  int tid = threadIdx.x;
  int lane = tid & 63;
  int wv = tid >> 6;
  int q = lane & 15;
  int g = lane >> 4;
  int row = wv * 4 + g;                 // node row in block (grid exact: 6250*16 = 100000)
  int n = blockIdx.x * 16 + row;
  int e0 = indptr[n], e1 = indptr[n + 1];
  float4 ad = ad4[n];
  int lbase = wv * WB + g * (GL + 1);
  const char* xb = (const char*)xg + q * 8;
  float s0 = 0.f, s1 = 0.f, s2 = 0.f, s3 = 0.f;
  float a[4][4];
#pragma unroll
  for (int d = 0; d < 4; d++)
#pragma unroll
    for (int h = 0; h < 4; h++) a[d][h] = 0.f;

  for (int c = e0; c < e1; c += GL) {
    int nc = min(GL, e1 - c);
    float w0 = 0.f, w1 = 0.f, w2 = 0.f, w3 = 0.f;
    int sB = 0;
    if (q < nc) {
      int sidx = esrc[c + q];
      float4 av = as4[sidx];
      w0 = __expf(lrelu(av.x + ad.x));
      w1 = __expf(lrelu(av.y + ad.y));
      w2 = __expf(lrelu(av.z + ad.z));
      w3 = __expf(lrelu(av.w + ad.w));
      sB = sidx << 7;
    }
    s0 += w0; s1 += w1; s2 += w2; s3 += w3;
    sOff[lbase + q] = sB;
    sW[lbase + q] = make_float4(w0, w1, w2, w3);
    __builtin_amdgcn_wave_barrier();
    for (int i = 0; i < nc; ++i) {
      float4 w = sW[lbase + i];
      int ob = sOff[lbase + i];
      uint2 px = *(const uint2*)(xb + ob);
      float2 f01 = __half22float2(*(const __half2*)&px.x);
      float2 f23 = __half22float2(*(const __half2*)&px.y);
      a[0][0] = fmaf(w.x, f01.x, a[0][0]); a[0][1] = fmaf(w.y, f01.x, a[0][1]);
      a[0][2] = fmaf(w.z, f01.x, a[0][2]); a[0][3] = fmaf(w.w, f01.x, a[0][3]);
      a[1][0] = fmaf(w.x, f01.y, a[1][0]); a[1][1] = fmaf(w.y, f01.y, a[1][1]);
      a[1][2] = fmaf(w.z, f01.y, a[1][2]); a[1][3] = fmaf(w.w, f01.y, a[1][3]);
      a[2][0] = fmaf(w.x, f23.x, a[2][0]); a[2][1] = fmaf(w.y, f23.x, a[2][1]);
      a[2][2] = fmaf(w.z, f23.x, a[2][2]); a[2][3] = fmaf(w.w, f23.x, a[2][3]);
      a[3][0] = fmaf(w.x, f23.y, a[3][0]); a[3][1] = fmaf(w.y, f23.y, a[3][1]);
      a[3][2] = fmaf(w.z, f23.y, a[3][2]); a[3][3] = fmaf(w.w, f23.y, a[3][3]);
    }
    __builtin_amdgcn_wave_barrier();
  }
#pragma unroll
  for (int off = 1; off < GL; off <<= 1) {
    s0 += __shfl_xor(s0, off);
    s1 += __shfl_xor(s1, off);
    s2 += __shfl_xor(s2, off);
    s3 += __shfl_xor(s3, off);
  }
  float r0 = 1.f / (s0 + 1e-16f), r1 = 1.f / (s1 + 1e-16f);
  float r2 = 1.f / (s2 + 1e-16f), r3 = 1.f / (s3 + 1e-16f);
  // stage normalized acc (kk = q*16 .. q*16+15) into the A-tile
  __half2 p[8];
#pragma unroll
  for (int d = 0; d < 4; d++) {
    p[2 * d] = __floats2half2_rn(a[d][0] * r0, a[d][1] * r1);
    p[2 * d + 1] = __floats2half2_rn(a[d][2] * r2, a[d][3] * r3);
  }
  uint4 lo = make_uint4(*(unsigned*)&p[0], *(unsigned*)&p[1], *(unsigned*)&p[2], *(unsigned*)&p[3]);
  uint4 hi = make_uint4(*(unsigned*)&p[4], *(unsigned*)&p[5], *(unsigned*)&p[6], *(unsigned*)&p[7]);
  *(uint4*)&aT[row * 264 + q * 16] = lo;
  *(uint4*)&aT[row * 264 + q * 16 + 8] = hi;
  __syncthreads();
  // MFMA phase: wave wv handles output column-tile ct = wv (waves >= NCT idle)
  if (wv < NCT) {
    int ct = wv;
    int m = lane & 15, kg = lane >> 4;
    f32x4 cacc = (f32x4){0.f, 0.f, 0.f, 0.f};
#pragma unroll
    for (int kt = 0; kt < 8; kt++) {
      half8 av = *(const half8*)&aT[m * 264 + kt * 32 + kg * 8];
      half8 bv = *(const half8*)(wfrag + ((kt * NCT + ct) * 64 + lane) * 8);
      cacc = __builtin_amdgcn_mfma_f32_16x16x32_f16(av, bv, cacc, 0, 0, 0);
    }
    float bv = bias[ct * 16 + m];
#pragma unroll
    for (int j = 0; j < 4; j++) {
      int nr = blockIdx.x * 16 + kg * 4 + j;
      tbuf[(size_t)nr * DOUT + ct * 16 + m] = fmaxf(fmaf(cacc[j], 0.25f, bv), 0.f);
    }
  }
}

// ---------------- MFMA projection (layer 1 only, NK=1) ----------------
template <int DOUT, int NK>
__global__ __launch_bounds__(256) void k_post_mfma(const __half* __restrict__ accA,
                                                   const __half* __restrict__ wfrag,
                                                   const float* __restrict__ bias,
                                                   float* __restrict__ tbuf) {
  constexpr int NCT = DOUT / 16;
  constexpr int AS = NK * 32;
  int l = threadIdx.x & 63;
  int n0 = (blockIdx.x * 4 + (threadIdx.x >> 6)) * 16;
  int m = l & 15, kg = l >> 4;
  f32x4 c[NCT];
#pragma unroll
  for (int ct = 0; ct < NCT; ct++) c[ct] = (f32x4){0.f, 0.f, 0.f, 0.f};
#pragma unroll
  for (int kt = 0; kt < NK; kt++) {
    half8 a = *(const half8*)(accA + (size_t)(n0 + m) * AS + kt * 32 + kg * 8);
#pragma unroll
    for (int ct = 0; ct < NCT; ct++) {
      half8 b = *(const half8*)(wfrag + ((kt * NCT + ct) * 64 + l) * 8);
      c[ct] = __builtin_amdgcn_mfma_f32_16x16x32_f16(a, b, c[ct], 0, 0, 0);
    }
  }
#pragma unroll
  for (int ct = 0; ct < NCT; ct++) {
    float bv = bias[ct * 16 + m];
#pragma unroll
    for (int j = 0; j < 4; j++) {
      int n = n0 + kg * 4 + j;
      if (n < N_NODES) tbuf[(size_t)n * DOUT + ct * 16 + m] = fmaxf(fmaf(c[ct][j], 0.25f, bv), 0.f);
    }
  }
}

// ---------------- batch norm stats ----------------
template <int C>
__global__ __launch_bounds__(256) void k_bnstat(const float* __restrict__ x, float* __restrict__ part) {
  const int RG = 256 / C;
  int col = threadIdx.x & (C - 1);
  int rg = threadIdx.x / C;
  int rows = (N_NODES + gridDim.x - 1) / gridDim.x;
  int r0 = blockIdx.x * rows;
  int r1 = min(N_NODES, r0 + rows);
  float s = 0.f, q = 0.f;
  for (int r = r0 + rg; r < r1; r += RG) {
    float v = x[(size_t)r * C + col];
    s += v;
    q = fmaf(v, v, q);
  }
  __shared__ float sh[512];
  sh[threadIdx.x] = s;
  sh[256 + threadIdx.x] = q;
  __syncthreads();
  for (int step = 128; step >= C; step >>= 1) {
    if (threadIdx.x < step) {
      sh[threadIdx.x] += sh[threadIdx.x + step];
      sh[256 + threadIdx.x] += sh[256 + threadIdx.x + step];
    }
    __syncthreads();
  }
  if (threadIdx.x < C) {
    part[blockIdx.x * 2 * C + threadIdx.x] = sh[threadIdx.x];
    part[blockIdx.x * 2 * C + C + threadIdx.x] = sh[256 + threadIdx.x];
  }
}

template <int C>
__global__ void k_bnfinal(const float* __restrict__ part, const float* __restrict__ g,
                          const float* __restrict__ be, float* __restrict__ scale,
                          float* __restrict__ shift) {
  int c = threadIdx.x;
  if (c >= C) return;
  float s = 0.f, q = 0.f;
  for (int b = 0; b < 256; b++) {
    s += part[b * 2 * C + c];
    q += part[b * 2 * C + C + c];
  }
  float mean = s / (float)N_NODES;
  float var = q / (float)N_NODES - mean * mean;
  float sc = g[c] * rsqrtf(var + 1e-5f);
  scale[c] = sc;
  shift[c] = be[c] - mean * sc;
}

// ---------------- pooling (applies layer-3 BN on load; batch sorted) ----------------
__global__ __launch_bounds__(256) void k_pool(const float* __restrict__ f3,
                                              const int* __restrict__ batch,
                                              const float* __restrict__ scale,
                                              const float* __restrict__ shift,
                                              float* __restrict__ pool,
                                              float* __restrict__ cntg) {
  __shared__ float acc[NG][33];
  int t = threadIdx.x;
  for (int i = t; i < NG * 33; i += 256) ((float*)acc)[i] = 0.f;
  __syncthreads();
  int c = t & 31, rg = t >> 5;
  float sc = scale[c], sh = shift[c];
  int n0 = blockIdx.x * POOL_NPB;
  int n1 = min(N_NODES, n0 + POOL_NPB);
  float r = 0.f, rc = 0.f;
  int gcur = -1;
  for (int n = n0 + rg; n < n1; n += 8) {
    int g = batch[n];
    if (g != gcur) {
      if (gcur >= 0) {
        atomicAdd(&acc[gcur][c], r);
        if (c == 0) atomicAdd(&acc[gcur][32], rc);
      }
      gcur = g;
      r = 0.f;
      rc = 0.f;
    }
    r += fmaf(f3[(size_t)n * 32 + c], sc, sh);
    rc += 1.f;
  }
  if (gcur >= 0) {
    atomicAdd(&acc[gcur][c], r);
    if (c == 0) atomicAdd(&acc[gcur][32], rc);
  }
  __syncthreads();
  for (int i = t; i < NG * 32; i += 256) {
    int g = i >> 5, cc = i & 31;
    float v = acc[g][cc];
    if (v != 0.f) atomicAdd(&pool[i], v);
  }
  for (int g = t; g < NG; g += 256) {
    float v = acc[g][32];
    if (v != 0.f) atomicAdd(&cntg[g], v);
  }
}

__global__ void k_mlp(const float* __restrict__ pool, const float* __restrict__ cntg,
                      const float* __restrict__ Wp1, const float* __restrict__ bp1,
                      const float* __restrict__ Wp2, const float* __restrict__ bp2,
                      float* __restrict__ out) {
  int g = threadIdx.x;
  if (g >= NG) return;
  float inv = 1.f / fmaxf(cntg[g], 1.f);
  float p[32];
#pragma unroll
  for (int c = 0; c < 32; c++) p[c] = pool[g * 32 + c] * inv;
  float o = bp2[0];
  for (int j = 0; j < 16; j++) {
    float hsum = bp1[j];
#pragma unroll
    for (int c = 0; c < 32; c++) hsum = fmaf(p[c], Wp1[c * 16 + j], hsum);
    o = fmaf(fmaxf(hsum, 0.f), Wp2[j], o);
  }
  out[g] = o;
}

extern "C" void kernel_launch(void* const* d_in, const int* in_sizes, int n_in,
                              void* d_out, int out_size, void* d_ws, size_t ws_size,
                              hipStream_t stream) {
  const float* x = (const float*)d_in[0];
  const int* ei = (const int*)d_in[1];
  const int* batch = (const int*)d_in[2];
  const float* W1 = (const float*)d_in[3];
  const float* aS1 = (const float*)d_in[4];
  const float* aD1 = (const float*)d_in[5];
  const float* b1 = (const float*)d_in[6];
  const float* g1 = (const float*)d_in[7];
  const float* be1 = (const float*)d_in[8];
  const float* W2 = (const float*)d_in[9];
  const float* aS2 = (const float*)d_in[10];
  const float* aD2 = (const float*)d_in[11];
  const float* b2 = (const float*)d_in[12];
  const float* g2 = (const float*)d_in[13];
  const float* be2 = (const float*)d_in[14];
  const float* W3 = (const float*)d_in[15];
  const float* aS3 = (const float*)d_in[16];
  const float* aD3 = (const float*)d_in[17];
  const float* b3 = (const float*)d_in[18];
  const float* g3 = (const float*)d_in[19];
  const float* be3 = (const float*)d_in[20];
  const float* Wp1 = (const float*)d_in[21];
  const float* bp1 = (const float*)d_in[22];
  const float* Wp2 = (const float*)d_in[23];
  const float* bp2 = (const float*)d_in[24];
  float* out = (float*)d_out;

  size_t off = 0;
  auto alloc = [&](size_t bytes) -> void* {
    void* p = (char*)d_ws + off;
    off += (bytes + 255) & ~(size_t)255;
    return p;
  };
  // zeroed region (single memset): pool, cntg
  float* pool = (float*)alloc((size_t)NG * 32 * 4);
  float* cntg = (float*)alloc((size_t)NG * 4);
  size_t zbytes = off;
  int* gCursor = (int*)alloc((size_t)NBUCK * 4);
  int* bstart = (int*)alloc((size_t)(NBUCK + 1) * 4);
  unsigned int* pairs = (unsigned int*)alloc((size_t)NBUCK * BCAP * 4);
  int* indptr = (int*)alloc((size_t)(N_NODES + 1) * 4);
  int* esrc = (int*)alloc((size_t)EP * 4);
  __half* xhat = (__half*)alloc((size_t)N_NODES * 64 * 2);
  __half* acc16 = (__half*)alloc((size_t)(N_NODES + 16) * 32 * 2);  // layer-1 interleaved [n][32]
  float* as_ = (float*)alloc((size_t)N_NODES * 16);
  float* ad_ = (float*)alloc((size_t)N_NODES * 16);
  float* tbuf = (float*)alloc((size_t)N_NODES * 64 * 4);
  float* part = (float*)alloc((size_t)256 * 128 * 4);
  float* scale = (float*)alloc(64 * 4);
  float* shift = (float*)alloc(64 * 4);
  float* wS1 = (float*)alloc(32 * 4);
  float* wD1 = (float*)alloc(32 * 4);
  float* wS2 = (float*)alloc(256 * 4);
  float* wD2 = (float*)alloc(256 * 4);
  float* wS3 = (float*)alloc(256 * 4);
  float* wD3 = (float*)alloc(256 * 4);
  __half* wf1 = (__half*)alloc((size_t)4 * 512 * 2);
  __half* wf2 = (__half*)alloc((size_t)32 * 512 * 2);
  __half* wf3 = (__half*)alloc((size_t)16 * 512 * 2);
  if (off > ws_size) return;

  hipMemsetAsync(pool, 0, zbytes, stream);

  k_prep<<<16 + cdiv(NBUCK, 256), 256, 0, stream>>>(W1, aS1, aD1, W2, aS2, aD2, W3, aS3, aD3,
                                                    wS1, wD1, wS2, wD2, wS3, wD3, wf1, wf2, wf3,
                                                    gCursor);
  k_bucket<<<cdiv(EP, BCHUNK), 256, 0, stream>>>(ei, gCursor, pairs);
  k_bscan<<<1, 1024, 0, stream>>>(gCursor, bstart);
  k_build<<<NBUCK, 256, 0, stream>>>(pairs, bstart, indptr, esrc);

  // ---- layer 1: gather raw x (8 fp32, 8-lane groups), MFMA projection (NK=1) ----
  k_attdots1<<<cdiv(N_NODES, 256), 256, 0, stream>>>(x, wS1, wD1, (float4*)as_, (float4*)ad_);
  k_agg1<<<cdiv(N_NODES, 32), 256, 0, stream>>>(indptr, esrc, x, (const float4*)as_,
                                                (const float4*)ad_, acc16);
  k_post_mfma<64, 1><<<cdiv(N_NODES, 64), 256, 0, stream>>>(acc16, wf1, b1, tbuf);
  k_bnstat<64><<<256, 256, 0, stream>>>(tbuf, part);
  k_bnfinal<64><<<1, 64, 0, stream>>>(part, g1, be1, scale, shift);

  // ---- layer 2: fused gather + MFMA projection (DOUT=64) ----
  k_bnx<<<cdiv(N_NODES, 4), 256, 0, stream>>>(tbuf, scale, shift, wS2, wD2, xhat,
                                              (float4*)as_, (float4*)ad_);
  k_aggp<64><<<N_NODES / 16, 256, 0, stream>>>(indptr, esrc, xhat, (const float4*)as_,
                                               (const float4*)ad_, wf2, b2, tbuf);
  k_bnstat<64><<<256, 256, 0, stream>>>(tbuf, part);
  k_bnfinal<64><<<1, 64, 0, stream>>>(part, g2, be2, scale, shift);

  // ---- layer 3: fused gather + MFMA projection (DOUT=32) ----
  k_bnx<<<cdiv(N_NODES, 4), 256, 0, stream>>>(tbuf, scale, shift, wS3, wD3, xhat,
                                              (float4*)as_, (float4*)ad_);
  k_aggp<32><<<N_NODES / 16, 256, 0, stream>>>(indptr, esrc, xhat, (const float4*)as_,
                                               (const float4*)ad_, wf3, b3, tbuf);
  k_bnstat<32><<<256, 256, 0, stream>>>(tbuf, part);
  k_bnfinal<32><<<1, 32, 0, stream>>>(part, g3, be3, scale, shift);

  // ---- pool (BN3 on load) + MLP ----
  k_pool<<<cdiv(N_NODES, POOL_NPB), 256, 0, stream>>>(tbuf, batch, scale, shift, pool, cntg);
  k_mlp<<<1, 64, 0, stream>>>(pool, cntg, Wp1, bp1, Wp2, bp2, out);
}